// Round 4
// baseline (742.818 us; speedup 1.0000x reference)
//
#include <hip/hip_runtime.h>
#include <hip/hip_bf16.h>

typedef __hip_bfloat16 bf16;
typedef __attribute__((ext_vector_type(8))) short short8;
typedef __attribute__((ext_vector_type(4))) float f32x4;
typedef __attribute__((ext_vector_type(4))) unsigned short us4;
#define DEV __device__ __forceinline__

static constexpr int T_ = 8, NC = 512, NT = 512, D_ = 256, H_ = 8, NBF = 1419;
static constexpr int FT32 = 46;             // 46 f-tiles of 32 (padded 1472)
static constexpr float EPS_ = 1e-4f;
static constexpr float DN = 0.25f;          // D^-0.25
static constexpr float DIAG_SC = 0.03125f;  // 0.5 * DN^2

DEV float bf2f(unsigned short u) { return __uint_as_float(((unsigned)u) << 16); }
DEV float tofloat(bf16 x) { return __bfloat162float(x); }
DEV unsigned short f2bu(float x) { bf16 h = __float2bfloat16(x); return *(unsigned short*)&h; }

DEV float ldx(const void* p, long i, int isb) {
  if (isb) return bf2f(((const unsigned short*)p)[i]);
  return ((const float*)p)[i];
}
DEV void stx(void* p, long i, float v, int isb) {
  if (isb) ((bf16*)p)[i] = __float2bfloat16(v);
  else     ((float*)p)[i] = v;
}
DEV void unpack8(uint4 u, float* dst) {
  unsigned w[4] = {u.x, u.y, u.z, u.w};
#pragma unroll
  for (int i = 0; i < 4; i++) {
    dst[2 * i + 0] = __uint_as_float((w[i] & 0xffffu) << 16);
    dst[2 * i + 1] = __uint_as_float(w[i] & 0xffff0000u);
  }
}

// ------------------------------------------------------------------
// dtype probe (1 = bf16 inputs, 0 = fp32)
// ------------------------------------------------------------------
__global__ __launch_bounds__(256)
void detect_dtype(const void* __restrict__ x, int* __restrict__ flag)
{
  __shared__ int bad;
  if (threadIdx.x == 0) bad = 0;
  __syncthreads();
  int mybad = 0;
  for (int j = 0; j < 16; j++) {
    long i = 2L * (threadIdx.x + 256L * j);
    unsigned short u = ((const unsigned short*)x)[i];
    int e = (u >> 7) & 0xff, mant = u & 0x7f;
    bool b = (e == 0xff) || (e >= 141) || (e <= 93 && !(e == 0 && mant == 0));
    mybad += b ? 1 : 0;
  }
  atomicAdd(&bad, mybad);
  __syncthreads();
  if (threadIdx.x == 0) *flag = (bad > 1024) ? 0 : 1;
}

// proj -> bf16 [FT32*32][256], zero rows past NBF
__global__ __launch_bounds__(256)
void conv_proj(const void* __restrict__ proj, bf16* __restrict__ projB,
               const int* __restrict__ dtFlag)
{
  const int fl = *dtFlag;
  int f = blockIdx.x, t = threadIdx.x;
  float v = (f < NBF) ? ldx(proj, (long)f * 256 + t, fl) : 0.f;
  projB[(long)f * 256 + t] = __float2bfloat16(v);
}

// zero the atomic-target region
__global__ __launch_bounds__(256)
void init_zero(float* __restrict__ p)
{
  p[blockIdx.x * 256 + threadIdx.x] = 0.f;
}

// ------------------------------------------------------------------
// MFMA GEMM, 64x64 tile. cT=0: natural. cT=2: MFMA-tiled store (vQ)
// with optional fused column-sum svOut (Sv for v-projection).
// diagOut!=null: atomicAdd per-row DIAG_SC*sum_n(c^2).
// ------------------------------------------------------------------
__global__ __launch_bounds__(256)
void gemm_mfma(const void* __restrict__ A, int aMode,
               const void* __restrict__ B, const void* __restrict__ bias,
               void* __restrict__ C, int cMode, int epi, int bPerm, int cT,
               const int* __restrict__ dtFlag, float* __restrict__ diagOut,
               float* __restrict__ svOut,
               int M, int N, int K, long sA, int divA, long sB, int modB, long sBias)
{
  __shared__ bf16 As[64 * 40];
  __shared__ bf16 Ws[64 * 40];
  const int fl = *dtFlag;
  const int aB = (aMode == 2) ? fl : aMode;
  const int cB = (cMode == 2) ? fl : cMode;
  const int t = threadIdx.x;
  const int bz = blockIdx.z;
  const long aOff = (long)(bz / divA) * sA;
  const long bOff = (long)(bz % modB) * sB;
  const long biasOff = (long)(bz % modB) * sBias;
  const long cOff = (long)bz * (long)M * N;
  const int m0 = blockIdx.y * 64, n0 = blockIdx.x * 64;
  const int w = t >> 6, l = t & 63, quad = l >> 4, ln = l & 15;
  const int am = t >> 2, ak8 = (t & 3) * 8;
  const int wk = t & 31, wg = t >> 5;
  f32x4 acc[4] = {};

  for (int k0 = 0; k0 < K; k0 += 32) {
    if (aB == 1) {
      const uint4* src = (const uint4*)((const bf16*)A + aOff + (long)(m0 + am) * K + k0 + ak8);
      *(uint4*)(&As[am * 40 + ak8]) = *src;
    } else {
      const float* src = (const float*)A + aOff + (long)(m0 + am) * K + k0 + ak8;
      unsigned short tmp[8];
#pragma unroll
      for (int i = 0; i < 8; i++) tmp[i] = f2bu(src[i]);
      *(uint4*)(&As[am * 40 + ak8]) = *(const uint4*)tmp;
    }
    {
      int k = k0 + wk;
      int krow = bPerm ? (((k & 255) << 3) | (k >> 8)) : k;
      if (fl == 1) {
        uint4 u = *(const uint4*)((const bf16*)B + bOff + (long)krow * N + n0 + wg * 8);
        const unsigned short* us = (const unsigned short*)&u;
#pragma unroll
        for (int j = 0; j < 8; j++) Ws[(wg * 8 + j) * 40 + wk] = *(const bf16*)&us[j];
      } else {
        const float* src = (const float*)B + bOff + (long)krow * N + n0 + wg * 8;
#pragma unroll
        for (int j = 0; j < 8; j++) {
          unsigned short u = f2bu(src[j]);
          Ws[(wg * 8 + j) * 40 + wk] = *(const bf16*)&u;
        }
      }
    }
    __syncthreads();
    short8 a = *(const short8*)(&As[(16 * w + ln) * 40 + quad * 8]);
#pragma unroll
    for (int i = 0; i < 4; i++) {
      short8 b = *(const short8*)(&Ws[(16 * i + ln) * 40 + quad * 8]);
      acc[i] = __builtin_amdgcn_mfma_f32_16x16x32_bf16(a, b, acc[i], 0, 0, 0);
    }
    __syncthreads();
  }

  float s2[4] = {0.f, 0.f, 0.f, 0.f};
  if (cT == 2) {
    const int mm = m0 + 16 * w + quad * 4;
    const int tile = mm >> 5, off = mm & 31;
#pragma unroll
    for (int i = 0; i < 4; i++) {
      int n = n0 + 16 * i + ln;
      us4 cv;
      float colsum = 0.f;
#pragma unroll
      for (int r = 0; r < 4; r++) {
        float c = acc[i][r];
        if (epi >= 1) c += ldx(bias, biasOff + n, fl);
        if (epi == 2) c = fmaxf(c, 0.f);
        colsum += c;
        cv[r] = f2bu(c);
      }
      *(us4*)((bf16*)C + cOff + ((long)tile * N + n) * 32 + off) = cv;
      if (svOut) {
        colsum += __shfl_xor(colsum, 16);
        colsum += __shfl_xor(colsum, 32);
        if (quad == 0) atomicAdd(&svOut[(long)bz * N + n], colsum);
      }
    }
  } else {
#pragma unroll
    for (int i = 0; i < 4; i++) {
#pragma unroll
      for (int r = 0; r < 4; r++) {
        int m = m0 + 16 * w + quad * 4 + r;
        int n = n0 + 16 * i + ln;
        float c = acc[i][r];
        if (epi >= 1) c += ldx(bias, biasOff + n, fl);
        if (epi == 2) c = fmaxf(c, 0.f);
        s2[r] += c * c;
        stx(C, cOff + (long)m * N + n, c, cB);
      }
    }
  }
  if (diagOut) {
#pragma unroll
    for (int r = 0; r < 4; r++) {
      float s = s2[r];
      s += __shfl_xor(s, 1); s += __shfl_xor(s, 2);
      s += __shfl_xor(s, 4); s += __shfl_xor(s, 8);
      if (ln == 0)
        atomicAdd(&diagOut[(long)bz * M + m0 + 16 * w + quad * 4 + r], DIAG_SC * s);
    }
  }
}

// ------------------------------------------------------------------
// MFMA GEMM, 32x64 tile (unchanged from round 16).
// ------------------------------------------------------------------
__global__ __launch_bounds__(256)
void gemm_mfma32(const void* __restrict__ A, int aMode,
                 const void* __restrict__ B, const void* __restrict__ bias,
                 void* __restrict__ C, int cMode, int epi,
                 const int* __restrict__ dtFlag, int M, int N, int K)
{
  __shared__ bf16 As[32 * 40];
  __shared__ bf16 Ws[64 * 40];
  const int fl = *dtFlag;
  const int aB = (aMode == 2) ? fl : aMode;
  const int cB = (cMode == 2) ? fl : cMode;
  const int t = threadIdx.x;
  const int m0 = blockIdx.y * 32, n0 = blockIdx.x * 64;
  const int w = t >> 6, l = t & 63, quad = l >> 4, ln = l & 15;
  const int am = t >> 3, ak4 = (t & 7) * 4;
  const int wk = t & 31, wg = t >> 5;
  const int mi = w & 1, nh = w >> 1;
  f32x4 acc[2] = {};

  for (int k0 = 0; k0 < K; k0 += 32) {
    if (aB == 1) {
      const uint2* src = (const uint2*)((const bf16*)A + (long)(m0 + am) * K + k0 + ak4);
      *(uint2*)(&As[am * 40 + ak4]) = *src;
    } else {
      const float* src = (const float*)A + (long)(m0 + am) * K + k0 + ak4;
      unsigned short tmp[4];
#pragma unroll
      for (int i = 0; i < 4; i++) tmp[i] = f2bu(src[i]);
      *(uint2*)(&As[am * 40 + ak4]) = *(const uint2*)tmp;
    }
    {
      int k = k0 + wk;
      if (fl == 1) {
        uint4 u = *(const uint4*)((const bf16*)B + (long)k * N + n0 + wg * 8);
        const unsigned short* us = (const unsigned short*)&u;
#pragma unroll
        for (int j = 0; j < 8; j++) Ws[(wg * 8 + j) * 40 + wk] = *(const bf16*)&us[j];
      } else {
        const float* src = (const float*)B + (long)k * N + n0 + wg * 8;
#pragma unroll
        for (int j = 0; j < 8; j++) {
          unsigned short u = f2bu(src[j]);
          Ws[(wg * 8 + j) * 40 + wk] = *(const bf16*)&u;
        }
      }
    }
    __syncthreads();
    short8 a = *(const short8*)(&As[(16 * mi + ln) * 40 + quad * 8]);
#pragma unroll
    for (int j = 0; j < 2; j++) {
      short8 b = *(const short8*)(&Ws[(16 * (2 * nh + j) + ln) * 40 + quad * 8]);
      acc[j] = __builtin_amdgcn_mfma_f32_16x16x32_bf16(a, b, acc[j], 0, 0, 0);
    }
    __syncthreads();
  }

#pragma unroll
  for (int j = 0; j < 2; j++) {
#pragma unroll
    for (int r = 0; r < 4; r++) {
      int m = m0 + 16 * mi + quad * 4 + r;
      int n = n0 + 16 * (2 * nh + j) + ln;
      float c = acc[j][r];
      if (epi >= 1) c += ldx(bias, n, fl);
      if (epi == 2) c = fmaxf(c, 0.f);
      stx(C, (long)m * N + n, c, cB);
    }
  }
}

// ------------------------------------------------------------------
// Wo GEMM, split-K x8 (unchanged).
// ------------------------------------------------------------------
__global__ __launch_bounds__(256)
void gemm_wo_splitk(const bf16* __restrict__ A, const void* __restrict__ B,
                    float* __restrict__ P, const int* __restrict__ dtFlag,
                    int M, int N, int K)
{
  __shared__ bf16 As[64 * 40];
  __shared__ bf16 Ws[64 * 40];
  const int fl = *dtFlag;
  const int t = threadIdx.x;
  const int z = blockIdx.z;
  const int m0 = blockIdx.y * 64, n0 = blockIdx.x * 64;
  const int w = t >> 6, l = t & 63, quad = l >> 4, ln = l & 15;
  const int am = t >> 2, ak8 = (t & 3) * 8;
  const int wk = t & 31, wg = t >> 5;
  f32x4 acc[4] = {};
  const int kbase = z * 256;

  for (int k0 = kbase; k0 < kbase + 256; k0 += 32) {
    {
      const uint4* src = (const uint4*)(A + (long)(m0 + am) * K + k0 + ak8);
      *(uint4*)(&As[am * 40 + ak8]) = *src;
    }
    {
      int k = k0 + wk;
      int krow = ((k & 255) << 3) | (k >> 8);
      if (fl == 1) {
        uint4 u = *(const uint4*)((const bf16*)B + (long)krow * N + n0 + wg * 8);
        const unsigned short* us = (const unsigned short*)&u;
#pragma unroll
        for (int j = 0; j < 8; j++) Ws[(wg * 8 + j) * 40 + wk] = *(const bf16*)&us[j];
      } else {
        const float* src = (const float*)B + (long)krow * N + n0 + wg * 8;
#pragma unroll
        for (int j = 0; j < 8; j++) {
          unsigned short u = f2bu(src[j]);
          Ws[(wg * 8 + j) * 40 + wk] = *(const bf16*)&u;
        }
      }
    }
    __syncthreads();
    short8 a = *(const short8*)(&As[(16 * w + ln) * 40 + quad * 8]);
#pragma unroll
    for (int i = 0; i < 4; i++) {
      short8 b = *(const short8*)(&Ws[(16 * i + ln) * 40 + quad * 8]);
      acc[i] = __builtin_amdgcn_mfma_f32_16x16x32_bf16(a, b, acc[i], 0, 0, 0);
    }
    __syncthreads();
  }

  float* Pz = P + (long)z * M * N;
#pragma unroll
  for (int i = 0; i < 4; i++) {
#pragma unroll
    for (int r = 0; r < 4; r++) {
      int m = m0 + 16 * w + quad * 4 + r;
      int n = n0 + 16 * i + ln;
      Pz[(long)m * N + n] = acc[i][r];
    }
  }
}

// rep[m][n] (bf16) = sum_z P[z][m][n] + bo[n]
__global__ __launch_bounds__(256)
void reduce_partials(const float* __restrict__ P, const void* __restrict__ bo,
                     bf16* __restrict__ rep, const int* __restrict__ dtFlag)
{
  const int fl = *dtFlag;
  long idx = (long)blockIdx.x * 256 + threadIdx.x;
  int n = idx & 255;
  float s = ldx(bo, n, fl);
#pragma unroll
  for (int z = 0; z < 8; z++) s += P[(long)z * 1048576 + idx];
  rep[idx] = __float2bfloat16(s);
}

__global__ __launch_bounds__(256)
void fixup_h1(bf16* __restrict__ h1, const void* __restrict__ label,
              const void* __restrict__ W1, const void* __restrict__ b1,
              const int* __restrict__ dtFlag)
{
  const int fl = *dtFlag;
  int idx = blockIdx.x * 256 + threadIdx.x;
  int m = idx >> 8, n = idx & 255;
  float c = tofloat(h1[idx]) + ldx(b1, n, fl);
#pragma unroll
  for (int j = 0; j < 3; j++)
    c += ldx(label, m * 3 + j, fl) * ldx(W1, (256 + j) * 256 + n, fl);
  h1[idx] = __float2bfloat16(fmaxf(c, 0.f));
}

// ------------------------------------------------------------------
// Key-side fused v6: the dd-phase A-tile (k) is wave-invariant -> all
// 4 waves were reading the SAME 16KB from LDS (64 of ~100KB/block-iter
// through the one saturated LDS port). v6 reads k fragments DIRECTLY
// from global: wave 0 misses to L2, waves 1-3 hit L1 (tile <= 32KB).
// No kS, no DMA, no vmcnt choreography. LDS keeps only pS[2] (the
// genuinely inter-wave E exchange) + 1 lgkmcnt barrier per iteration.
// pS[2] race-freedom: writer of pS[i&1] at iter i+2 passed barrier(i+1);
// every wave reaches barrier(i+1) only after its ctx(i) reads. LDS ~10.3KB.
// ------------------------------------------------------------------
__global__ __launch_bounds__(256)
void key_fused_mfma(const bf16* __restrict__ k, const bf16* __restrict__ vQ,
                    const bf16* __restrict__ projB, const float* __restrict__ diagk,
                    float* __restrict__ ksumE, bf16* __restrict__ ctxQ,
                    float* __restrict__ mpart)
{
  __shared__ alignas(16) bf16 pS[2][64 * 40];
  __shared__ float wredM[4];

  const int bz = blockIdx.x, ft = blockIdx.y, f0 = ft * 64;
  const int t = threadIdx.x;
  const int w = t >> 6, l = t & 63, quad = l >> 4, ln = l & 15;
  const int fmine = f0 + 16 * w + ln;
  const bool fv = fmine < NBF;

  const bf16* kb = k + (long)bz * NC * 256;
  const bf16* vqb = vQ + (long)bz * 16 * 256 * 32;
  const float* db = diagk + bz * NC;

  short8 pf[8];
  {
    const bf16* prow = projB + (long)fmine * 256;
#pragma unroll
    for (int kc = 0; kc < 8; kc++)
      pf[kc] = *(const short8*)(prow + kc * 32 + quad * 8);
  }

  f32x4 acc[4][4] = {};
  float ksumP = 0.f, mP = -1e30f;

  for (int it = 0; it < 16; it++) {
    const int n0 = it * 32;
    // A-fragments of k direct from global (wave-shared tile, L1-served)
    short8 ka[8][2];
#pragma unroll
    for (int kc = 0; kc < 8; kc++)
#pragma unroll
      for (int mi = 0; mi < 2; mi++)
        ka[kc][mi] = *(const short8*)(kb + (long)(n0 + 16 * mi + ln) * 256 +
                                      kc * 32 + quad * 8);
    // per-wave-distinct operands
    short8 bfr[4];
#pragma unroll
    for (int ei = 0; ei < 4; ei++) {
      int e = 64 * w + 16 * ei + ln;
      bfr[ei] = *(const short8*)(vqb + ((long)it * 256 + e) * 32 + quad * 8);
    }
    f32x4 dv0 = *(const f32x4*)(db + n0 + quad * 4);
    f32x4 dv1 = *(const f32x4*)(db + n0 + 16 + quad * 4);

    // dd phase
    f32x4 dd[2][2] = {};
    __builtin_amdgcn_s_setprio(1);
#pragma unroll
    for (int kc = 0; kc < 8; kc++) {
      const int hf = kc & 1;
#pragma unroll
      for (int mi = 0; mi < 2; mi++)
        dd[mi][hf] = __builtin_amdgcn_mfma_f32_16x16x32_bf16(ka[kc][mi], pf[kc], dd[mi][hf], 0, 0, 0);
    }
    __builtin_amdgcn_s_setprio(0);

    bf16* pcur = &pS[it & 1][0];
#pragma unroll
    for (int mi = 0; mi < 2; mi++) {
      us4 ev;
      f32x4 dvv = mi ? dv1 : dv0;
#pragma unroll
      for (int r = 0; r < 4; r++) {
        float sc = DN * (dd[mi][0][r] + dd[mi][1][r]);
        float E = fv ? __expf(fminf(sc - dvv[r], 80.f)) : 0.f;
        unsigned short u = f2bu(E);
        ksumP += bf2f(u);
        if (fv) mP = fmaxf(mP, sc);
        ev[r] = u;
      }
      *(us4*)(pcur + (16 * w + ln) * 40 + 16 * mi + quad * 4) = ev;
    }
    // single barrier per iteration: pS[it&1] visible to all waves
    asm volatile("s_waitcnt lgkmcnt(0)" ::: "memory");
    __builtin_amdgcn_s_barrier();

    // ctx phase: all f-row groups x this wave's e-slice
    __builtin_amdgcn_s_setprio(1);
#pragma unroll
    for (int fh = 0; fh < 4; fh++) {
      short8 a = *(const short8*)(pcur + (16 * fh + ln) * 40 + quad * 8);
#pragma unroll
      for (int ei = 0; ei < 4; ei++)
        acc[fh][ei] = __builtin_amdgcn_mfma_f32_16x16x32_bf16(a, bfr[ei], acc[fh][ei], 0, 0, 0);
    }
    __builtin_amdgcn_s_setprio(0);
  }
  __syncthreads();

#pragma unroll
  for (int fh = 0; fh < 4; fh++) {
    const int ft32 = 2 * ft + (fh >> 1);
    const int f32b = 16 * (fh & 1) + quad * 4;
#pragma unroll
    for (int ei = 0; ei < 4; ei++) {
      int e = 64 * w + 16 * ei + ln;
      us4 cv;
#pragma unroll
      for (int r = 0; r < 4; r++) cv[r] = f2bu(acc[fh][ei][r]);
      *(us4*)(&ctxQ[((long)(bz * FT32 + ft32) * 256 + e) * 32 + f32b]) = cv;
    }
  }

  float s = ksumP;
  s += __shfl_xor(s, 16); s += __shfl_xor(s, 32);
  if (quad == 0 && fv) ksumE[(long)bz * NBF + fmine] = s;
  float m = mP;
#pragma unroll
  for (int off = 1; off < 64; off <<= 1) m = fmaxf(m, __shfl_xor(m, off));
  if (l == 0) wredM[w] = m;
  __syncthreads();
  if (t == 0)
    mpart[bz * 23 + ft] = fmaxf(fmaxf(wredM[0], wredM[1]), fmaxf(wredM[2], wredM[3]));
}

__global__ __launch_bounds__(64)
void mk_reduce(const float* __restrict__ mpart, float* __restrict__ mk)
{
  int bz = blockIdx.x, l = threadIdx.x;
  float m = (l < 23) ? mpart[bz * 23 + l] : -1e30f;
#pragma unroll
  for (int off = 32; off > 0; off >>= 1) m = fmaxf(m, __shfl_down(m, off));
  if (l == 0) mk[bz] = m;
}

// ctxQ finalize + fused ctxsum accumulation (ctxs pre-zeroed)
__global__ __launch_bounds__(256)
void ctx_finQ(bf16* __restrict__ ctxQ, const float* __restrict__ Sv,
              const float* __restrict__ mk, float* __restrict__ ctxs)
{
  int ft32 = blockIdx.x, bz = blockIdx.y, e = threadIdx.x;
  float emk = __expf(-mk[bz]);
  float sve = EPS_ * Sv[bz * 256 + e];
  uint4* row = (uint4*)(ctxQ + ((long)(bz * FT32 + ft32) * 256 + e) * 32);
  int fbase = 32 * ft32;
  float rsum = 0.f;
#pragma unroll
  for (int cchunk = 0; cchunk < 4; cchunk++) {
    float tmp[8];
    unpack8(row[cchunk], tmp);
    unsigned short out[8];
#pragma unroll
    for (int j = 0; j < 8; j++) {
      int f = fbase + cchunk * 8 + j;
      float val = (f < NBF) ? (emk * tmp[j] + sve) : 0.f;
      rsum += val;
      out[j] = f2bu(val);
    }
    row[cchunk] = *(const uint4*)out;
  }
  atomicAdd(&ctxs[bz * 256 + e], rsum);
}

// ksum finalize, parallel: grid (64, 6); ktot via atomicAdd (pre-zeroed)
__global__ __launch_bounds__(256)
void ksum_fin(float* __restrict__ ksumE, const float* __restrict__ mk,
              float* __restrict__ ksumtot)
{
  __shared__ float red[4];
  int bz = blockIdx.x, t = threadIdx.x;
  int f = blockIdx.y * 256 + t;
  float emk = __expf(-mk[bz]);
  float s = 0.f;
  if (f < NBF) {
    float kf = emk * ksumE[(long)bz * NBF + f] + (float)NC * EPS_;
    ksumE[(long)bz * NBF + f] = kf;
    s = kf;
  }
#pragma unroll
  for (int off = 32; off > 0; off >>= 1) s += __shfl_down(s, off);
  if ((t & 63) == 0) red[t >> 6] = s;
  __syncthreads();
  if (t == 0) atomicAdd(&ksumtot[bz], red[0] + red[1] + red[2] + red[3]);
}

// ------------------------------------------------------------------
// Query-side fused v6: projS was wave-invariant (all 4 waves read the
// same 16KB/iter from LDS). v6 reads proj B-fragments directly from
// global (L1-served); projS + DMA + end barrier deleted. eS double-
// buffered (same race proof as key's pS) -> 1 barrier/iter. LDS ~12KB.
// ------------------------------------------------------------------
__global__ __launch_bounds__(256)
void q_fused_mfma(const bf16* __restrict__ q, const bf16* __restrict__ projB,
                  const float* __restrict__ diagq, const bf16* __restrict__ ctxQ,
                  const float* __restrict__ ksum, const float* __restrict__ ctxsum,
                  const float* __restrict__ ksumtot, bf16* __restrict__ merged)
{
  __shared__ alignas(16) bf16 eS[2][64 * 40];
  __shared__ float dS[64];
  __shared__ float csS[256];
  __shared__ float sS[64];
  __shared__ float mS[64];

  const int bz = blockIdx.x, nt = blockIdx.y, t = threadIdx.x;
  const int w = t >> 6, l = t & 63, quad = l >> 4, ln = l & 15;
  const int tq = bz / H_, hh = bz % H_;
  const bf16* cqb = ctxQ + (long)bz * FT32 * 256 * 32;
  const bf16* qb = q + ((long)bz * NT + nt * 64) * 256;

  // q fragments: no ft dependence -> load once, keep in 32 VGPRs
  short8 qf[8];
  {
    const bf16* qrow = qb + (long)(16 * w + ln) * 256;
#pragma unroll
    for (int kc = 0; kc < 8; kc++)
      qf[kc] = *(const short8*)(qrow + kc * 32 + quad * 8);
  }
  if (t < 64) dS[t] = diagq[(long)bz * NT + nt * 64 + t];
  csS[t] = ctxsum[bz * 256 + t];

  f32x4 acc[4][4] = {};           // [mh][ei]: rows 16mh+quad*4+r, e=16(4w+ei)+ln
  float sPart[4] = {0.f, 0.f, 0.f, 0.f};   // rows 16w+quad*4+r (wave-private)
  float mPart[4] = {0.f, 0.f, 0.f, 0.f};
  __syncthreads();

  for (int ft = 0; ft < FT32; ft++) {
    const int f0 = ft * 32;
    // per-wave-distinct ctxQ B-fragments (reused across 4 m-halves)
    short8 cfr[4];
#pragma unroll
    for (int i = 0; i < 4; i++) {
      int e = 16 * (4 * w + i) + ln;
      cfr[i] = *(const short8*)(cqb + ((long)ft * 256 + e) * 32 + quad * 8);
    }
    const float kv0 = (f0 + ln < NBF) ? ksum[(long)bz * NBF + f0 + ln] : 0.f;
    const float kv1 = (f0 + 16 + ln < NBF) ? ksum[(long)bz * NBF + f0 + 16 + ln] : 0.f;
    // proj B-fragments direct from global (wave-shared tile, L1-served)
    short8 pb0[8], pb1[8];
#pragma unroll
    for (int kc = 0; kc < 8; kc++) {
      pb0[kc] = *(const short8*)(projB + (long)(f0 + ln) * 256 + kc * 32 + quad * 8);
      pb1[kc] = *(const short8*)(projB + (long)(f0 + 16 + ln) * 256 + kc * 32 + quad * 8);
    }

    // Phase A: wave w owns rows 16w..16w+15, both f-halves
    f32x4 dd0 = {}, dd1 = {};
    __builtin_amdgcn_s_setprio(1);
#pragma unroll
    for (int kc = 0; kc < 8; kc++) {
      dd0 = __builtin_amdgcn_mfma_f32_16x16x32_bf16(qf[kc], pb0[kc], dd0, 0, 0, 0);
      dd1 = __builtin_amdgcn_mfma_f32_16x16x32_bf16(qf[kc], pb1[kc], dd1, 0, 0, 0);
    }
    __builtin_amdgcn_s_setprio(0);
    const bool fv0 = (f0 + ln) < NBF;
    const bool fv1 = (f0 + 16 + ln) < NBF;
    bf16* ecur = &eS[ft & 1][0];
#pragma unroll
    for (int r = 0; r < 4; r++) {
      float E0 = fv0 ? __expf(fminf(DN * dd0[r], 80.f)) : 0.f;
      float E1 = fv1 ? __expf(fminf(DN * dd1[r], 80.f)) : 0.f;
      bf16 h0 = __float2bfloat16(E0), h1v = __float2bfloat16(E1);
      float e0 = tofloat(h0), e1 = tofloat(h1v);
      ecur[(16 * w + quad * 4 + r) * 40 + ln] = h0;
      ecur[(16 * w + quad * 4 + r) * 40 + 16 + ln] = h1v;
      sPart[r] += e0 * kv0 + e1 * kv1;
      mPart[r] = fmaxf(mPart[r], fmaxf(e0, e1));
    }
    // single barrier per iteration: eS[ft&1] visible to all waves
    asm volatile("s_waitcnt lgkmcnt(0)" ::: "memory");
    __builtin_amdgcn_s_barrier();

    // Phase B: all 4 m-halves, 4 e-tiles each (cfr reused)
    __builtin_amdgcn_s_setprio(1);
#pragma unroll
    for (int mh = 0; mh < 4; mh++) {
      short8 a = *(const short8*)(ecur + (16 * mh + ln) * 40 + quad * 8);
#pragma unroll
      for (int i = 0; i < 4; i++)
        acc[mh][i] = __builtin_amdgcn_mfma_f32_16x16x32_bf16(a, cfr[i], acc[mh][i], 0, 0, 0);
    }
    __builtin_amdgcn_s_setprio(0);
  }
  __syncthreads();

  // wave-private row stats: reduce over 16 lanes
#pragma unroll
  for (int r = 0; r < 4; r++) {
    float s = sPart[r], m = mPart[r];
#pragma unroll
    for (int off = 1; off < 16; off <<= 1) {
      s += __shfl_xor(s, off);
      m = fmaxf(m, __shfl_xor(m, off));
    }
    if (ln == 0) {
      sS[16 * w + quad * 4 + r] = s;
      mS[16 * w + quad * 4 + r] = m;
    }
  }
  __syncthreads();

  const float ktotv = ksumtot[bz];
#pragma unroll
  for (int mh = 0; mh < 4; mh++) {
#pragma unroll
    for (int r = 0; r < 4; r++) {
      int row = 16 * mh + quad * 4 + r;
      float st = sS[row];
      float mt = fmaxf(mS[row], 1e-30f);
      float c = __expf(-dS[row]) / mt;
      float inv = 1.f / (c * st + EPS_ * ktotv);
#pragma unroll
      for (int i = 0; i < 4; i++) {
        int e = 16 * (4 * w + i) + ln;
        float val = (c * acc[mh][i][r] + EPS_ * csS[e]) * inv;
        merged[((long)tq * NT + nt * 64 + row) * 2048 + hh * 256 + e] =
            __float2bfloat16(val);
      }
    }
  }
}

// ------------------------------------------------------------------
extern "C" void kernel_launch(void* const* d_in, const int* in_sizes, int n_in,
                              void* d_out, int out_size, void* d_ws, size_t ws_size,
                              hipStream_t stream)
{
  const void* x_ctx = d_in[0];
  const void* label = d_in[1];
  const void* x_tgt = d_in[2];
  const void* W1 = d_in[3];
  const void* b1 = d_in[4];
  const void* W2 = d_in[5];
  const void* b2 = d_in[6];
  const void* W3 = d_in[7];
  const void* b3 = d_in[8];
  const void* Wk = d_in[9];
  const void* bk = d_in[10];
  const void* Wv = d_in[11];
  const void* bv = d_in[12];
  const void* Wq = d_in[13];
  const void* bq = d_in[14];
  const void* Wo = d_in[15];
  const void* bo = d_in[16];
  const void* Wmu = d_in[17];
  const void* bmu = d_in[18];
  const void* proj = d_in[19];

  // Arena (floats), peak ~84 MB
  float* W = (float*)d_ws;
  const long F0 = 0, F1 = 4194304, F2 = 8388608;
  const long CTXQ_F = (long)64 * FT32 * 256 * 32 / 2;
  const long F3 = F2 + CTXQ_F;
  bf16* kB = (bf16*)(W + F0);
  bf16* qB = (bf16*)(W + F0);
  bf16* rep = (bf16*)(W + F0);
  bf16* vQ = (bf16*)(W + F1);
  bf16* merged = (bf16*)(W + F1);
  bf16* h1 = (bf16*)(W + F2);
  bf16* h2 = (bf16*)(W + F2 + 524288);
  bf16* cf = (bf16*)(W + F2 + 1048576);
  bf16* ctxQ = (bf16*)(W + F2);
  float* woP = W + F2;
  long o = F3;
  auto alloc = [&](long n) { float* p = W + o; o += n; return p; };
  float* zbase = W + o;
  float* dgk = alloc(32768);
  float* dgq = alloc(32768);
  float* Sv = alloc(64 * 256);
  float* ctxs = alloc(64 * 256);
  float* ktot = alloc(64);
  alloc(192);
  float* ksumE = alloc((long)64 * NBF);
  float* mpart = alloc(64 * 23);
  float* mk = alloc(64);
  int* dtFlag = (int*)alloc(64);
  bf16* projB = (bf16*)alloc((long)FT32 * 32 * 256 / 2);
  (void)ws_size; (void)in_sizes; (void)n_in; (void)out_size;

  const dim3 B(256);
  detect_dtype<<<1, B, 0, stream>>>(x_ctx, dtFlag);
  conv_proj<<<FT32 * 32, B, 0, stream>>>(proj, projB, dtFlag);
  init_zero<<<385, B, 0, stream>>>(zbase);
  // 1. task-encoder MLP
  gemm_mfma32<<<dim3(4, 128), B, 0, stream>>>(
      x_ctx, 2, W1, nullptr, h1, 1, 0, dtFlag, 4096, 256, 256);
  fixup_h1<<<4096, B, 0, stream>>>(h1, label, W1, b1, dtFlag);
  gemm_mfma32<<<dim3(4, 128), B, 0, stream>>>(
      h1, 1, W2, b2, h2, 1, 2, dtFlag, 4096, 256, 256);
  gemm_mfma32<<<dim3(4, 128), B, 0, stream>>>(
      h2, 1, W3, b3, cf, 1, 2, dtFlag, 4096, 256, 256);
  // 2. k projection (fused diag), v projection (tiled -> vQ, fused Sv)
  gemm_mfma<<<dim3(4, 8, 64), B, 0, stream>>>(
      x_ctx, 2, Wk, bk, kB, 1, 1, 0, 0, dtFlag, dgk, nullptr, 512, 256, 256, (long)512 * 256, H_, 65536L, H_, 256L);
  gemm_mfma<<<dim3(4, 8, 64), B, 0, stream>>>(
      cf, 1, Wv, bv, vQ, 1, 1, 0, 2, dtFlag, nullptr, Sv, 512, 256, 256, (long)512 * 256, H_, 65536L, H_, 256L);
  // 3. key side
  key_fused_mfma<<<dim3(64, 23), B, 0, stream>>>(kB, vQ, projB, dgk, ksumE, ctxQ, mpart);
  mk_reduce<<<64, 64, 0, stream>>>(mpart, mk);
  ctx_finQ<<<dim3(FT32, 64), B, 0, stream>>>(ctxQ, Sv, mk, ctxs);
  ksum_fin<<<dim3(64, 6), B, 0, stream>>>(ksumE, mk, ktot);
  // 4. q projection (fused diag)
  gemm_mfma<<<dim3(4, 8, 64), B, 0, stream>>>(
      x_tgt, 2, Wq, bq, qB, 1, 1, 0, 0, dtFlag, dgq, nullptr, 512, 256, 256, (long)512 * 256, H_, 65536L, H_, 256L);
  // 5. query side (64-row blocks) -> merged [t][n][h][e]
  q_fused_mfma<<<dim3(64, 8), B, 0, stream>>>(qB, projB, dgq, ctxQ, ksumE, ctxs, ktot, merged);
  // 6. Wo split-K x8 -> fp32 partials, reduce, Wmu
  gemm_wo_splitk<<<dim3(4, 64, 8), B, 0, stream>>>(merged, Wo, woP, dtFlag, 4096, 256, 2048);
  reduce_partials<<<4096, B, 0, stream>>>(woP, bo, rep, dtFlag);
  gemm_mfma32<<<dim3(4, 128), B, 0, stream>>>(
      rep, 1, Wmu, bmu, d_out, 2, 1, dtFlag, 4096, 256, 256);
}

// Round 5
// 452.264 us; speedup vs baseline: 1.6424x; 1.6424x over previous
//
#include <hip/hip_runtime.h>
#include <hip/hip_bf16.h>

typedef __hip_bfloat16 bf16;
typedef __attribute__((ext_vector_type(8))) short short8;
typedef __attribute__((ext_vector_type(4))) float f32x4;
typedef __attribute__((ext_vector_type(4))) unsigned short us4;
#define DEV __device__ __forceinline__

static constexpr int T_ = 8, NC = 512, NT = 512, D_ = 256, H_ = 8, NBF = 1419;
static constexpr int FT32 = 46;             // 46 f-tiles of 32 (padded 1472)
static constexpr float EPS_ = 1e-4f;
static constexpr float DN = 0.25f;          // D^-0.25
static constexpr float DIAG_SC = 0.03125f;  // 0.5 * DN^2

DEV float bf2f(unsigned short u) { return __uint_as_float(((unsigned)u) << 16); }
DEV float tofloat(bf16 x) { return __bfloat162float(x); }
DEV unsigned short f2bu(float x) { bf16 h = __float2bfloat16(x); return *(unsigned short*)&h; }

DEV float ldx(const void* p, long i, int isb) {
  if (isb) return bf2f(((const unsigned short*)p)[i]);
  return ((const float*)p)[i];
}
DEV void stx(void* p, long i, float v, int isb) {
  if (isb) ((bf16*)p)[i] = __float2bfloat16(v);
  else     ((float*)p)[i] = v;
}
DEV void unpack8(uint4 u, float* dst) {
  unsigned w[4] = {u.x, u.y, u.z, u.w};
#pragma unroll
  for (int i = 0; i < 4; i++) {
    dst[2 * i + 0] = __uint_as_float((w[i] & 0xffffu) << 16);
    dst[2 * i + 1] = __uint_as_float(w[i] & 0xffff0000u);
  }
}

// async global->LDS 16B (wave-uniform LDS base + lane*16; global addr per-lane)
DEV void async_copy16(const void* g, void* lds) {
  __builtin_amdgcn_global_load_lds(
      (const __attribute__((address_space(1))) unsigned int*)g,
      (__attribute__((address_space(3))) unsigned int*)lds, 16, 0, 0);
}

// ------------------------------------------------------------------
// dtype probe (1 = bf16 inputs, 0 = fp32)
// ------------------------------------------------------------------
__global__ __launch_bounds__(256)
void detect_dtype(const void* __restrict__ x, int* __restrict__ flag)
{
  __shared__ int bad;
  if (threadIdx.x == 0) bad = 0;
  __syncthreads();
  int mybad = 0;
  for (int j = 0; j < 16; j++) {
    long i = 2L * (threadIdx.x + 256L * j);
    unsigned short u = ((const unsigned short*)x)[i];
    int e = (u >> 7) & 0xff, mant = u & 0x7f;
    bool b = (e == 0xff) || (e >= 141) || (e <= 93 && !(e == 0 && mant == 0));
    mybad += b ? 1 : 0;
  }
  atomicAdd(&bad, mybad);
  __syncthreads();
  if (threadIdx.x == 0) *flag = (bad > 1024) ? 0 : 1;
}

// proj -> bf16 [FT32*32][256], zero rows past NBF
__global__ __launch_bounds__(256)
void conv_proj(const void* __restrict__ proj, bf16* __restrict__ projB,
               const int* __restrict__ dtFlag)
{
  const int fl = *dtFlag;
  int f = blockIdx.x, t = threadIdx.x;
  float v = (f < NBF) ? ldx(proj, (long)f * 256 + t, fl) : 0.f;
  projB[(long)f * 256 + t] = __float2bfloat16(v);
}

// ------------------------------------------------------------------
// Weight pre-transpose: W[k][n] -> WT[n][k] bf16, so GEMM B-staging
// becomes a vector copy (identical to A-staging) instead of 8 scalar
// ds_write_b16 per thread per K-step. Wo additionally folds the merged
// k-permutation krow = ((k&255)<<3)|(k>>8). One dispatch, grid (64,8,25):
// z 0..7 Wk heads, 8..15 Wv, 16..23 Wq, 24 Wo (kt 0..63).
// ------------------------------------------------------------------
__global__ __launch_bounds__(256)
void conv_wT(const void* __restrict__ Wk, const void* __restrict__ Wv,
             const void* __restrict__ Wq, const void* __restrict__ Wo,
             bf16* __restrict__ WkT, bf16* __restrict__ WvT,
             bf16* __restrict__ WqT, bf16* __restrict__ WoT,
             const int* __restrict__ dtFlag)
{
  __shared__ float tile[32][33];
  const int fl = *dtFlag;
  const int kt = blockIdx.x, nt = blockIdx.y, z = blockIdx.z, t = threadIdx.x;
  const void* in; bf16* out; int K; int perm = 0; long off = 0;
  if (z < 8)       { in = Wk; out = WkT; K = 256; off = (long)z * 65536; }
  else if (z < 16) { in = Wv; out = WvT; K = 256; off = (long)(z - 8) * 65536; }
  else if (z < 24) { in = Wq; out = WqT; K = 256; off = (long)(z - 16) * 65536; }
  else             { in = Wo; out = WoT; K = 2048; perm = 1; }
  if (K == 256 && kt >= 8) return;
  const int k0 = kt * 32, n0 = nt * 32;
  const int row = t >> 3, cb = (t & 7) * 4;
  {
    int kk = k0 + row;
    int krow = perm ? (((kk & 255) << 3) | (kk >> 8)) : kk;
#pragma unroll
    for (int j = 0; j < 4; j++)
      tile[row][cb + j] = ldx(in, off + (long)krow * 256 + n0 + cb + j, fl);
  }
  __syncthreads();
  us4 o;
#pragma unroll
  for (int j = 0; j < 4; j++) o[j] = f2bu(tile[cb + j][row]);
  *(us4*)(out + off + (long)(n0 + row) * K + k0 + cb) = o;
}

// zero the atomic-target region
__global__ __launch_bounds__(256)
void init_zero(float* __restrict__ p)
{
  p[blockIdx.x * 256 + threadIdx.x] = 0.f;
}

// ------------------------------------------------------------------
// MFMA GEMM, 64x64 tile. B is PRE-TRANSPOSED bf16 [N][K] (conv_wT) ->
// staging is a vector copy identical to the A path. cT=0: natural.
// cT=2: MFMA-tiled store (vQ) with optional fused column-sum svOut.
// diagOut!=null: atomicAdd per-row DIAG_SC*sum_n(c^2).
// ------------------------------------------------------------------
__global__ __launch_bounds__(256)
void gemm_mfma(const void* __restrict__ A, int aMode,
               const bf16* __restrict__ BT, const void* __restrict__ bias,
               void* __restrict__ C, int cMode, int epi, int cT,
               const int* __restrict__ dtFlag, float* __restrict__ diagOut,
               float* __restrict__ svOut,
               int M, int N, int K, long sA, int divA, long sB, int modB, long sBias)
{
  __shared__ bf16 As[64 * 40];
  __shared__ bf16 Ws[64 * 40];
  const int fl = *dtFlag;
  const int aB = (aMode == 2) ? fl : aMode;
  const int cB = (cMode == 2) ? fl : cMode;
  const int t = threadIdx.x;
  const int bz = blockIdx.z;
  const long aOff = (long)(bz / divA) * sA;
  const long bOff = (long)(bz % modB) * sB;
  const long biasOff = (long)(bz % modB) * sBias;
  const long cOff = (long)bz * (long)M * N;
  const int m0 = blockIdx.y * 64, n0 = blockIdx.x * 64;
  const int w = t >> 6, l = t & 63, quad = l >> 4, ln = l & 15;
  const int am = t >> 2, ak8 = (t & 3) * 8;
  f32x4 acc[4] = {};

  for (int k0 = 0; k0 < K; k0 += 32) {
    if (aB == 1) {
      const uint4* src = (const uint4*)((const bf16*)A + aOff + (long)(m0 + am) * K + k0 + ak8);
      *(uint4*)(&As[am * 40 + ak8]) = *src;
    } else {
      const float* src = (const float*)A + aOff + (long)(m0 + am) * K + k0 + ak8;
      unsigned short tmp[8];
#pragma unroll
      for (int i = 0; i < 8; i++) tmp[i] = f2bu(src[i]);
      *(uint4*)(&As[am * 40 + ak8]) = *(const uint4*)tmp;
    }
    {
      // B staging: vector copy from BT[n][k] (pre-transposed, always bf16)
      const uint4* src = (const uint4*)(BT + bOff + (long)(n0 + am) * K + k0 + ak8);
      *(uint4*)(&Ws[am * 40 + ak8]) = *src;
    }
    __syncthreads();
    short8 a = *(const short8*)(&As[(16 * w + ln) * 40 + quad * 8]);
#pragma unroll
    for (int i = 0; i < 4; i++) {
      short8 b = *(const short8*)(&Ws[(16 * i + ln) * 40 + quad * 8]);
      acc[i] = __builtin_amdgcn_mfma_f32_16x16x32_bf16(a, b, acc[i], 0, 0, 0);
    }
    __syncthreads();
  }

  float s2[4] = {0.f, 0.f, 0.f, 0.f};
  if (cT == 2) {
    const int mm = m0 + 16 * w + quad * 4;
    const int tile = mm >> 5, off = mm & 31;
#pragma unroll
    for (int i = 0; i < 4; i++) {
      int n = n0 + 16 * i + ln;
      us4 cv;
      float colsum = 0.f;
#pragma unroll
      for (int r = 0; r < 4; r++) {
        float c = acc[i][r];
        if (epi >= 1) c += ldx(bias, biasOff + n, fl);
        if (epi == 2) c = fmaxf(c, 0.f);
        colsum += c;
        cv[r] = f2bu(c);
      }
      *(us4*)((bf16*)C + cOff + ((long)tile * N + n) * 32 + off) = cv;
      if (svOut) {
        colsum += __shfl_xor(colsum, 16);
        colsum += __shfl_xor(colsum, 32);
        if (quad == 0) atomicAdd(&svOut[(long)bz * N + n], colsum);
      }
    }
  } else {
#pragma unroll
    for (int i = 0; i < 4; i++) {
#pragma unroll
      for (int r = 0; r < 4; r++) {
        int m = m0 + 16 * w + quad * 4 + r;
        int n = n0 + 16 * i + ln;
        float c = acc[i][r];
        if (epi >= 1) c += ldx(bias, biasOff + n, fl);
        if (epi == 2) c = fmaxf(c, 0.f);
        s2[r] += c * c;
        stx(C, cOff + (long)m * N + n, c, cB);
      }
    }
  }
  if (diagOut) {
#pragma unroll
    for (int r = 0; r < 4; r++) {
      float s = s2[r];
      s += __shfl_xor(s, 1); s += __shfl_xor(s, 2);
      s += __shfl_xor(s, 4); s += __shfl_xor(s, 8);
      if (ln == 0)
        atomicAdd(&diagOut[(long)bz * M + m0 + 16 * w + quad * 4 + r], DIAG_SC * s);
    }
  }
}

// ------------------------------------------------------------------
// MFMA GEMM, 32x64 tile (unchanged; used by the small MLP/Wmu GEMMs).
// ------------------------------------------------------------------
__global__ __launch_bounds__(256)
void gemm_mfma32(const void* __restrict__ A, int aMode,
                 const void* __restrict__ B, const void* __restrict__ bias,
                 void* __restrict__ C, int cMode, int epi,
                 const int* __restrict__ dtFlag, int M, int N, int K)
{
  __shared__ bf16 As[32 * 40];
  __shared__ bf16 Ws[64 * 40];
  const int fl = *dtFlag;
  const int aB = (aMode == 2) ? fl : aMode;
  const int cB = (cMode == 2) ? fl : cMode;
  const int t = threadIdx.x;
  const int m0 = blockIdx.y * 32, n0 = blockIdx.x * 64;
  const int w = t >> 6, l = t & 63, quad = l >> 4, ln = l & 15;
  const int am = t >> 3, ak4 = (t & 7) * 4;
  const int wk = t & 31, wg = t >> 5;
  const int mi = w & 1, nh = w >> 1;
  f32x4 acc[2] = {};

  for (int k0 = 0; k0 < K; k0 += 32) {
    if (aB == 1) {
      const uint2* src = (const uint2*)((const bf16*)A + (long)(m0 + am) * K + k0 + ak4);
      *(uint2*)(&As[am * 40 + ak4]) = *src;
    } else {
      const float* src = (const float*)A + (long)(m0 + am) * K + k0 + ak4;
      unsigned short tmp[4];
#pragma unroll
      for (int i = 0; i < 4; i++) tmp[i] = f2bu(src[i]);
      *(uint2*)(&As[am * 40 + ak4]) = *(const uint2*)tmp;
    }
    {
      int k = k0 + wk;
      if (fl == 1) {
        uint4 u = *(const uint4*)((const bf16*)B + (long)k * N + n0 + wg * 8);
        const unsigned short* us = (const unsigned short*)&u;
#pragma unroll
        for (int j = 0; j < 8; j++) Ws[(wg * 8 + j) * 40 + wk] = *(const bf16*)&us[j];
      } else {
        const float* src = (const float*)B + (long)k * N + n0 + wg * 8;
#pragma unroll
        for (int j = 0; j < 8; j++) {
          unsigned short u = f2bu(src[j]);
          Ws[(wg * 8 + j) * 40 + wk] = *(const bf16*)&u;
        }
      }
    }
    __syncthreads();
    short8 a = *(const short8*)(&As[(16 * mi + ln) * 40 + quad * 8]);
#pragma unroll
    for (int j = 0; j < 2; j++) {
      short8 b = *(const short8*)(&Ws[(16 * (2 * nh + j) + ln) * 40 + quad * 8]);
      acc[j] = __builtin_amdgcn_mfma_f32_16x16x32_bf16(a, b, acc[j], 0, 0, 0);
    }
    __syncthreads();
  }

#pragma unroll
  for (int j = 0; j < 2; j++) {
#pragma unroll
    for (int r = 0; r < 4; r++) {
      int m = m0 + 16 * mi + quad * 4 + r;
      int n = n0 + 16 * (2 * nh + j) + ln;
      float c = acc[j][r];
      if (epi >= 1) c += ldx(bias, n, fl);
      if (epi == 2) c = fmaxf(c, 0.f);
      stx(C, (long)m * N + n, c, cB);
    }
  }
}

// ------------------------------------------------------------------
// Wo GEMM, split-K x8. B = WoT pre-transposed [256][2048] bf16 with the
// merged-k permutation folded in -> vector B staging, straight indexing.
// ------------------------------------------------------------------
__global__ __launch_bounds__(256)
void gemm_wo_splitk(const bf16* __restrict__ A, const bf16* __restrict__ BT,
                    float* __restrict__ P, const int* __restrict__ dtFlag,
                    int M, int N, int K)
{
  __shared__ bf16 As[64 * 40];
  __shared__ bf16 Ws[64 * 40];
  const int t = threadIdx.x;
  const int z = blockIdx.z;
  const int m0 = blockIdx.y * 64, n0 = blockIdx.x * 64;
  const int w = t >> 6, l = t & 63, quad = l >> 4, ln = l & 15;
  const int am = t >> 2, ak8 = (t & 3) * 8;
  f32x4 acc[4] = {};
  const int kbase = z * 256;
  (void)dtFlag;

  for (int k0 = kbase; k0 < kbase + 256; k0 += 32) {
    {
      const uint4* src = (const uint4*)(A + (long)(m0 + am) * K + k0 + ak8);
      *(uint4*)(&As[am * 40 + ak8]) = *src;
    }
    {
      const uint4* src = (const uint4*)(BT + (long)(n0 + am) * K + k0 + ak8);
      *(uint4*)(&Ws[am * 40 + ak8]) = *src;
    }
    __syncthreads();
    short8 a = *(const short8*)(&As[(16 * w + ln) * 40 + quad * 8]);
#pragma unroll
    for (int i = 0; i < 4; i++) {
      short8 b = *(const short8*)(&Ws[(16 * i + ln) * 40 + quad * 8]);
      acc[i] = __builtin_amdgcn_mfma_f32_16x16x32_bf16(a, b, acc[i], 0, 0, 0);
    }
    __syncthreads();
  }

  float* Pz = P + (long)z * M * N;
#pragma unroll
  for (int i = 0; i < 4; i++) {
#pragma unroll
    for (int r = 0; r < 4; r++) {
      int m = m0 + 16 * w + quad * 4 + r;
      int n = n0 + 16 * i + ln;
      Pz[(long)m * N + n] = acc[i][r];
    }
  }
}

// rep[m][n] (bf16) = sum_z P[z][m][n] + bo[n]
__global__ __launch_bounds__(256)
void reduce_partials(const float* __restrict__ P, const void* __restrict__ bo,
                     bf16* __restrict__ rep, const int* __restrict__ dtFlag)
{
  const int fl = *dtFlag;
  long idx = (long)blockIdx.x * 256 + threadIdx.x;
  int n = idx & 255;
  float s = ldx(bo, n, fl);
#pragma unroll
  for (int z = 0; z < 8; z++) s += P[(long)z * 1048576 + idx];
  rep[idx] = __float2bfloat16(s);
}

__global__ __launch_bounds__(256)
void fixup_h1(bf16* __restrict__ h1, const void* __restrict__ label,
              const void* __restrict__ W1, const void* __restrict__ b1,
              const int* __restrict__ dtFlag)
{
  const int fl = *dtFlag;
  int idx = blockIdx.x * 256 + threadIdx.x;
  int m = idx >> 8, n = idx & 255;
  float c = tofloat(h1[idx]) + ldx(b1, n, fl);
#pragma unroll
  for (int j = 0; j < 3; j++)
    c += ldx(label, m * 3 + j, fl) * ldx(W1, (256 + j) * 256 + n, fl);
  h1[idx] = __float2bfloat16(fmaxf(c, 0.f));
}

// ------------------------------------------------------------------
// Key-side fused v5 (best measured, 87.7us): kS triple-buffered via
// global_load_lds with pre-swizzled source, one barrier per iteration
// with counted vmcnt(4), pS double-buffered, setprio on MFMA clusters.
// ------------------------------------------------------------------
__global__ __launch_bounds__(256)
void key_fused_mfma(const bf16* __restrict__ k, const bf16* __restrict__ vQ,
                    const bf16* __restrict__ projB, const float* __restrict__ diagk,
                    float* __restrict__ ksumE, bf16* __restrict__ ctxQ,
                    float* __restrict__ mpart)
{
  __shared__ alignas(16) bf16 kS[3][32 * 256];
  __shared__ alignas(16) bf16 pS[2][64 * 40];
  __shared__ float wredM[4];

  const int bz = blockIdx.x, ft = blockIdx.y, f0 = ft * 64;
  const int t = threadIdx.x;
  const int w = t >> 6, l = t & 63, quad = l >> 4, ln = l & 15;
  const int fmine = f0 + 16 * w + ln;
  const bool fv = fmine < NBF;

  const bf16* kb = k + (long)bz * NC * 256;
  const bf16* vqb = vQ + (long)bz * 16 * 256 * 32;
  const float* db = diagk + bz * NC;

  auto stage = [&](int buf, int n0) {
#pragma unroll
    for (int j = 0; j < 4; j++) {
      int row = w * 8 + j * 2 + (l >> 5);
      int cc = (l & 31) ^ ((2 * j + (l >> 5)) & 7);   // = (l&31) ^ (row&7)
      async_copy16(kb + (long)(n0 + row) * 256 + cc * 8,
                   &kS[buf][w * 2048 + j * 512]);
    }
  };
  stage(0, 0);
  stage(1, 32);

  short8 pf[8];
  {
    const bf16* prow = projB + (long)fmine * 256;
#pragma unroll
    for (int kc = 0; kc < 8; kc++)
      pf[kc] = *(const short8*)(prow + kc * 32 + quad * 8);
  }

  f32x4 acc[4][4] = {};
  float ksumP = 0.f, mP = -1e30f;

  __syncthreads();   // full drain once: kS[0], kS[1] + pf ready

  int cur = 0;       // buffer holding tile `it`
  for (int it = 0; it < 16; it++) {
    const int n0 = it * 32;
    short8 bfr[4];
#pragma unroll
    for (int ei = 0; ei < 4; ei++) {
      int e = 64 * w + 16 * ei + ln;
      bfr[ei] = *(const short8*)(vqb + ((long)it * 256 + e) * 32 + quad * 8);
    }
    f32x4 dv0 = *(const f32x4*)(db + n0 + quad * 4);
    f32x4 dv1 = *(const f32x4*)(db + n0 + 16 + quad * 4);
    __builtin_amdgcn_sched_barrier(0);
    if (it + 2 < 16) {
      int nb = cur + 2; if (nb >= 3) nb -= 3;
      stage(nb, n0 + 64);
    }
    __builtin_amdgcn_sched_barrier(0);

    const bf16* kcur = &kS[cur][0];
    f32x4 dd[2][2] = {};
    __builtin_amdgcn_s_setprio(1);
#pragma unroll
    for (int kc = 0; kc < 8; kc++) {
      const int hf = kc & 1;
#pragma unroll
      for (int mi = 0; mi < 2; mi++) {
        short8 a = *(const short8*)(kcur + (16 * mi + ln) * 256 +
                                    (((kc * 4 + quad) ^ (ln & 7)) << 3));
        dd[mi][hf] = __builtin_amdgcn_mfma_f32_16x16x32_bf16(a, pf[kc], dd[mi][hf], 0, 0, 0);
      }
    }
    __builtin_amdgcn_s_setprio(0);
    bf16* pcur = &pS[it & 1][0];
#pragma unroll
    for (int mi = 0; mi < 2; mi++) {
      us4 ev;
      f32x4 dvv = mi ? dv1 : dv0;
#pragma unroll
      for (int r = 0; r < 4; r++) {
        float sc = DN * (dd[mi][0][r] + dd[mi][1][r]);
        float E = fv ? __expf(fminf(sc - dvv[r], 80.f)) : 0.f;
        unsigned short u = f2bu(E);
        ksumP += bf2f(u);
        if (fv) mP = fmaxf(mP, sc);
        ev[r] = u;
      }
      *(us4*)(pcur + (16 * w + ln) * 40 + 16 * mi + quad * 4) = ev;
    }
    asm volatile("s_waitcnt vmcnt(4) lgkmcnt(0)" ::: "memory");
    __builtin_amdgcn_s_barrier();
    __builtin_amdgcn_sched_barrier(0);

    __builtin_amdgcn_s_setprio(1);
#pragma unroll
    for (int fh = 0; fh < 4; fh++) {
      short8 a = *(const short8*)(pcur + (16 * fh + ln) * 40 + quad * 8);
#pragma unroll
      for (int ei = 0; ei < 4; ei++)
        acc[fh][ei] = __builtin_amdgcn_mfma_f32_16x16x32_bf16(a, bfr[ei], acc[fh][ei], 0, 0, 0);
    }
    __builtin_amdgcn_s_setprio(0);
    cur = (cur == 2) ? 0 : cur + 1;
  }
  __syncthreads();

#pragma unroll
  for (int fh = 0; fh < 4; fh++) {
    const int ft32 = 2 * ft + (fh >> 1);
    const int f32b = 16 * (fh & 1) + quad * 4;
#pragma unroll
    for (int ei = 0; ei < 4; ei++) {
      int e = 64 * w + 16 * ei + ln;
      us4 cv;
#pragma unroll
      for (int r = 0; r < 4; r++) cv[r] = f2bu(acc[fh][ei][r]);
      *(us4*)(&ctxQ[((long)(bz * FT32 + ft32) * 256 + e) * 32 + f32b]) = cv;
    }
  }

  float s = ksumP;
  s += __shfl_xor(s, 16); s += __shfl_xor(s, 32);
  if (quad == 0 && fv) ksumE[(long)bz * NBF + fmine] = s;
  float m = mP;
#pragma unroll
  for (int off = 1; off < 64; off <<= 1) m = fmaxf(m, __shfl_xor(m, off));
  if (l == 0) wredM[w] = m;
  __syncthreads();
  if (t == 0)
    mpart[bz * 23 + ft] = fmaxf(fmaxf(wredM[0], wredM[1]), fmaxf(wredM[2], wredM[3]));
}

__global__ __launch_bounds__(64)
void mk_reduce(const float* __restrict__ mpart, float* __restrict__ mk)
{
  int bz = blockIdx.x, l = threadIdx.x;
  float m = (l < 23) ? mpart[bz * 23 + l] : -1e30f;
#pragma unroll
  for (int off = 32; off > 0; off >>= 1) m = fmaxf(m, __shfl_down(m, off));
  if (l == 0) mk[bz] = m;
}

// ctxQ finalize + fused ctxsum accumulation (ctxs pre-zeroed)
__global__ __launch_bounds__(256)
void ctx_finQ(bf16* __restrict__ ctxQ, const float* __restrict__ Sv,
              const float* __restrict__ mk, float* __restrict__ ctxs)
{
  int ft32 = blockIdx.x, bz = blockIdx.y, e = threadIdx.x;
  float emk = __expf(-mk[bz]);
  float sve = EPS_ * Sv[bz * 256 + e];
  uint4* row = (uint4*)(ctxQ + ((long)(bz * FT32 + ft32) * 256 + e) * 32);
  int fbase = 32 * ft32;
  float rsum = 0.f;
#pragma unroll
  for (int cchunk = 0; cchunk < 4; cchunk++) {
    float tmp[8];
    unpack8(row[cchunk], tmp);
    unsigned short out[8];
#pragma unroll
    for (int j = 0; j < 8; j++) {
      int f = fbase + cchunk * 8 + j;
      float val = (f < NBF) ? (emk * tmp[j] + sve) : 0.f;
      rsum += val;
      out[j] = f2bu(val);
    }
    row[cchunk] = *(const uint4*)out;
  }
  atomicAdd(&ctxs[bz * 256 + e], rsum);
}

// ksum finalize, parallel: grid (64, 6); ktot via atomicAdd (pre-zeroed)
__global__ __launch_bounds__(256)
void ksum_fin(float* __restrict__ ksumE, const float* __restrict__ mk,
              float* __restrict__ ksumtot)
{
  __shared__ float red[4];
  int bz = blockIdx.x, t = threadIdx.x;
  int f = blockIdx.y * 256 + t;
  float emk = __expf(-mk[bz]);
  float s = 0.f;
  if (f < NBF) {
    float kf = emk * ksumE[(long)bz * NBF + f] + (float)NC * EPS_;
    ksumE[(long)bz * NBF + f] = kf;
    s = kf;
  }
#pragma unroll
  for (int off = 32; off > 0; off >>= 1) s += __shfl_down(s, off);
  if ((t & 63) == 0) red[t >> 6] = s;
  __syncthreads();
  if (t == 0) atomicAdd(&ksumtot[bz], red[0] + red[1] + red[2] + red[3]);
}

// ------------------------------------------------------------------
// Query-side fused v5 (best measured): q in registers, projS double-
// buffered via swizzled-source global_load_lds, counted waits.
// ------------------------------------------------------------------
__global__ __launch_bounds__(256)
void q_fused_mfma(const bf16* __restrict__ q, const bf16* __restrict__ projB,
                  const float* __restrict__ diagq, const bf16* __restrict__ ctxQ,
                  const float* __restrict__ ksum, const float* __restrict__ ctxsum,
                  const float* __restrict__ ksumtot, bf16* __restrict__ merged)
{
  __shared__ alignas(16) bf16 projS[2][32 * 256];
  __shared__ alignas(16) bf16 eS[64 * 40];
  __shared__ float dS[64];
  __shared__ float csS[256];
  __shared__ float sS[64];
  __shared__ float mS[64];

  const int bz = blockIdx.x, nt = blockIdx.y, t = threadIdx.x;
  const int w = t >> 6, l = t & 63, quad = l >> 4, ln = l & 15;
  const int tq = bz / H_, hh = bz % H_;
  const bf16* cqb = ctxQ + (long)bz * FT32 * 256 * 32;
  const bf16* qb = q + ((long)bz * NT + nt * 64) * 256;

  auto stage_proj = [&](int buf, int f0n) {
#pragma unroll
    for (int j = 0; j < 4; j++) {
      int row = 8 * w + 2 * j + (l >> 5);
      int cc = (l & 31) ^ (row & 7);
      async_copy16(projB + (long)(f0n + row) * 256 + cc * 8,
                   &projS[buf][(8 * w + 2 * j) * 256]);
    }
  };
  stage_proj(0, 0);

  // q fragments: no ft dependence -> load once, keep in 32 VGPRs
  short8 qf[8];
  {
    const bf16* qrow = qb + (long)(16 * w + ln) * 256;
#pragma unroll
    for (int kc = 0; kc < 8; kc++)
      qf[kc] = *(const short8*)(qrow + kc * 32 + quad * 8);
  }
  if (t < 64) dS[t] = diagq[(long)bz * NT + nt * 64 + t];
  csS[t] = ctxsum[bz * 256 + t];

  f32x4 acc[4][4] = {};           // [mh][ei]: rows 16mh+quad*4+r, e=16(4w+ei)+ln
  float sPart[4] = {0.f, 0.f, 0.f, 0.f};   // rows 16w+quad*4+r (wave-private)
  float mPart[4] = {0.f, 0.f, 0.f, 0.f};
  __syncthreads();   // full drain: projS[0] + dS/csS ready

  for (int ft = 0; ft < FT32; ft++) {
    const int f0 = ft * 32;
    const bf16* pcur = &projS[ft & 1][0];
    short8 cfr[4];
#pragma unroll
    for (int i = 0; i < 4; i++) {
      int e = 16 * (4 * w + i) + ln;
      cfr[i] = *(const short8*)(cqb + ((long)ft * 256 + e) * 32 + quad * 8);
    }
    const float kv0 = (f0 + ln < NBF) ? ksum[(long)bz * NBF + f0 + ln] : 0.f;
    const float kv1 = (f0 + 16 + ln < NBF) ? ksum[(long)bz * NBF + f0 + 16 + ln] : 0.f;
    if (ft + 1 < FT32) stage_proj((ft + 1) & 1, f0 + 32);

    // Phase A: wave w owns rows 16w..16w+15, both f-halves
    f32x4 dd0 = {}, dd1 = {};
#pragma unroll
    for (int kc = 0; kc < 8; kc++) {
      const int co = ((kc * 4 + quad) ^ (ln & 7)) << 3;
      short8 b0 = *(const short8*)(pcur + ln * 256 + co);
      dd0 = __builtin_amdgcn_mfma_f32_16x16x32_bf16(qf[kc], b0, dd0, 0, 0, 0);
      short8 b1 = *(const short8*)(pcur + (16 + ln) * 256 + co);
      dd1 = __builtin_amdgcn_mfma_f32_16x16x32_bf16(qf[kc], b1, dd1, 0, 0, 0);
    }
    const bool fv0 = (f0 + ln) < NBF;
    const bool fv1 = (f0 + 16 + ln) < NBF;
#pragma unroll
    for (int r = 0; r < 4; r++) {
      float E0 = fv0 ? __expf(fminf(DN * dd0[r], 80.f)) : 0.f;
      float E1 = fv1 ? __expf(fminf(DN * dd1[r], 80.f)) : 0.f;
      bf16 h0 = __float2bfloat16(E0), h1v = __float2bfloat16(E1);
      float e0 = tofloat(h0), e1 = tofloat(h1v);
      eS[(16 * w + quad * 4 + r) * 40 + ln] = h0;
      eS[(16 * w + quad * 4 + r) * 40 + 16 + ln] = h1v;
      sPart[r] += e0 * kv0 + e1 * kv1;
      mPart[r] = fmaxf(mPart[r], fmaxf(e0, e1));
    }
    // mid barrier: eS writes visible; proj prefetch stays in flight
    asm volatile("s_waitcnt lgkmcnt(0)" ::: "memory");
    __builtin_amdgcn_s_barrier();
    __builtin_amdgcn_sched_barrier(0);

    // Phase B: all 4 m-halves, 4 e-tiles each (cfr reused)
#pragma unroll
    for (int mh = 0; mh < 4; mh++) {
      short8 a = *(const short8*)(&eS[(16 * mh + ln) * 40 + quad * 8]);
#pragma unroll
      for (int i = 0; i < 4; i++)
        acc[mh][i] = __builtin_amdgcn_mfma_f32_16x16x32_bf16(a, cfr[i], acc[mh][i], 0, 0, 0);
    }
    // end barrier: next projS buffer complete (vmcnt covers global_load_lds)
    asm volatile("s_waitcnt vmcnt(0) lgkmcnt(0)" ::: "memory");
    __builtin_amdgcn_s_barrier();
    __builtin_amdgcn_sched_barrier(0);
  }
  __syncthreads();

  // wave-private row stats: reduce over 16 lanes
#pragma unroll
  for (int r = 0; r < 4; r++) {
    float s = sPart[r], m = mPart[r];
#pragma unroll
    for (int off = 1; off < 16; off <<= 1) {
      s += __shfl_xor(s, off);
      m = fmaxf(m, __shfl_xor(m, off));
    }
    if (ln == 0) {
      sS[16 * w + quad * 4 + r] = s;
      mS[16 * w + quad * 4 + r] = m;
    }
  }
  __syncthreads();

  const float ktotv = ksumtot[bz];
#pragma unroll
  for (int mh = 0; mh < 4; mh++) {
#pragma unroll
    for (int r = 0; r < 4; r++) {
      int row = 16 * mh + quad * 4 + r;
      float st = sS[row];
      float mt = fmaxf(mS[row], 1e-30f);
      float c = __expf(-dS[row]) / mt;
      float inv = 1.f / (c * st + EPS_ * ktotv);
#pragma unroll
      for (int i = 0; i < 4; i++) {
        int e = 16 * (4 * w + i) + ln;
        float val = (c * acc[mh][i][r] + EPS_ * csS[e]) * inv;
        merged[((long)tq * NT + nt * 64 + row) * 2048 + hh * 256 + e] =
            __float2bfloat16(val);
      }
    }
  }
}

// ------------------------------------------------------------------
extern "C" void kernel_launch(void* const* d_in, const int* in_sizes, int n_in,
                              void* d_out, int out_size, void* d_ws, size_t ws_size,
                              hipStream_t stream)
{
  const void* x_ctx = d_in[0];
  const void* label = d_in[1];
  const void* x_tgt = d_in[2];
  const void* W1 = d_in[3];
  const void* b1 = d_in[4];
  const void* W2 = d_in[5];
  const void* b2 = d_in[6];
  const void* W3 = d_in[7];
  const void* b3 = d_in[8];
  const void* Wk = d_in[9];
  const void* bk = d_in[10];
  const void* Wv = d_in[11];
  const void* bv = d_in[12];
  const void* Wq = d_in[13];
  const void* bq = d_in[14];
  const void* Wo = d_in[15];
  const void* bo = d_in[16];
  const void* Wmu = d_in[17];
  const void* bmu = d_in[18];
  const void* proj = d_in[19];

  // Arena (floats), peak ~88 MB
  float* W = (float*)d_ws;
  const long F0 = 0, F1 = 4194304, F2 = 8388608;
  const long CTXQ_F = (long)64 * FT32 * 256 * 32 / 2;
  const long F3 = F2 + CTXQ_F;
  bf16* kB = (bf16*)(W + F0);
  bf16* qB = (bf16*)(W + F0);
  bf16* rep = (bf16*)(W + F0);
  bf16* vQ = (bf16*)(W + F1);
  bf16* merged = (bf16*)(W + F1);
  bf16* h1 = (bf16*)(W + F2);
  bf16* h2 = (bf16*)(W + F2 + 524288);
  bf16* cf = (bf16*)(W + F2 + 1048576);
  bf16* ctxQ = (bf16*)(W + F2);
  float* woP = W + F2;
  long o = F3;
  auto alloc = [&](long n) { float* p = W + o; o += n; return p; };
  float* zbase = W + o;
  float* dgk = alloc(32768);
  float* dgq = alloc(32768);
  float* Sv = alloc(64 * 256);
  float* ctxs = alloc(64 * 256);
  float* ktot = alloc(64);
  alloc(192);
  float* ksumE = alloc((long)64 * NBF);
  float* mpart = alloc(64 * 23);
  float* mk = alloc(64);
  int* dtFlag = (int*)alloc(64);
  bf16* projB = (bf16*)alloc((long)FT32 * 32 * 256 / 2);
  bf16* WkT = (bf16*)alloc(262144);   // 8 x 256 x 256 bf16
  bf16* WvT = (bf16*)alloc(262144);
  bf16* WqT = (bf16*)alloc(262144);
  bf16* WoT = (bf16*)alloc(262144);   // 256 x 2048 bf16 (perm folded)
  (void)ws_size; (void)in_sizes; (void)n_in; (void)out_size;

  const dim3 B(256);
  detect_dtype<<<1, B, 0, stream>>>(x_ctx, dtFlag);
  conv_proj<<<FT32 * 32, B, 0, stream>>>(proj, projB, dtFlag);
  conv_wT<<<dim3(64, 8, 25), B, 0, stream>>>(Wk, Wv, Wq, Wo, WkT, WvT, WqT, WoT, dtFlag);
  init_zero<<<385, B, 0, stream>>>(zbase);
  // 1. task-encoder MLP
  gemm_mfma32<<<dim3(4, 128), B, 0, stream>>>(
      x_ctx, 2, W1, nullptr, h1, 1, 0, dtFlag, 4096, 256, 256);
  fixup_h1<<<4096, B, 0, stream>>>(h1, label, W1, b1, dtFlag);
  gemm_mfma32<<<dim3(4, 128), B, 0, stream>>>(
      h1, 1, W2, b2, h2, 1, 2, dtFlag, 4096, 256, 256);
  gemm_mfma32<<<dim3(4, 128), B, 0, stream>>>(
      h2, 1, W3, b3, cf, 1, 2, dtFlag, 4096, 256, 256);
  // 2. k projection (fused diag), v projection (tiled -> vQ, fused Sv)
  gemm_mfma<<<dim3(4, 8, 64), B, 0, stream>>>(
      x_ctx, 2, WkT, bk, kB, 1, 1, 0, dtFlag, dgk, nullptr, 512, 256, 256, (long)512 * 256, H_, 65536L, H_, 256L);
  gemm_mfma<<<dim3(4, 8, 64), B, 0, stream>>>(
      cf, 1, WvT, bv, vQ, 1, 1, 2, dtFlag, nullptr, Sv, 512, 256, 256, (long)512 * 256, H_, 65536L, H_, 256L);
  // 3. key side
  key_fused_mfma<<<dim3(64, 23), B, 0, stream>>>(kB, vQ, projB, dgk, ksumE, ctxQ, mpart);
  mk_reduce<<<64, 64, 0, stream>>>(mpart, mk);
  ctx_finQ<<<dim3(FT32, 64), B, 0, stream>>>(ctxQ, Sv, mk, ctxs);
  ksum_fin<<<dim3(64, 6), B, 0, stream>>>(ksumE, mk, ktot);
  // 4. q projection (fused diag)
  gemm_mfma<<<dim3(4, 8, 64), B, 0, stream>>>(
      x_tgt, 2, WqT, bq, qB, 1, 1, 0, dtFlag, dgq, nullptr, 512, 256, 256, (long)512 * 256, H_, 65536L, H_, 256L);
  // 5. query side (64-row blocks) -> merged [t][n][h][e]
  q_fused_mfma<<<dim3(64, 8), B, 0, stream>>>(qB, projB, dgq, ctxQ, ksumE, ctxs, ktot, merged);
  // 6. Wo split-K x8 -> fp32 partials, reduce, Wmu
  gemm_wo_splitk<<<dim3(4, 64, 8), B, 0, stream>>>(merged, WoT, woP, dtFlag, 4096, 256, 2048);
  reduce_partials<<<4096, B, 0, stream>>>(woP, bo, rep, dtFlag);
  gemm_mfma32<<<dim3(4, 128), B, 0, stream>>>(
      rep, 1, Wmu, bmu, d_out, 2, 1, dtFlag, 4096, 256, 256);
}

// Round 6
// 425.140 us; speedup vs baseline: 1.7472x; 1.0638x over previous
//
#include <hip/hip_runtime.h>
#include <hip/hip_bf16.h>

typedef __hip_bfloat16 bf16;
typedef __attribute__((ext_vector_type(8))) short short8;
typedef __attribute__((ext_vector_type(4))) float f32x4;
typedef __attribute__((ext_vector_type(4))) unsigned short us4;
#define DEV __device__ __forceinline__

static constexpr int T_ = 8, NC = 512, NT = 512, D_ = 256, H_ = 8, NBF = 1419;
static constexpr int FT32 = 46;             // 46 f-tiles of 32 (padded 1472)
static constexpr float EPS_ = 1e-4f;
static constexpr float DN = 0.25f;          // D^-0.25
static constexpr float DIAG_SC = 0.03125f;  // 0.5 * DN^2

DEV float bf2f(unsigned short u) { return __uint_as_float(((unsigned)u) << 16); }
DEV float tofloat(bf16 x) { return __bfloat162float(x); }
DEV unsigned short f2bu(float x) { bf16 h = __float2bfloat16(x); return *(unsigned short*)&h; }

DEV float ldx(const void* p, long i, int isb) {
  if (isb) return bf2f(((const unsigned short*)p)[i]);
  return ((const float*)p)[i];
}
DEV void stx(void* p, long i, float v, int isb) {
  if (isb) ((bf16*)p)[i] = __float2bfloat16(v);
  else     ((float*)p)[i] = v;
}
DEV void unpack8(uint4 u, float* dst) {
  unsigned w[4] = {u.x, u.y, u.z, u.w};
#pragma unroll
  for (int i = 0; i < 4; i++) {
    dst[2 * i + 0] = __uint_as_float((w[i] & 0xffffu) << 16);
    dst[2 * i + 1] = __uint_as_float(w[i] & 0xffff0000u);
  }
}

// async global->LDS 16B (wave-uniform LDS base + lane*16; global addr per-lane)
DEV void async_copy16(const void* g, void* lds) {
  __builtin_amdgcn_global_load_lds(
      (const __attribute__((address_space(1))) unsigned int*)g,
      (__attribute__((address_space(3))) unsigned int*)lds, 16, 0, 0);
}

// ------------------------------------------------------------------
// dtype probe (1 = bf16 inputs, 0 = fp32)
// ------------------------------------------------------------------
__global__ __launch_bounds__(256)
void detect_dtype(const void* __restrict__ x, int* __restrict__ flag)
{
  __shared__ int bad;
  if (threadIdx.x == 0) bad = 0;
  __syncthreads();
  int mybad = 0;
  for (int j = 0; j < 16; j++) {
    long i = 2L * (threadIdx.x + 256L * j);
    unsigned short u = ((const unsigned short*)x)[i];
    int e = (u >> 7) & 0xff, mant = u & 0x7f;
    bool b = (e == 0xff) || (e >= 141) || (e <= 93 && !(e == 0 && mant == 0));
    mybad += b ? 1 : 0;
  }
  atomicAdd(&bad, mybad);
  __syncthreads();
  if (threadIdx.x == 0) *flag = (bad > 1024) ? 0 : 1;
}

// proj -> bf16 [FT32*32][256], zero rows past NBF
__global__ __launch_bounds__(256)
void conv_proj(const void* __restrict__ proj, bf16* __restrict__ projB,
               const int* __restrict__ dtFlag)
{
  const int fl = *dtFlag;
  int f = blockIdx.x, t = threadIdx.x;
  float v = (f < NBF) ? ldx(proj, (long)f * 256 + t, fl) : 0.f;
  projB[(long)f * 256 + t] = __float2bfloat16(v);
}

// generic activation convert -> bf16 (1M elements, grid 4096)
__global__ __launch_bounds__(256)
void conv_bf16(const void* __restrict__ src, bf16* __restrict__ dst,
               const int* __restrict__ dtFlag)
{
  const int fl = *dtFlag;
  long i = (long)blockIdx.x * 256 + threadIdx.x;
  dst[i] = __float2bfloat16(ldx(src, i, fl));
}

// ------------------------------------------------------------------
// Weight pre-transpose: W[k][n] -> WT[n][k] bf16. Wo folds the merged
// k-permutation. Grid (64,8,29): z 0..7 Wk, 8..15 Wv, 16..23 Wq,
// 24 Wo (kt 0..63), 25 W1, 26 W2, 27 W3, 28 Wmu.
// ------------------------------------------------------------------
__global__ __launch_bounds__(256)
void conv_wT(const void* __restrict__ Wk, const void* __restrict__ Wv,
             const void* __restrict__ Wq, const void* __restrict__ Wo,
             const void* __restrict__ W1, const void* __restrict__ W2,
             const void* __restrict__ W3, const void* __restrict__ Wmu,
             bf16* __restrict__ WkT, bf16* __restrict__ WvT,
             bf16* __restrict__ WqT, bf16* __restrict__ WoT,
             bf16* __restrict__ W1T, bf16* __restrict__ W2T,
             bf16* __restrict__ W3T, bf16* __restrict__ WmuT,
             const int* __restrict__ dtFlag)
{
  __shared__ float tile[32][33];
  const int fl = *dtFlag;
  const int kt = blockIdx.x, nt = blockIdx.y, z = blockIdx.z, t = threadIdx.x;
  const void* in; bf16* out; int K; int perm = 0; long off = 0;
  if (z < 8)        { in = Wk;  out = WkT;  K = 256; off = (long)z * 65536; }
  else if (z < 16)  { in = Wv;  out = WvT;  K = 256; off = (long)(z - 8) * 65536; }
  else if (z < 24)  { in = Wq;  out = WqT;  K = 256; off = (long)(z - 16) * 65536; }
  else if (z == 24) { in = Wo;  out = WoT;  K = 2048; perm = 1; }
  else if (z == 25) { in = W1;  out = W1T;  K = 256; }
  else if (z == 26) { in = W2;  out = W2T;  K = 256; }
  else if (z == 27) { in = W3;  out = W3T;  K = 256; }
  else              { in = Wmu; out = WmuT; K = 256; }
  if (K == 256 && kt >= 8) return;
  const int k0 = kt * 32, n0 = nt * 32;
  const int row = t >> 3, cb = (t & 7) * 4;
  {
    int kk = k0 + row;
    int krow = perm ? (((kk & 255) << 3) | (kk >> 8)) : kk;
#pragma unroll
    for (int j = 0; j < 4; j++)
      tile[row][cb + j] = ldx(in, off + (long)krow * 256 + n0 + cb + j, fl);
  }
  __syncthreads();
  us4 o;
#pragma unroll
  for (int j = 0; j < 4; j++) o[j] = f2bu(tile[cb + j][row]);
  *(us4*)(out + off + (long)(n0 + row) * K + k0 + cb) = o;
}

// zero the atomic-target region
__global__ __launch_bounds__(256)
void init_zero(float* __restrict__ p)
{
  p[blockIdx.x * 256 + threadIdx.x] = 0.f;
}

// ------------------------------------------------------------------
// Unified MFMA GEMM v2, 64x64 tile, K-step 64. A bf16 [M][K], BT bf16
// [N][K] (pre-transposed). Double-buffered LDS staged via
// global_load_lds with XOR-pre-swizzled source (cc=(l&7)^(l>>3), linear
// LDS dest -> conflict-free DMA write); swizzle-matched ds_read_b128.
// One barrier per K-iter (vmcnt(0) drain), prefetch distance 1.
// Epilogues: epi 0/1/2 (none/bias/bias+relu); cT=2 MFMA-tiled store
// (vQ) + optional column-sum svOut; diagOut per-row DIAG_SC*sum(c^2).
// LDS 32KB -> 4 blocks/CU.
// ------------------------------------------------------------------
__global__ __launch_bounds__(256)
void gemm_mfma(const bf16* __restrict__ A, const bf16* __restrict__ BT,
               const void* __restrict__ bias,
               void* __restrict__ C, int cMode, int epi, int cT,
               const int* __restrict__ dtFlag, float* __restrict__ diagOut,
               float* __restrict__ svOut,
               int M, int N, int K, long sA, int divA, long sB, int modB, long sBias)
{
  __shared__ alignas(16) bf16 As[2][64 * 64];
  __shared__ alignas(16) bf16 Bs[2][64 * 64];
  const int fl = *dtFlag;
  const int cB = (cMode == 2) ? fl : cMode;
  const int t = threadIdx.x;
  const int bz = blockIdx.z;
  const long aOff = (long)(bz / divA) * sA;
  const long bOff = (long)(bz % modB) * sB;
  const long biasOff = (long)(bz % modB) * sBias;
  const long cOff = (long)bz * (long)M * N;
  const int m0 = blockIdx.y * 64, n0 = blockIdx.x * 64;
  const int w = t >> 6, l = t & 63, quad = l >> 4, ln = l & 15;
  const bf16* Ab = A + aOff + (long)m0 * K;
  const bf16* Bb = BT + bOff + (long)n0 * K;
  const int srow = l >> 3;            // 0..7 within the wave's 8-row slab
  const int scc = (l & 7) ^ srow;     // XOR swizzle chunk (row&7 == srow)
  f32x4 acc[4] = {};

  auto stage = [&](int buf, int k0) {
#pragma unroll
    for (int j = 0; j < 2; j++) {
      const int rbase = 32 * j + 8 * w;         // rbase&7 == 0
      const int row = rbase + srow;
      async_copy16(Ab + (long)row * K + k0 + scc * 8, &As[buf][rbase * 64]);
      async_copy16(Bb + (long)row * K + k0 + scc * 8, &Bs[buf][rbase * 64]);
    }
  };

  stage(0, 0);
  __syncthreads();   // full drain: buffer 0 ready

  int cur = 0;
  for (int k0 = 0; k0 < K; k0 += 64) {
    if (k0 + 64 < K) stage(cur ^ 1, k0 + 64);
    const bf16* Ac = &As[cur][0];
    const bf16* Bc = &Bs[cur][0];
    const int arow = 16 * w + ln;
#pragma unroll
    for (int ks = 0; ks < 2; ks++) {
      short8 a = *(const short8*)(Ac + arow * 64 + (((ks * 4 + quad) ^ (arow & 7)) << 3));
#pragma unroll
      for (int i = 0; i < 4; i++) {
        const int brow = 16 * i + ln;
        short8 b = *(const short8*)(Bc + brow * 64 + (((ks * 4 + quad) ^ (brow & 7)) << 3));
        acc[i] = __builtin_amdgcn_mfma_f32_16x16x32_bf16(a, b, acc[i], 0, 0, 0);
      }
    }
    // single barrier: next buffer's DMAs complete across all waves;
    // also gates the +2-iter overwrite of the buffer just read
    asm volatile("s_waitcnt vmcnt(0)" ::: "memory");
    __builtin_amdgcn_s_barrier();
    __builtin_amdgcn_sched_barrier(0);
    cur ^= 1;
  }

  float s2[4] = {0.f, 0.f, 0.f, 0.f};
  if (cT == 2) {
    const int mm = m0 + 16 * w + quad * 4;
    const int tile = mm >> 5, off = mm & 31;
#pragma unroll
    for (int i = 0; i < 4; i++) {
      int n = n0 + 16 * i + ln;
      us4 cv;
      float colsum = 0.f;
#pragma unroll
      for (int r = 0; r < 4; r++) {
        float c = acc[i][r];
        if (epi >= 1) c += ldx(bias, biasOff + n, fl);
        if (epi == 2) c = fmaxf(c, 0.f);
        colsum += c;
        cv[r] = f2bu(c);
      }
      *(us4*)((bf16*)C + cOff + ((long)tile * N + n) * 32 + off) = cv;
      if (svOut) {
        colsum += __shfl_xor(colsum, 16);
        colsum += __shfl_xor(colsum, 32);
        if (quad == 0) atomicAdd(&svOut[(long)bz * N + n], colsum);
      }
    }
  } else {
#pragma unroll
    for (int i = 0; i < 4; i++) {
#pragma unroll
      for (int r = 0; r < 4; r++) {
        int m = m0 + 16 * w + quad * 4 + r;
        int n = n0 + 16 * i + ln;
        float c = acc[i][r];
        if (epi >= 1) c += ldx(bias, biasOff + n, fl);
        if (epi == 2) c = fmaxf(c, 0.f);
        s2[r] += c * c;
        stx(C, cOff + (long)m * N + n, c, cB);
      }
    }
  }
  if (diagOut) {
#pragma unroll
    for (int r = 0; r < 4; r++) {
      float s = s2[r];
      s += __shfl_xor(s, 1); s += __shfl_xor(s, 2);
      s += __shfl_xor(s, 4); s += __shfl_xor(s, 8);
      if (ln == 0)
        atomicAdd(&diagOut[(long)bz * M + m0 + 16 * w + quad * 4 + r], DIAG_SC * s);
    }
  }
}

// ------------------------------------------------------------------
// Wo GEMM, split-K x8, same v2 staging (A=merged bf16, BT=WoT).
// ------------------------------------------------------------------
__global__ __launch_bounds__(256)
void gemm_wo_splitk(const bf16* __restrict__ A, const bf16* __restrict__ BT,
                    float* __restrict__ P, int M, int N, int K)
{
  __shared__ alignas(16) bf16 As[2][64 * 64];
  __shared__ alignas(16) bf16 Bs[2][64 * 64];
  const int t = threadIdx.x;
  const int z = blockIdx.z;
  const int m0 = blockIdx.y * 64, n0 = blockIdx.x * 64;
  const int w = t >> 6, l = t & 63, quad = l >> 4, ln = l & 15;
  const bf16* Ab = A + (long)m0 * K;
  const bf16* Bb = BT + (long)n0 * K;
  const int srow = l >> 3, scc = (l & 7) ^ srow;
  f32x4 acc[4] = {};
  const int kbase = z * 256, kend = kbase + 256;

  auto stage = [&](int buf, int k0) {
#pragma unroll
    for (int j = 0; j < 2; j++) {
      const int rbase = 32 * j + 8 * w;
      const int row = rbase + srow;
      async_copy16(Ab + (long)row * K + k0 + scc * 8, &As[buf][rbase * 64]);
      async_copy16(Bb + (long)row * K + k0 + scc * 8, &Bs[buf][rbase * 64]);
    }
  };

  stage(0, kbase);
  __syncthreads();

  int cur = 0;
  for (int k0 = kbase; k0 < kend; k0 += 64) {
    if (k0 + 64 < kend) stage(cur ^ 1, k0 + 64);
    const bf16* Ac = &As[cur][0];
    const bf16* Bc = &Bs[cur][0];
    const int arow = 16 * w + ln;
#pragma unroll
    for (int ks = 0; ks < 2; ks++) {
      short8 a = *(const short8*)(Ac + arow * 64 + (((ks * 4 + quad) ^ (arow & 7)) << 3));
#pragma unroll
      for (int i = 0; i < 4; i++) {
        const int brow = 16 * i + ln;
        short8 b = *(const short8*)(Bc + brow * 64 + (((ks * 4 + quad) ^ (brow & 7)) << 3));
        acc[i] = __builtin_amdgcn_mfma_f32_16x16x32_bf16(a, b, acc[i], 0, 0, 0);
      }
    }
    asm volatile("s_waitcnt vmcnt(0)" ::: "memory");
    __builtin_amdgcn_s_barrier();
    __builtin_amdgcn_sched_barrier(0);
    cur ^= 1;
  }

  float* Pz = P + (long)z * M * N;
#pragma unroll
  for (int i = 0; i < 4; i++) {
#pragma unroll
    for (int r = 0; r < 4; r++) {
      int m = m0 + 16 * w + quad * 4 + r;
      int n = n0 + 16 * i + ln;
      Pz[(long)m * N + n] = acc[i][r];
    }
  }
}

// rep[m][n] (bf16) = sum_z P[z][m][n] + bo[n]
__global__ __launch_bounds__(256)
void reduce_partials(const float* __restrict__ P, const void* __restrict__ bo,
                     bf16* __restrict__ rep, const int* __restrict__ dtFlag)
{
  const int fl = *dtFlag;
  long idx = (long)blockIdx.x * 256 + threadIdx.x;
  int n = idx & 255;
  float s = ldx(bo, n, fl);
#pragma unroll
  for (int z = 0; z < 8; z++) s += P[(long)z * 1048576 + idx];
  rep[idx] = __float2bfloat16(s);
}

__global__ __launch_bounds__(256)
void fixup_h1(bf16* __restrict__ h1, const void* __restrict__ label,
              const void* __restrict__ W1, const void* __restrict__ b1,
              const int* __restrict__ dtFlag)
{
  const int fl = *dtFlag;
  int idx = blockIdx.x * 256 + threadIdx.x;
  int m = idx >> 8, n = idx & 255;
  float c = tofloat(h1[idx]) + ldx(b1, n, fl);
#pragma unroll
  for (int j = 0; j < 3; j++)
    c += ldx(label, m * 3 + j, fl) * ldx(W1, (256 + j) * 256 + n, fl);
  h1[idx] = __float2bfloat16(fmaxf(c, 0.f));
}

// ------------------------------------------------------------------
// Key-side fused v5 (best measured): kS triple-buffered via
// global_load_lds with pre-swizzled source, one barrier per iteration
// with counted vmcnt(4), pS double-buffered, setprio on MFMA clusters.
// ------------------------------------------------------------------
__global__ __launch_bounds__(256)
void key_fused_mfma(const bf16* __restrict__ k, const bf16* __restrict__ vQ,
                    const bf16* __restrict__ projB, const float* __restrict__ diagk,
                    float* __restrict__ ksumE, bf16* __restrict__ ctxQ,
                    float* __restrict__ mpart)
{
  __shared__ alignas(16) bf16 kS[3][32 * 256];
  __shared__ alignas(16) bf16 pS[2][64 * 40];
  __shared__ float wredM[4];

  const int bz = blockIdx.x, ft = blockIdx.y, f0 = ft * 64;
  const int t = threadIdx.x;
  const int w = t >> 6, l = t & 63, quad = l >> 4, ln = l & 15;
  const int fmine = f0 + 16 * w + ln;
  const bool fv = fmine < NBF;

  const bf16* kb = k + (long)bz * NC * 256;
  const bf16* vqb = vQ + (long)bz * 16 * 256 * 32;
  const float* db = diagk + bz * NC;

  auto stage = [&](int buf, int n0) {
#pragma unroll
    for (int j = 0; j < 4; j++) {
      int row = w * 8 + j * 2 + (l >> 5);
      int cc = (l & 31) ^ ((2 * j + (l >> 5)) & 7);   // = (l&31) ^ (row&7)
      async_copy16(kb + (long)(n0 + row) * 256 + cc * 8,
                   &kS[buf][w * 2048 + j * 512]);
    }
  };
  stage(0, 0);
  stage(1, 32);

  short8 pf[8];
  {
    const bf16* prow = projB + (long)fmine * 256;
#pragma unroll
    for (int kc = 0; kc < 8; kc++)
      pf[kc] = *(const short8*)(prow + kc * 32 + quad * 8);
  }

  f32x4 acc[4][4] = {};
  float ksumP = 0.f, mP = -1e30f;

  __syncthreads();   // full drain once: kS[0], kS[1] + pf ready

  int cur = 0;       // buffer holding tile `it`
  for (int it = 0; it < 16; it++) {
    const int n0 = it * 32;
    short8 bfr[4];
#pragma unroll
    for (int ei = 0; ei < 4; ei++) {
      int e = 64 * w + 16 * ei + ln;
      bfr[ei] = *(const short8*)(vqb + ((long)it * 256 + e) * 32 + quad * 8);
    }
    f32x4 dv0 = *(const f32x4*)(db + n0 + quad * 4);
    f32x4 dv1 = *(const f32x4*)(db + n0 + 16 + quad * 4);
    __builtin_amdgcn_sched_barrier(0);
    if (it + 2 < 16) {
      int nb = cur + 2; if (nb >= 3) nb -= 3;
      stage(nb, n0 + 64);
    }
    __builtin_amdgcn_sched_barrier(0);

    const bf16* kcur = &kS[cur][0];
    f32x4 dd[2][2] = {};
    __builtin_amdgcn_s_setprio(1);
#pragma unroll
    for (int kc = 0; kc < 8; kc++) {
      const int hf = kc & 1;
#pragma unroll
      for (int mi = 0; mi < 2; mi++) {
        short8 a = *(const short8*)(kcur + (16 * mi + ln) * 256 +
                                    (((kc * 4 + quad) ^ (ln & 7)) << 3));
        dd[mi][hf] = __builtin_amdgcn_mfma_f32_16x16x32_bf16(a, pf[kc], dd[mi][hf], 0, 0, 0);
      }
    }
    __builtin_amdgcn_s_setprio(0);
    bf16* pcur = &pS[it & 1][0];
#pragma unroll
    for (int mi = 0; mi < 2; mi++) {
      us4 ev;
      f32x4 dvv = mi ? dv1 : dv0;
#pragma unroll
      for (int r = 0; r < 4; r++) {
        float sc = DN * (dd[mi][0][r] + dd[mi][1][r]);
        float E = fv ? __expf(fminf(sc - dvv[r], 80.f)) : 0.f;
        unsigned short u = f2bu(E);
        ksumP += bf2f(u);
        if (fv) mP = fmaxf(mP, sc);
        ev[r] = u;
      }
      *(us4*)(pcur + (16 * w + ln) * 40 + 16 * mi + quad * 4) = ev;
    }
    asm volatile("s_waitcnt vmcnt(4) lgkmcnt(0)" ::: "memory");
    __builtin_amdgcn_s_barrier();
    __builtin_amdgcn_sched_barrier(0);

    __builtin_amdgcn_s_setprio(1);
#pragma unroll
    for (int fh = 0; fh < 4; fh++) {
      short8 a = *(const short8*)(pcur + (16 * fh + ln) * 40 + quad * 8);
#pragma unroll
      for (int ei = 0; ei < 4; ei++)
        acc[fh][ei] = __builtin_amdgcn_mfma_f32_16x16x32_bf16(a, bfr[ei], acc[fh][ei], 0, 0, 0);
    }
    __builtin_amdgcn_s_setprio(0);
    cur = (cur == 2) ? 0 : cur + 1;
  }
  __syncthreads();

#pragma unroll
  for (int fh = 0; fh < 4; fh++) {
    const int ft32 = 2 * ft + (fh >> 1);
    const int f32b = 16 * (fh & 1) + quad * 4;
#pragma unroll
    for (int ei = 0; ei < 4; ei++) {
      int e = 64 * w + 16 * ei + ln;
      us4 cv;
#pragma unroll
      for (int r = 0; r < 4; r++) cv[r] = f2bu(acc[fh][ei][r]);
      *(us4*)(&ctxQ[((long)(bz * FT32 + ft32) * 256 + e) * 32 + f32b]) = cv;
    }
  }

  float s = ksumP;
  s += __shfl_xor(s, 16); s += __shfl_xor(s, 32);
  if (quad == 0 && fv) ksumE[(long)bz * NBF + fmine] = s;
  float m = mP;
#pragma unroll
  for (int off = 1; off < 64; off <<= 1) m = fmaxf(m, __shfl_xor(m, off));
  if (l == 0) wredM[w] = m;
  __syncthreads();
  if (t == 0)
    mpart[bz * 23 + ft] = fmaxf(fmaxf(wredM[0], wredM[1]), fmaxf(wredM[2], wredM[3]));
}

__global__ __launch_bounds__(64)
void mk_reduce(const float* __restrict__ mpart, float* __restrict__ mk)
{
  int bz = blockIdx.x, l = threadIdx.x;
  float m = (l < 23) ? mpart[bz * 23 + l] : -1e30f;
#pragma unroll
  for (int off = 32; off > 0; off >>= 1) m = fmaxf(m, __shfl_down(m, off));
  if (l == 0) mk[bz] = m;
}

// ctxQ finalize + fused ctxsum accumulation (ctxs pre-zeroed)
__global__ __launch_bounds__(256)
void ctx_finQ(bf16* __restrict__ ctxQ, const float* __restrict__ Sv,
              const float* __restrict__ mk, float* __restrict__ ctxs)
{
  int ft32 = blockIdx.x, bz = blockIdx.y, e = threadIdx.x;
  float emk = __expf(-mk[bz]);
  float sve = EPS_ * Sv[bz * 256 + e];
  uint4* row = (uint4*)(ctxQ + ((long)(bz * FT32 + ft32) * 256 + e) * 32);
  int fbase = 32 * ft32;
  float rsum = 0.f;
#pragma unroll
  for (int cchunk = 0; cchunk < 4; cchunk++) {
    float tmp[8];
    unpack8(row[cchunk], tmp);
    unsigned short out[8];
#pragma unroll
    for (int j = 0; j < 8; j++) {
      int f = fbase + cchunk * 8 + j;
      float val = (f < NBF) ? (emk * tmp[j] + sve) : 0.f;
      rsum += val;
      out[j] = f2bu(val);
    }
    row[cchunk] = *(const uint4*)out;
  }
  atomicAdd(&ctxs[bz * 256 + e], rsum);
}

// ksum finalize, parallel: grid (64, 6); ktot via atomicAdd (pre-zeroed)
__global__ __launch_bounds__(256)
void ksum_fin(float* __restrict__ ksumE, const float* __restrict__ mk,
              float* __restrict__ ksumtot)
{
  __shared__ float red[4];
  int bz = blockIdx.x, t = threadIdx.x;
  int f = blockIdx.y * 256 + t;
  float emk = __expf(-mk[bz]);
  float s = 0.f;
  if (f < NBF) {
    float kf = emk * ksumE[(long)bz * NBF + f] + (float)NC * EPS_;
    ksumE[(long)bz * NBF + f] = kf;
    s = kf;
  }
#pragma unroll
  for (int off = 32; off > 0; off >>= 1) s += __shfl_down(s, off);
  if ((t & 63) == 0) red[t >> 6] = s;
  __syncthreads();
  if (t == 0) atomicAdd(&ksumtot[bz], red[0] + red[1] + red[2] + red[3]);
}

// ------------------------------------------------------------------
// Query-side fused v5 (best measured): q in registers, projS double-
// buffered via swizzled-source global_load_lds, counted waits.
// ------------------------------------------------------------------
__global__ __launch_bounds__(256)
void q_fused_mfma(const bf16* __restrict__ q, const bf16* __restrict__ projB,
                  const float* __restrict__ diagq, const bf16* __restrict__ ctxQ,
                  const float* __restrict__ ksum, const float* __restrict__ ctxsum,
                  const float* __restrict__ ksumtot, bf16* __restrict__ merged)
{
  __shared__ alignas(16) bf16 projS[2][32 * 256];
  __shared__ alignas(16) bf16 eS[64 * 40];
  __shared__ float dS[64];
  __shared__ float csS[256];
  __shared__ float sS[64];
  __shared__ float mS[64];

  const int bz = blockIdx.x, nt = blockIdx.y, t = threadIdx.x;
  const int w = t >> 6, l = t & 63, quad = l >> 4, ln = l & 15;
  const int tq = bz / H_, hh = bz % H_;
  const bf16* cqb = ctxQ + (long)bz * FT32 * 256 * 32;
  const bf16* qb = q + ((long)bz * NT + nt * 64) * 256;

  auto stage_proj = [&](int buf, int f0n) {
#pragma unroll
    for (int j = 0; j < 4; j++) {
      int row = 8 * w + 2 * j + (l >> 5);
      int cc = (l & 31) ^ (row & 7);
      async_copy16(projB + (long)(f0n + row) * 256 + cc * 8,
                   &projS[buf][(8 * w + 2 * j) * 256]);
    }
  };
  stage_proj(0, 0);

  // q fragments: no ft dependence -> load once, keep in 32 VGPRs
  short8 qf[8];
  {
    const bf16* qrow = qb + (long)(16 * w + ln) * 256;
#pragma unroll
    for (int kc = 0; kc < 8; kc++)
      qf[kc] = *(const short8*)(qrow + kc * 32 + quad * 8);
  }
  if (t < 64) dS[t] = diagq[(long)bz * NT + nt * 64 + t];
  csS[t] = ctxsum[bz * 256 + t];

  f32x4 acc[4][4] = {};           // [mh][ei]: rows 16mh+quad*4+r, e=16(4w+ei)+ln
  float sPart[4] = {0.f, 0.f, 0.f, 0.f};   // rows 16w+quad*4+r (wave-private)
  float mPart[4] = {0.f, 0.f, 0.f, 0.f};
  __syncthreads();   // full drain: projS[0] + dS/csS ready

  for (int ft = 0; ft < FT32; ft++) {
    const int f0 = ft * 32;
    const bf16* pcur = &projS[ft & 1][0];
    short8 cfr[4];
#pragma unroll
    for (int i = 0; i < 4; i++) {
      int e = 16 * (4 * w + i) + ln;
      cfr[i] = *(const short8*)(cqb + ((long)ft * 256 + e) * 32 + quad * 8);
    }
    const float kv0 = (f0 + ln < NBF) ? ksum[(long)bz * NBF + f0 + ln] : 0.f;
    const float kv1 = (f0 + 16 + ln < NBF) ? ksum[(long)bz * NBF + f0 + 16 + ln] : 0.f;
    if (ft + 1 < FT32) stage_proj((ft + 1) & 1, f0 + 32);

    // Phase A: wave w owns rows 16w..16w+15, both f-halves
    f32x4 dd0 = {}, dd1 = {};
#pragma unroll
    for (int kc = 0; kc < 8; kc++) {
      const int co = ((kc * 4 + quad) ^ (ln & 7)) << 3;
      short8 b0 = *(const short8*)(pcur + ln * 256 + co);
      dd0 = __builtin_amdgcn_mfma_f32_16x16x32_bf16(qf[kc], b0, dd0, 0, 0, 0);
      short8 b1 = *(const short8*)(pcur + (16 + ln) * 256 + co);
      dd1 = __builtin_amdgcn_mfma_f32_16x16x32_bf16(qf[kc], b1, dd1, 0, 0, 0);
    }
    const bool fv0 = (f0 + ln) < NBF;
    const bool fv1 = (f0 + 16 + ln) < NBF;
#pragma unroll
    for (int r = 0; r < 4; r++) {
      float E0 = fv0 ? __expf(fminf(DN * dd0[r], 80.f)) : 0.f;
      float E1 = fv1 ? __expf(fminf(DN * dd1[r], 80.f)) : 0.f;
      bf16 h0 = __float2bfloat16(E0), h1v = __float2bfloat16(E1);
      float e0 = tofloat(h0), e1 = tofloat(h1v);
      eS[(16 * w + quad * 4 + r) * 40 + ln] = h0;
      eS[(16 * w + quad * 4 + r) * 40 + 16 + ln] = h1v;
      sPart[r] += e0 * kv0 + e1 * kv1;
      mPart[r] = fmaxf(mPart[r], fmaxf(e0, e1));
    }
    // mid barrier: eS writes visible; proj prefetch stays in flight
    asm volatile("s_waitcnt lgkmcnt(0)" ::: "memory");
    __builtin_amdgcn_s_barrier();
    __builtin_amdgcn_sched_barrier(0);

    // Phase B: all 4 m-halves, 4 e-tiles each (cfr reused)
#pragma unroll
    for (int mh = 0; mh < 4; mh++) {
      short8 a = *(const short8*)(&eS[(16 * mh + ln) * 40 + quad * 8]);
#pragma unroll
      for (int i = 0; i < 4; i++)
        acc[mh][i] = __builtin_amdgcn_mfma_f32_16x16x32_bf16(a, cfr[i], acc[mh][i], 0, 0, 0);
    }
    // end barrier: next projS buffer complete (vmcnt covers global_load_lds)
    asm volatile("s_waitcnt vmcnt(0) lgkmcnt(0)" ::: "memory");
    __builtin_amdgcn_s_barrier();
    __builtin_amdgcn_sched_barrier(0);
  }
  __syncthreads();

  // wave-private row stats: reduce over 16 lanes
#pragma unroll
  for (int r = 0; r < 4; r++) {
    float s = sPart[r], m = mPart[r];
#pragma unroll
    for (int off = 1; off < 16; off <<= 1) {
      s += __shfl_xor(s, off);
      m = fmaxf(m, __shfl_xor(m, off));
    }
    if (ln == 0) {
      sS[16 * w + quad * 4 + r] = s;
      mS[16 * w + quad * 4 + r] = m;
    }
  }
  __syncthreads();

  const float ktotv = ksumtot[bz];
#pragma unroll
  for (int mh = 0; mh < 4; mh++) {
#pragma unroll
    for (int r = 0; r < 4; r++) {
      int row = 16 * mh + quad * 4 + r;
      float st = sS[row];
      float mt = fmaxf(mS[row], 1e-30f);
      float c = __expf(-dS[row]) / mt;
      float inv = 1.f / (c * st + EPS_ * ktotv);
#pragma unroll
      for (int i = 0; i < 4; i++) {
        int e = 16 * (4 * w + i) + ln;
        float val = (c * acc[mh][i][r] + EPS_ * csS[e]) * inv;
        merged[((long)tq * NT + nt * 64 + row) * 2048 + hh * 256 + e] =
            __float2bfloat16(val);
      }
    }
  }
}

// ------------------------------------------------------------------
extern "C" void kernel_launch(void* const* d_in, const int* in_sizes, int n_in,
                              void* d_out, int out_size, void* d_ws, size_t ws_size,
                              hipStream_t stream)
{
  const void* x_ctx = d_in[0];
  const void* label = d_in[1];
  const void* x_tgt = d_in[2];
  const void* W1 = d_in[3];
  const void* b1 = d_in[4];
  const void* W2 = d_in[5];
  const void* b2 = d_in[6];
  const void* W3 = d_in[7];
  const void* b3 = d_in[8];
  const void* Wk = d_in[9];
  const void* bk = d_in[10];
  const void* Wv = d_in[11];
  const void* bv = d_in[12];
  const void* Wq = d_in[13];
  const void* bq = d_in[14];
  const void* Wo = d_in[15];
  const void* bo = d_in[16];
  const void* Wmu = d_in[17];
  const void* bmu = d_in[18];
  const void* proj = d_in[19];

  // Arena (floats), peak ~89 MB. Overlays:
  //  xcB @ F2+1572864 (after cf; dead before ctxQ is written by key_fused)
  //  xtB @ F1 (vQ region; vQ dead after key_fused, merged written after q-proj)
  float* W = (float*)d_ws;
  const long F0 = 0, F1 = 4194304, F2 = 8388608;
  const long CTXQ_F = (long)64 * FT32 * 256 * 32 / 2;
  const long F3 = F2 + CTXQ_F;
  bf16* kB = (bf16*)(W + F0);
  bf16* qB = (bf16*)(W + F0);
  bf16* rep = (bf16*)(W + F0);
  bf16* vQ = (bf16*)(W + F1);
  bf16* merged = (bf16*)(W + F1);
  bf16* xtB = (bf16*)(W + F1);
  bf16* h1 = (bf16*)(W + F2);
  bf16* h2 = (bf16*)(W + F2 + 524288);
  bf16* cf = (bf16*)(W + F2 + 1048576);
  bf16* xcB = (bf16*)(W + F2 + 1572864);
  bf16* ctxQ = (bf16*)(W + F2);
  float* woP = W + F2;
  long o = F3;
  auto alloc = [&](long n) { float* p = W + o; o += n; return p; };
  float* zbase = W + o;
  float* dgk = alloc(32768);
  float* dgq = alloc(32768);
  float* Sv = alloc(64 * 256);
  float* ctxs = alloc(64 * 256);
  float* ktot = alloc(64);
  alloc(192);
  float* ksumE = alloc((long)64 * NBF);
  float* mpart = alloc(64 * 23);
  float* mk = alloc(64);
  int* dtFlag = (int*)alloc(64);
  bf16* projB = (bf16*)alloc((long)FT32 * 32 * 256 / 2);
  bf16* WkT = (bf16*)alloc(262144);   // 8 x 256 x 256 bf16
  bf16* WvT = (bf16*)alloc(262144);
  bf16* WqT = (bf16*)alloc(262144);
  bf16* WoT = (bf16*)alloc(262144);   // 256 x 2048 bf16 (perm folded)
  bf16* W1T = (bf16*)alloc(32768);    // 256 x 256 bf16
  bf16* W2T = (bf16*)alloc(32768);
  bf16* W3T = (bf16*)alloc(32768);
  bf16* WmuT = (bf16*)alloc(32768);
  (void)ws_size; (void)in_sizes; (void)n_in; (void)out_size;

  const dim3 B(256);
  detect_dtype<<<1, B, 0, stream>>>(x_ctx, dtFlag);
  conv_proj<<<FT32 * 32, B, 0, stream>>>(proj, projB, dtFlag);
  conv_wT<<<dim3(64, 8, 29), B, 0, stream>>>(Wk, Wv, Wq, Wo, W1, W2, W3, Wmu,
                                             WkT, WvT, WqT, WoT, W1T, W2T, W3T, WmuT, dtFlag);
  conv_bf16<<<4096, B, 0, stream>>>(x_ctx, xcB, dtFlag);
  init_zero<<<385, B, 0, stream>>>(zbase);
  // 1. task-encoder MLP (all via unified async gemm)
  gemm_mfma<<<dim3(4, 64, 1), B, 0, stream>>>(
      xcB, W1T, nullptr, h1, 1, 0, 0, dtFlag, nullptr, nullptr,
      4096, 256, 256, 0L, 1, 0L, 1, 0L);
  fixup_h1<<<4096, B, 0, stream>>>(h1, label, W1, b1, dtFlag);
  gemm_mfma<<<dim3(4, 64, 1), B, 0, stream>>>(
      h1, W2T, b2, h2, 1, 2, 0, dtFlag, nullptr, nullptr,
      4096, 256, 256, 0L, 1, 0L, 1, 0L);
  gemm_mfma<<<dim3(4, 64, 1), B, 0, stream>>>(
      h2, W3T, b3, cf, 1, 2, 0, dtFlag, nullptr, nullptr,
      4096, 256, 256, 0L, 1, 0L, 1, 0L);
  // 2. k projection (fused diag), v projection (tiled -> vQ, fused Sv)
  gemm_mfma<<<dim3(4, 8, 64), B, 0, stream>>>(
      xcB, WkT, bk, kB, 1, 1, 0, dtFlag, dgk, nullptr,
      512, 256, 256, 131072L, 8, 65536L, 8, 256L);
  gemm_mfma<<<dim3(4, 8, 64), B, 0, stream>>>(
      cf, WvT, bv, vQ, 1, 1, 2, dtFlag, nullptr, Sv,
      512, 256, 256, 131072L, 8, 65536L, 8, 256L);
  // 3. key side
  key_fused_mfma<<<dim3(64, 23), B, 0, stream>>>(kB, vQ, projB, dgk, ksumE, ctxQ, mpart);
  mk_reduce<<<64, 64, 0, stream>>>(mpart, mk);
  ctx_finQ<<<dim3(FT32, 64), B, 0, stream>>>(ctxQ, Sv, mk, ctxs);
  ksum_fin<<<dim3(64, 6), B, 0, stream>>>(ksumE, mk, ktot);
  // 4. q projection (fused diag); xtB converted now (vQ region is dead)
  conv_bf16<<<4096, B, 0, stream>>>(x_tgt, xtB, dtFlag);
  gemm_mfma<<<dim3(4, 8, 64), B, 0, stream>>>(
      xtB, WqT, bq, qB, 1, 1, 0, dtFlag, dgq, nullptr,
      512, 256, 256, 131072L, 8, 65536L, 8, 256L);
  // 5. query side (64-row blocks) -> merged [t][n][h][e]
  q_fused_mfma<<<dim3(64, 8), B, 0, stream>>>(qB, projB, dgq, ctxQ, ksumE, ctxs, ktot, merged);
  // 6. Wo split-K x8 -> fp32 partials, reduce, Wmu
  gemm_wo_splitk<<<dim3(4, 64, 8), B, 0, stream>>>(merged, WoT, woP, 4096, 256, 2048);
  reduce_partials<<<4096, B, 0, stream>>>(woP, bo, rep, dtFlag);
  gemm_mfma<<<dim3(4, 64, 1), B, 0, stream>>>(
      rep, WmuT, bmu, d_out, 2, 1, 0, dtFlag, nullptr, nullptr,
      4096, 256, 256, 0L, 1, 0L, 1, 0L);
}

// Round 7
// 417.916 us; speedup vs baseline: 1.7774x; 1.0173x over previous
//
#include <hip/hip_runtime.h>
#include <hip/hip_bf16.h>

typedef __hip_bfloat16 bf16;
typedef __attribute__((ext_vector_type(8))) short short8;
typedef __attribute__((ext_vector_type(4))) float f32x4;
typedef __attribute__((ext_vector_type(4))) unsigned short us4;
#define DEV __device__ __forceinline__

static constexpr int T_ = 8, NC = 512, NT = 512, D_ = 256, H_ = 8, NBF = 1419;
static constexpr int FT32 = 46;             // 46 f-tiles of 32 (padded 1472)
static constexpr float EPS_ = 1e-4f;
static constexpr float DN = 0.25f;          // D^-0.25
static constexpr float DIAG_SC = 0.03125f;  // 0.5 * DN^2

DEV float bf2f(unsigned short u) { return __uint_as_float(((unsigned)u) << 16); }
DEV float tofloat(bf16 x) { return __bfloat162float(x); }
DEV unsigned short f2bu(float x) { bf16 h = __float2bfloat16(x); return *(unsigned short*)&h; }

DEV float ldx(const void* p, long i, int isb) {
  if (isb) return bf2f(((const unsigned short*)p)[i]);
  return ((const float*)p)[i];
}
DEV void stx(void* p, long i, float v, int isb) {
  if (isb) ((bf16*)p)[i] = __float2bfloat16(v);
  else     ((float*)p)[i] = v;
}

// async global->LDS 16B (wave-uniform LDS base + lane*16; global addr per-lane)
DEV void async_copy16(const void* g, void* lds) {
  __builtin_amdgcn_global_load_lds(
      (const __attribute__((address_space(1))) unsigned int*)g,
      (__attribute__((address_space(3))) unsigned int*)lds, 16, 0, 0);
}

// ------------------------------------------------------------------
// dtype probe (1 = bf16 inputs, 0 = fp32)
// ------------------------------------------------------------------
__global__ __launch_bounds__(256)
void detect_dtype(const void* __restrict__ x, int* __restrict__ flag)
{
  __shared__ int bad;
  if (threadIdx.x == 0) bad = 0;
  __syncthreads();
  int mybad = 0;
  for (int j = 0; j < 16; j++) {
    long i = 2L * (threadIdx.x + 256L * j);
    unsigned short u = ((const unsigned short*)x)[i];
    int e = (u >> 7) & 0xff, mant = u & 0x7f;
    bool b = (e == 0xff) || (e >= 141) || (e <= 93 && !(e == 0 && mant == 0));
    mybad += b ? 1 : 0;
  }
  atomicAdd(&bad, mybad);
  __syncthreads();
  if (threadIdx.x == 0) *flag = (bad > 1024) ? 0 : 1;
}

// proj -> bf16 [FT32*32][256], zero rows past NBF
__global__ __launch_bounds__(256)
void conv_proj(const void* __restrict__ proj, bf16* __restrict__ projB,
               const int* __restrict__ dtFlag)
{
  const int fl = *dtFlag;
  int f = blockIdx.x, t = threadIdx.x;
  float v = (f < NBF) ? ldx(proj, (long)f * 256 + t, fl) : 0.f;
  projB[(long)f * 256 + t] = __float2bfloat16(v);
}

// generic activation convert -> bf16 (1M elements, grid 4096)
__global__ __launch_bounds__(256)
void conv_bf16(const void* __restrict__ src, bf16* __restrict__ dst,
               const int* __restrict__ dtFlag)
{
  const int fl = *dtFlag;
  long i = (long)blockIdx.x * 256 + threadIdx.x;
  dst[i] = __float2bfloat16(ldx(src, i, fl));
}

// ------------------------------------------------------------------
// Weight pre-transpose: W[k][n] -> WT[n][k] bf16. Wo folds the merged
// k-permutation. Grid (64,8,29): z 0..7 Wk, 8..15 Wv, 16..23 Wq,
// 24 Wo (kt 0..63), 25 W1, 26 W2, 27 W3, 28 Wmu.
// ------------------------------------------------------------------
__global__ __launch_bounds__(256)
void conv_wT(const void* __restrict__ Wk, const void* __restrict__ Wv,
             const void* __restrict__ Wq, const void* __restrict__ Wo,
             const void* __restrict__ W1, const void* __restrict__ W2,
             const void* __restrict__ W3, const void* __restrict__ Wmu,
             bf16* __restrict__ WkT, bf16* __restrict__ WvT,
             bf16* __restrict__ WqT, bf16* __restrict__ WoT,
             bf16* __restrict__ W1T, bf16* __restrict__ W2T,
             bf16* __restrict__ W3T, bf16* __restrict__ WmuT,
             const int* __restrict__ dtFlag)
{
  __shared__ float tile[32][33];
  const int fl = *dtFlag;
  const int kt = blockIdx.x, nt = blockIdx.y, z = blockIdx.z, t = threadIdx.x;
  const void* in; bf16* out; int K; int perm = 0; long off = 0;
  if (z < 8)        { in = Wk;  out = WkT;  K = 256; off = (long)z * 65536; }
  else if (z < 16)  { in = Wv;  out = WvT;  K = 256; off = (long)(z - 8) * 65536; }
  else if (z < 24)  { in = Wq;  out = WqT;  K = 256; off = (long)(z - 16) * 65536; }
  else if (z == 24) { in = Wo;  out = WoT;  K = 2048; perm = 1; }
  else if (z == 25) { in = W1;  out = W1T;  K = 256; }
  else if (z == 26) { in = W2;  out = W2T;  K = 256; }
  else if (z == 27) { in = W3;  out = W3T;  K = 256; }
  else              { in = Wmu; out = WmuT; K = 256; }
  if (K == 256 && kt >= 8) return;
  const int k0 = kt * 32, n0 = nt * 32;
  const int row = t >> 3, cb = (t & 7) * 4;
  {
    int kk = k0 + row;
    int krow = perm ? (((kk & 255) << 3) | (kk >> 8)) : kk;
#pragma unroll
    for (int j = 0; j < 4; j++)
      tile[row][cb + j] = ldx(in, off + (long)krow * 256 + n0 + cb + j, fl);
  }
  __syncthreads();
  us4 o;
#pragma unroll
  for (int j = 0; j < 4; j++) o[j] = f2bu(tile[cb + j][row]);
  *(us4*)(out + off + (long)(n0 + row) * K + k0 + cb) = o;
}

// zero the atomic-target region
__global__ __launch_bounds__(256)
void init_zero(float* __restrict__ p)
{
  p[blockIdx.x * 256 + threadIdx.x] = 0.f;
}

// ------------------------------------------------------------------
// Unified MFMA GEMM v2, 64x64 tile, K-step 64 (proven round 5).
// ------------------------------------------------------------------
__global__ __launch_bounds__(256)
void gemm_mfma(const bf16* __restrict__ A, const bf16* __restrict__ BT,
               const void* __restrict__ bias,
               void* __restrict__ C, int cMode, int epi, int cT,
               const int* __restrict__ dtFlag, float* __restrict__ diagOut,
               float* __restrict__ svOut,
               int M, int N, int K, long sA, int divA, long sB, int modB, long sBias)
{
  __shared__ alignas(16) bf16 As[2][64 * 64];
  __shared__ alignas(16) bf16 Bs[2][64 * 64];
  const int fl = *dtFlag;
  const int cB = (cMode == 2) ? fl : cMode;
  const int t = threadIdx.x;
  const int bz = blockIdx.z;
  const long aOff = (long)(bz / divA) * sA;
  const long bOff = (long)(bz % modB) * sB;
  const long biasOff = (long)(bz % modB) * sBias;
  const long cOff = (long)bz * (long)M * N;
  const int m0 = blockIdx.y * 64, n0 = blockIdx.x * 64;
  const int w = t >> 6, l = t & 63, quad = l >> 4, ln = l & 15;
  const bf16* Ab = A + aOff + (long)m0 * K;
  const bf16* Bb = BT + bOff + (long)n0 * K;
  const int srow = l >> 3;            // 0..7 within the wave's 8-row slab
  const int scc = (l & 7) ^ srow;     // XOR swizzle chunk (row&7 == srow)
  f32x4 acc[4] = {};

  auto stage = [&](int buf, int k0) {
#pragma unroll
    for (int j = 0; j < 2; j++) {
      const int rbase = 32 * j + 8 * w;         // rbase&7 == 0
      const int row = rbase + srow;
      async_copy16(Ab + (long)row * K + k0 + scc * 8, &As[buf][rbase * 64]);
      async_copy16(Bb + (long)row * K + k0 + scc * 8, &Bs[buf][rbase * 64]);
    }
  };

  stage(0, 0);
  __syncthreads();   // full drain: buffer 0 ready

  int cur = 0;
  for (int k0 = 0; k0 < K; k0 += 64) {
    if (k0 + 64 < K) stage(cur ^ 1, k0 + 64);
    const bf16* Ac = &As[cur][0];
    const bf16* Bc = &Bs[cur][0];
    const int arow = 16 * w + ln;
#pragma unroll
    for (int ks = 0; ks < 2; ks++) {
      short8 a = *(const short8*)(Ac + arow * 64 + (((ks * 4 + quad) ^ (arow & 7)) << 3));
#pragma unroll
      for (int i = 0; i < 4; i++) {
        const int brow = 16 * i + ln;
        short8 b = *(const short8*)(Bc + brow * 64 + (((ks * 4 + quad) ^ (brow & 7)) << 3));
        acc[i] = __builtin_amdgcn_mfma_f32_16x16x32_bf16(a, b, acc[i], 0, 0, 0);
      }
    }
    asm volatile("s_waitcnt vmcnt(0)" ::: "memory");
    __builtin_amdgcn_s_barrier();
    __builtin_amdgcn_sched_barrier(0);
    cur ^= 1;
  }

  float s2[4] = {0.f, 0.f, 0.f, 0.f};
  if (cT == 2) {
    const int mm = m0 + 16 * w + quad * 4;
    const int tile = mm >> 5, off = mm & 31;
#pragma unroll
    for (int i = 0; i < 4; i++) {
      int n = n0 + 16 * i + ln;
      us4 cv;
      float colsum = 0.f;
#pragma unroll
      for (int r = 0; r < 4; r++) {
        float c = acc[i][r];
        if (epi >= 1) c += ldx(bias, biasOff + n, fl);
        if (epi == 2) c = fmaxf(c, 0.f);
        colsum += c;
        cv[r] = f2bu(c);
      }
      *(us4*)((bf16*)C + cOff + ((long)tile * N + n) * 32 + off) = cv;
      if (svOut) {
        colsum += __shfl_xor(colsum, 16);
        colsum += __shfl_xor(colsum, 32);
        if (quad == 0) atomicAdd(&svOut[(long)bz * N + n], colsum);
      }
    }
  } else {
#pragma unroll
    for (int i = 0; i < 4; i++) {
#pragma unroll
      for (int r = 0; r < 4; r++) {
        int m = m0 + 16 * w + quad * 4 + r;
        int n = n0 + 16 * i + ln;
        float c = acc[i][r];
        if (epi >= 1) c += ldx(bias, biasOff + n, fl);
        if (epi == 2) c = fmaxf(c, 0.f);
        s2[r] += c * c;
        stx(C, cOff + (long)m * N + n, c, cB);
      }
    }
  }
  if (diagOut) {
#pragma unroll
    for (int r = 0; r < 4; r++) {
      float s = s2[r];
      s += __shfl_xor(s, 1); s += __shfl_xor(s, 2);
      s += __shfl_xor(s, 4); s += __shfl_xor(s, 8);
      if (ln == 0)
        atomicAdd(&diagOut[(long)bz * M + m0 + 16 * w + quad * 4 + r], DIAG_SC * s);
    }
  }
}

// ------------------------------------------------------------------
// Wo GEMM, split-K x2 (was x8): partials traffic 32+32MB -> 8+8MB.
// ------------------------------------------------------------------
__global__ __launch_bounds__(256)
void gemm_wo_splitk(const bf16* __restrict__ A, const bf16* __restrict__ BT,
                    float* __restrict__ P, int M, int N, int K)
{
  __shared__ alignas(16) bf16 As[2][64 * 64];
  __shared__ alignas(16) bf16 Bs[2][64 * 64];
  const int t = threadIdx.x;
  const int z = blockIdx.z;
  const int m0 = blockIdx.y * 64, n0 = blockIdx.x * 64;
  const int w = t >> 6, l = t & 63, quad = l >> 4, ln = l & 15;
  const bf16* Ab = A + (long)m0 * K;
  const bf16* Bb = BT + (long)n0 * K;
  const int srow = l >> 3, scc = (l & 7) ^ srow;
  f32x4 acc[4] = {};
  const int kbase = z * 1024, kend = kbase + 1024;

  auto stage = [&](int buf, int k0) {
#pragma unroll
    for (int j = 0; j < 2; j++) {
      const int rbase = 32 * j + 8 * w;
      const int row = rbase + srow;
      async_copy16(Ab + (long)row * K + k0 + scc * 8, &As[buf][rbase * 64]);
      async_copy16(Bb + (long)row * K + k0 + scc * 8, &Bs[buf][rbase * 64]);
    }
  };

  stage(0, kbase);
  __syncthreads();

  int cur = 0;
  for (int k0 = kbase; k0 < kend; k0 += 64) {
    if (k0 + 64 < kend) stage(cur ^ 1, k0 + 64);
    const bf16* Ac = &As[cur][0];
    const bf16* Bc = &Bs[cur][0];
    const int arow = 16 * w + ln;
#pragma unroll
    for (int ks = 0; ks < 2; ks++) {
      short8 a = *(const short8*)(Ac + arow * 64 + (((ks * 4 + quad) ^ (arow & 7)) << 3));
#pragma unroll
      for (int i = 0; i < 4; i++) {
        const int brow = 16 * i + ln;
        short8 b = *(const short8*)(Bc + brow * 64 + (((ks * 4 + quad) ^ (brow & 7)) << 3));
        acc[i] = __builtin_amdgcn_mfma_f32_16x16x32_bf16(a, b, acc[i], 0, 0, 0);
      }
    }
    asm volatile("s_waitcnt vmcnt(0)" ::: "memory");
    __builtin_amdgcn_s_barrier();
    __builtin_amdgcn_sched_barrier(0);
    cur ^= 1;
  }

  float* Pz = P + (long)z * M * N;
#pragma unroll
  for (int i = 0; i < 4; i++) {
#pragma unroll
    for (int r = 0; r < 4; r++) {
      int m = m0 + 16 * w + quad * 4 + r;
      int n = n0 + 16 * i + ln;
      Pz[(long)m * N + n] = acc[i][r];
    }
  }
}

// rep[m][n] (bf16) = sum_z P[z][m][n] + bo[n]   (z = 2 now)
__global__ __launch_bounds__(256)
void reduce_partials(const float* __restrict__ P, const void* __restrict__ bo,
                     bf16* __restrict__ rep, const int* __restrict__ dtFlag)
{
  const int fl = *dtFlag;
  long idx = (long)blockIdx.x * 256 + threadIdx.x;
  int n = idx & 255;
  float s = ldx(bo, n, fl) + P[idx] + P[1048576 + idx];
  rep[idx] = __float2bfloat16(s);
}

__global__ __launch_bounds__(256)
void fixup_h1(bf16* __restrict__ h1, const void* __restrict__ label,
              const void* __restrict__ W1, const void* __restrict__ b1,
              const int* __restrict__ dtFlag)
{
  const int fl = *dtFlag;
  int idx = blockIdx.x * 256 + threadIdx.x;
  int m = idx >> 8, n = idx & 255;
  float c = tofloat(h1[idx]) + ldx(b1, n, fl);
#pragma unroll
  for (int j = 0; j < 3; j++)
    c += ldx(label, m * 3 + j, fl) * ldx(W1, (256 + j) * 256 + n, fl);
  h1[idx] = __float2bfloat16(fmaxf(c, 0.f));
}

// ------------------------------------------------------------------
// Key-side fused v7: kS double-buffered (distance-1 prefetch, vmcnt(0)
// at the single per-iter barrier) -> LDS ~42KB -> 3 blocks/CU (was 2).
// Epilogue additionally produces the RAW reductions that replace the
// ctx_finQ / ksum_fin passes (folded into q_fused):
//   csR[bz][e]  += sum_f ctxR[f][e]   (invalid-f rows are exactly 0)
//   ktotR[bz]   += sum_f ksumR[f]
// ------------------------------------------------------------------
__global__ __launch_bounds__(256)
void key_fused_mfma(const bf16* __restrict__ k, const bf16* __restrict__ vQ,
                    const bf16* __restrict__ projB, const float* __restrict__ diagk,
                    float* __restrict__ ksumE, bf16* __restrict__ ctxQ,
                    float* __restrict__ mpart, float* __restrict__ csR,
                    float* __restrict__ ktotR)
{
  __shared__ alignas(16) bf16 kS[2][32 * 256];
  __shared__ alignas(16) bf16 pS[2][64 * 40];
  __shared__ float wredM[4];

  const int bz = blockIdx.x, ft = blockIdx.y, f0 = ft * 64;
  const int t = threadIdx.x;
  const int w = t >> 6, l = t & 63, quad = l >> 4, ln = l & 15;
  const int fmine = f0 + 16 * w + ln;
  const bool fv = fmine < NBF;

  const bf16* kb = k + (long)bz * NC * 256;
  const bf16* vqb = vQ + (long)bz * 16 * 256 * 32;
  const float* db = diagk + bz * NC;

  auto stage = [&](int buf, int n0) {
#pragma unroll
    for (int j = 0; j < 4; j++) {
      int row = w * 8 + j * 2 + (l >> 5);
      int cc = (l & 31) ^ ((2 * j + (l >> 5)) & 7);   // = (l&31) ^ (row&7)
      async_copy16(kb + (long)(n0 + row) * 256 + cc * 8,
                   &kS[buf][w * 2048 + j * 512]);
    }
  };
  stage(0, 0);

  short8 pf[8];
  {
    const bf16* prow = projB + (long)fmine * 256;
#pragma unroll
    for (int kc = 0; kc < 8; kc++)
      pf[kc] = *(const short8*)(prow + kc * 32 + quad * 8);
  }

  f32x4 acc[4][4] = {};
  float ksumP = 0.f, mP = -1e30f;

  __syncthreads();   // full drain once: kS[0] + pf ready

  int cur = 0;
  for (int it = 0; it < 16; it++) {
    const int n0 = it * 32;
    short8 bfr[4];
#pragma unroll
    for (int ei = 0; ei < 4; ei++) {
      int e = 64 * w + 16 * ei + ln;
      bfr[ei] = *(const short8*)(vqb + ((long)it * 256 + e) * 32 + quad * 8);
    }
    f32x4 dv0 = *(const f32x4*)(db + n0 + quad * 4);
    f32x4 dv1 = *(const f32x4*)(db + n0 + 16 + quad * 4);
    __builtin_amdgcn_sched_barrier(0);
    if (it + 1 < 16) stage(cur ^ 1, n0 + 32);
    __builtin_amdgcn_sched_barrier(0);

    const bf16* kcur = &kS[cur][0];
    f32x4 dd[2][2] = {};
    __builtin_amdgcn_s_setprio(1);
#pragma unroll
    for (int kc = 0; kc < 8; kc++) {
      const int hf = kc & 1;
#pragma unroll
      for (int mi = 0; mi < 2; mi++) {
        short8 a = *(const short8*)(kcur + (16 * mi + ln) * 256 +
                                    (((kc * 4 + quad) ^ (ln & 7)) << 3));
        dd[mi][hf] = __builtin_amdgcn_mfma_f32_16x16x32_bf16(a, pf[kc], dd[mi][hf], 0, 0, 0);
      }
    }
    __builtin_amdgcn_s_setprio(0);
    bf16* pcur = &pS[it & 1][0];
#pragma unroll
    for (int mi = 0; mi < 2; mi++) {
      us4 ev;
      f32x4 dvv = mi ? dv1 : dv0;
#pragma unroll
      for (int r = 0; r < 4; r++) {
        float sc = DN * (dd[mi][0][r] + dd[mi][1][r]);
        float E = fv ? __expf(fminf(sc - dvv[r], 80.f)) : 0.f;
        unsigned short u = f2bu(E);
        ksumP += bf2f(u);
        if (fv) mP = fmaxf(mP, sc);
        ev[r] = u;
      }
      *(us4*)(pcur + (16 * w + ln) * 40 + 16 * mi + quad * 4) = ev;
    }
    // single barrier: pS visible, kS[cur^1] DMA complete
    asm volatile("s_waitcnt vmcnt(0) lgkmcnt(0)" ::: "memory");
    __builtin_amdgcn_s_barrier();
    __builtin_amdgcn_sched_barrier(0);

    __builtin_amdgcn_s_setprio(1);
#pragma unroll
    for (int fh = 0; fh < 4; fh++) {
      short8 a = *(const short8*)(pcur + (16 * fh + ln) * 40 + quad * 8);
#pragma unroll
      for (int ei = 0; ei < 4; ei++)
        acc[fh][ei] = __builtin_amdgcn_mfma_f32_16x16x32_bf16(a, bfr[ei], acc[fh][ei], 0, 0, 0);
    }
    __builtin_amdgcn_s_setprio(0);
    cur ^= 1;
  }
  __syncthreads();

#pragma unroll
  for (int fh = 0; fh < 4; fh++) {
    const int ft32 = 2 * ft + (fh >> 1);
    const int f32b = 16 * (fh & 1) + quad * 4;
#pragma unroll
    for (int ei = 0; ei < 4; ei++) {
      int e = 64 * w + 16 * ei + ln;
      us4 cv;
#pragma unroll
      for (int r = 0; r < 4; r++) cv[r] = f2bu(acc[fh][ei][r]);
      *(us4*)(&ctxQ[((long)(bz * FT32 + ft32) * 256 + e) * 32 + f32b]) = cv;
    }
  }

  // csR: column sum over this block's 64 f-rows per e (raw; invalid f = 0)
#pragma unroll
  for (int ei = 0; ei < 4; ei++) {
    float col = 0.f;
#pragma unroll
    for (int fh = 0; fh < 4; fh++)
#pragma unroll
      for (int r = 0; r < 4; r++) col += acc[fh][ei][r];
    col += __shfl_xor(col, 16);
    col += __shfl_xor(col, 32);
    if (quad == 0) atomicAdd(&csR[(long)bz * 256 + 64 * w + 16 * ei + ln], col);
  }

  float s = ksumP;
  s += __shfl_xor(s, 16); s += __shfl_xor(s, 32);
  if (quad == 0 && fv) ksumE[(long)bz * NBF + fmine] = s;
  // ktotR: sum of raw ksum over this block's f-rows (invalid-f lanes: s==0)
  float s2 = s;
  s2 += __shfl_xor(s2, 1); s2 += __shfl_xor(s2, 2);
  s2 += __shfl_xor(s2, 4); s2 += __shfl_xor(s2, 8);
  if (l == 0) atomicAdd(&ktotR[bz], s2);

  float m = mP;
#pragma unroll
  for (int off = 1; off < 64; off <<= 1) m = fmaxf(m, __shfl_xor(m, off));
  if (l == 0) wredM[w] = m;
  __syncthreads();
  if (t == 0)
    mpart[bz * 23 + ft] = fmaxf(fmaxf(wredM[0], wredM[1]), fmaxf(wredM[2], wredM[3]));
}

__global__ __launch_bounds__(64)
void mk_reduce(const float* __restrict__ mpart, float* __restrict__ mk)
{
  int bz = blockIdx.x, l = threadIdx.x;
  float m = (l < 23) ? mpart[bz * 23 + l] : -1e30f;
#pragma unroll
  for (int off = 32; off > 0; off >>= 1) m = fmaxf(m, __shfl_down(m, off));
  if (l == 0) mk[bz] = m;
}

// ------------------------------------------------------------------
// Query-side fused v7: reads RAW ctxQ/ksumE; ctx_finQ + ksum_fin are
// folded algebraically:
//   ctxF = emk*ctxR + EPS*Sv[e],  ksumF = emk*ksumR + NC*EPS
//   A    = c*sE + NBF*EPS                        (sE = sum_f E_q)
//   num  = emk*(c*accR + EPS*csR[e]) + EPS*Sv[e]*A
//   den  = emk*(c*stR  + EPS*ktotR) + NC*EPS*A
// One fewer bf16 rounding on the ctx path; ~96MB HBM traffic deleted.
// ------------------------------------------------------------------
__global__ __launch_bounds__(256)
void q_fused_mfma(const bf16* __restrict__ q, const bf16* __restrict__ projB,
                  const float* __restrict__ diagq, const bf16* __restrict__ ctxQ,
                  const float* __restrict__ ksum, const float* __restrict__ Sv,
                  const float* __restrict__ csR, const float* __restrict__ ktotR,
                  const float* __restrict__ mk, bf16* __restrict__ merged)
{
  __shared__ alignas(16) bf16 projS[2][32 * 256];
  __shared__ alignas(16) bf16 eS[64 * 40];
  __shared__ float dS[64];
  __shared__ float svS[256];
  __shared__ float crS[256];
  __shared__ float sS[64];
  __shared__ float mS[64];
  __shared__ float seS[64];

  const int bz = blockIdx.x, nt = blockIdx.y, t = threadIdx.x;
  const int w = t >> 6, l = t & 63, quad = l >> 4, ln = l & 15;
  const int tq = bz / H_, hh = bz % H_;
  const bf16* cqb = ctxQ + (long)bz * FT32 * 256 * 32;
  const bf16* qb = q + ((long)bz * NT + nt * 64) * 256;
  const float emk = __expf(-mk[bz]);

  auto stage_proj = [&](int buf, int f0n) {
#pragma unroll
    for (int j = 0; j < 4; j++) {
      int row = 8 * w + 2 * j + (l >> 5);
      int cc = (l & 31) ^ (row & 7);
      async_copy16(projB + (long)(f0n + row) * 256 + cc * 8,
                   &projS[buf][(8 * w + 2 * j) * 256]);
    }
  };
  stage_proj(0, 0);

  // q fragments: no ft dependence -> load once, keep in 32 VGPRs
  short8 qf[8];
  {
    const bf16* qrow = qb + (long)(16 * w + ln) * 256;
#pragma unroll
    for (int kc = 0; kc < 8; kc++)
      qf[kc] = *(const short8*)(qrow + kc * 32 + quad * 8);
  }
  if (t < 64) dS[t] = diagq[(long)bz * NT + nt * 64 + t];
  svS[t] = Sv[bz * 256 + t];
  crS[t] = csR[bz * 256 + t];

  f32x4 acc[4][4] = {};           // [mh][ei]: rows 16mh+quad*4+r, e=16(4w+ei)+ln
  float sPart[4] = {0.f, 0.f, 0.f, 0.f};   // stR partial (rows 16w+quad*4+r)
  float sEp[4] = {0.f, 0.f, 0.f, 0.f};     // sE partial
  float mPart[4] = {0.f, 0.f, 0.f, 0.f};
  __syncthreads();   // full drain: projS[0] + LDS scalars ready

  for (int ft = 0; ft < FT32; ft++) {
    const int f0 = ft * 32;
    const bf16* pcur = &projS[ft & 1][0];
    short8 cfr[4];
#pragma unroll
    for (int i = 0; i < 4; i++) {
      int e = 16 * (4 * w + i) + ln;
      cfr[i] = *(const short8*)(cqb + ((long)ft * 256 + e) * 32 + quad * 8);
    }
    const float kv0 = (f0 + ln < NBF) ? ksum[(long)bz * NBF + f0 + ln] : 0.f;
    const float kv1 = (f0 + 16 + ln < NBF) ? ksum[(long)bz * NBF + f0 + 16 + ln] : 0.f;
    if (ft + 1 < FT32) stage_proj((ft + 1) & 1, f0 + 32);

    // Phase A: wave w owns rows 16w..16w+15, both f-halves
    f32x4 dd0 = {}, dd1 = {};
#pragma unroll
    for (int kc = 0; kc < 8; kc++) {
      const int co = ((kc * 4 + quad) ^ (ln & 7)) << 3;
      short8 b0 = *(const short8*)(pcur + ln * 256 + co);
      dd0 = __builtin_amdgcn_mfma_f32_16x16x32_bf16(qf[kc], b0, dd0, 0, 0, 0);
      short8 b1 = *(const short8*)(pcur + (16 + ln) * 256 + co);
      dd1 = __builtin_amdgcn_mfma_f32_16x16x32_bf16(qf[kc], b1, dd1, 0, 0, 0);
    }
    const bool fv0 = (f0 + ln) < NBF;
    const bool fv1 = (f0 + 16 + ln) < NBF;
#pragma unroll
    for (int r = 0; r < 4; r++) {
      float E0 = fv0 ? __expf(fminf(DN * dd0[r], 80.f)) : 0.f;
      float E1 = fv1 ? __expf(fminf(DN * dd1[r], 80.f)) : 0.f;
      bf16 h0 = __float2bfloat16(E0), h1v = __float2bfloat16(E1);
      float e0 = tofloat(h0), e1 = tofloat(h1v);
      eS[(16 * w + quad * 4 + r) * 40 + ln] = h0;
      eS[(16 * w + quad * 4 + r) * 40 + 16 + ln] = h1v;
      sPart[r] += e0 * kv0 + e1 * kv1;
      sEp[r] += e0 + e1;
      mPart[r] = fmaxf(mPart[r], fmaxf(e0, e1));
    }
    // mid barrier: eS writes visible; proj prefetch stays in flight
    asm volatile("s_waitcnt lgkmcnt(0)" ::: "memory");
    __builtin_amdgcn_s_barrier();
    __builtin_amdgcn_sched_barrier(0);

    // Phase B: all 4 m-halves, 4 e-tiles each (cfr reused)
#pragma unroll
    for (int mh = 0; mh < 4; mh++) {
      short8 a = *(const short8*)(&eS[(16 * mh + ln) * 40 + quad * 8]);
#pragma unroll
      for (int i = 0; i < 4; i++)
        acc[mh][i] = __builtin_amdgcn_mfma_f32_16x16x32_bf16(a, cfr[i], acc[mh][i], 0, 0, 0);
    }
    // end barrier: next projS buffer complete (vmcnt covers global_load_lds)
    asm volatile("s_waitcnt vmcnt(0) lgkmcnt(0)" ::: "memory");
    __builtin_amdgcn_s_barrier();
    __builtin_amdgcn_sched_barrier(0);
  }
  __syncthreads();

  // wave-private row stats: reduce over 16 lanes
#pragma unroll
  for (int r = 0; r < 4; r++) {
    float s = sPart[r], m = mPart[r], se = sEp[r];
#pragma unroll
    for (int off = 1; off < 16; off <<= 1) {
      s += __shfl_xor(s, off);
      m = fmaxf(m, __shfl_xor(m, off));
      se += __shfl_xor(se, off);
    }
    if (ln == 0) {
      sS[16 * w + quad * 4 + r] = s;
      mS[16 * w + quad * 4 + r] = m;
      seS[16 * w + quad * 4 + r] = se;
    }
  }
  __syncthreads();

  const float ktotv = ktotR[bz];
#pragma unroll
  for (int mh = 0; mh < 4; mh++) {
#pragma unroll
    for (int r = 0; r < 4; r++) {
      int row = 16 * mh + quad * 4 + r;
      float st = sS[row];
      float se = seS[row];
      float mt = fmaxf(mS[row], 1e-30f);
      float c = __expf(-dS[row]) / mt;
      float A = c * se + (float)NBF * EPS_;
      float den = emk * (c * st + EPS_ * ktotv) + (float)NC * EPS_ * A;
      float inv = 1.f / den;
#pragma unroll
      for (int i = 0; i < 4; i++) {
        int e = 16 * (4 * w + i) + ln;
        float val = (emk * (c * acc[mh][i][r] + EPS_ * crS[e]) + EPS_ * svS[e] * A) * inv;
        merged[((long)tq * NT + nt * 64 + row) * 2048 + hh * 256 + e] =
            __float2bfloat16(val);
      }
    }
  }
}

// ------------------------------------------------------------------
extern "C" void kernel_launch(void* const* d_in, const int* in_sizes, int n_in,
                              void* d_out, int out_size, void* d_ws, size_t ws_size,
                              hipStream_t stream)
{
  const void* x_ctx = d_in[0];
  const void* label = d_in[1];
  const void* x_tgt = d_in[2];
  const void* W1 = d_in[3];
  const void* b1 = d_in[4];
  const void* W2 = d_in[5];
  const void* b2 = d_in[6];
  const void* W3 = d_in[7];
  const void* b3 = d_in[8];
  const void* Wk = d_in[9];
  const void* bk = d_in[10];
  const void* Wv = d_in[11];
  const void* bv = d_in[12];
  const void* Wq = d_in[13];
  const void* bq = d_in[14];
  const void* Wo = d_in[15];
  const void* bo = d_in[16];
  const void* Wmu = d_in[17];
  const void* bmu = d_in[18];
  const void* proj = d_in[19];

  // Arena (floats), peak ~89 MB. Overlays:
  //  xcB @ F2+1572864 (after cf; dead before ctxQ is written by key_fused)
  //  xtB @ F1 (vQ region; vQ dead after key_fused, merged written after q-proj)
  float* W = (float*)d_ws;
  const long F0 = 0, F1 = 4194304, F2 = 8388608;
  const long CTXQ_F = (long)64 * FT32 * 256 * 32 / 2;
  const long F3 = F2 + CTXQ_F;
  bf16* kB = (bf16*)(W + F0);
  bf16* qB = (bf16*)(W + F0);
  bf16* rep = (bf16*)(W + F0);
  bf16* vQ = (bf16*)(W + F1);
  bf16* merged = (bf16*)(W + F1);
  bf16* xtB = (bf16*)(W + F1);
  bf16* h1 = (bf16*)(W + F2);
  bf16* h2 = (bf16*)(W + F2 + 524288);
  bf16* cf = (bf16*)(W + F2 + 1048576);
  bf16* xcB = (bf16*)(W + F2 + 1572864);
  bf16* ctxQ = (bf16*)(W + F2);
  float* woP = W + F2;
  long o = F3;
  auto alloc = [&](long n) { float* p = W + o; o += n; return p; };
  float* zbase = W + o;
  float* dgk = alloc(32768);
  float* dgq = alloc(32768);
  float* Sv = alloc(64 * 256);
  float* csR = alloc(64 * 256);
  float* ktotR = alloc(64);
  alloc(192);
  float* ksumE = alloc((long)64 * NBF);
  float* mpart = alloc(64 * 23);
  float* mk = alloc(64);
  int* dtFlag = (int*)alloc(64);
  bf16* projB = (bf16*)alloc((long)FT32 * 32 * 256 / 2);
  bf16* WkT = (bf16*)alloc(262144);   // 8 x 256 x 256 bf16
  bf16* WvT = (bf16*)alloc(262144);
  bf16* WqT = (bf16*)alloc(262144);
  bf16* WoT = (bf16*)alloc(262144);   // 256 x 2048 bf16 (perm folded)
  bf16* W1T = (bf16*)alloc(32768);    // 256 x 256 bf16
  bf16* W2T = (bf16*)alloc(32768);
  bf16* W3T = (bf16*)alloc(32768);
  bf16* WmuT = (bf16*)alloc(32768);
  (void)ws_size; (void)in_sizes; (void)n_in; (void)out_size;

  const dim3 B(256);
  detect_dtype<<<1, B, 0, stream>>>(x_ctx, dtFlag);
  conv_proj<<<FT32 * 32, B, 0, stream>>>(proj, projB, dtFlag);
  conv_wT<<<dim3(64, 8, 29), B, 0, stream>>>(Wk, Wv, Wq, Wo, W1, W2, W3, Wmu,
                                             WkT, WvT, WqT, WoT, W1T, W2T, W3T, WmuT, dtFlag);
  conv_bf16<<<4096, B, 0, stream>>>(x_ctx, xcB, dtFlag);
  init_zero<<<385, B, 0, stream>>>(zbase);
  // 1. task-encoder MLP (unified async gemm)
  gemm_mfma<<<dim3(4, 64, 1), B, 0, stream>>>(
      xcB, W1T, nullptr, h1, 1, 0, 0, dtFlag, nullptr, nullptr,
      4096, 256, 256, 0L, 1, 0L, 1, 0L);
  fixup_h1<<<4096, B, 0, stream>>>(h1, label, W1, b1, dtFlag);
  gemm_mfma<<<dim3(4, 64, 1), B, 0, stream>>>(
      h1, W2T, b2, h2, 1, 2, 0, dtFlag, nullptr, nullptr,
      4096, 256, 256, 0L, 1, 0L, 1, 0L);
  gemm_mfma<<<dim3(4, 64, 1), B, 0, stream>>>(
      h2, W3T, b3, cf, 1, 2, 0, dtFlag, nullptr, nullptr,
      4096, 256, 256, 0L, 1, 0L, 1, 0L);
  // 2. k projection (fused diag), v projection (tiled -> vQ, fused Sv)
  gemm_mfma<<<dim3(4, 8, 64), B, 0, stream>>>(
      xcB, WkT, bk, kB, 1, 1, 0, dtFlag, dgk, nullptr,
      512, 256, 256, 131072L, 8, 65536L, 8, 256L);
  gemm_mfma<<<dim3(4, 8, 64), B, 0, stream>>>(
      cf, WvT, bv, vQ, 1, 1, 2, dtFlag, nullptr, Sv,
      512, 256, 256, 131072L, 8, 65536L, 8, 256L);
  // 3. key side (also emits raw csR / ktotR reductions)
  key_fused_mfma<<<dim3(64, 23), B, 0, stream>>>(kB, vQ, projB, dgk, ksumE, ctxQ,
                                                 mpart, csR, ktotR);
  mk_reduce<<<64, 64, 0, stream>>>(mpart, mk);
  // 4. q projection (fused diag); xtB converted now (vQ region is dead)
  conv_bf16<<<4096, B, 0, stream>>>(x_tgt, xtB, dtFlag);
  gemm_mfma<<<dim3(4, 8, 64), B, 0, stream>>>(
      xtB, WqT, bq, qB, 1, 1, 0, dtFlag, dgq, nullptr,
      512, 256, 256, 131072L, 8, 65536L, 8, 256L);
  // 5. query side (finalize folded in) -> merged [t][n][h][e]
  q_fused_mfma<<<dim3(64, 8), B, 0, stream>>>(qB, projB, dgq, ctxQ, ksumE,
                                              Sv, csR, ktotR, mk, merged);
  // 6. Wo split-K x2 -> fp32 partials, reduce, Wmu
  gemm_wo_splitk<<<dim3(4, 64, 2), B, 0, stream>>>(merged, WoT, woP, 4096, 256, 2048);
  reduce_partials<<<4096, B, 0, stream>>>(woP, bo, rep, dtFlag);
  gemm_mfma<<<dim3(4, 64, 1), B, 0, stream>>>(
      rep, WmuT, bmu, d_out, 2, 1, 0, dtFlag, nullptr, nullptr,
      4096, 256, 256, 0L, 1, 0L, 1, 0L);
}

// Round 8
// 403.153 us; speedup vs baseline: 1.8425x; 1.0366x over previous
//
#include <hip/hip_runtime.h>
#include <hip/hip_bf16.h>

typedef __hip_bfloat16 bf16;
typedef __attribute__((ext_vector_type(8))) short short8;
typedef __attribute__((ext_vector_type(4))) float f32x4;
typedef __attribute__((ext_vector_type(4))) unsigned short us4;
#define DEV __device__ __forceinline__

static constexpr int T_ = 8, NC = 512, NT = 512, D_ = 256, H_ = 8, NBF = 1419;
static constexpr int FT32 = 46;             // 46 f-tiles of 32 (padded 1472)
static constexpr float EPS_ = 1e-4f;
static constexpr float DN = 0.25f;          // D^-0.25
static constexpr float DIAG_SC = 0.03125f;  // 0.5 * DN^2

DEV float bf2f(unsigned short u) { return __uint_as_float(((unsigned)u) << 16); }
DEV float tofloat(bf16 x) { return __bfloat162float(x); }
DEV unsigned short f2bu(float x) { bf16 h = __float2bfloat16(x); return *(unsigned short*)&h; }

DEV float ldx(const void* p, long i, int isb) {
  if (isb) return bf2f(((const unsigned short*)p)[i]);
  return ((const float*)p)[i];
}
DEV void stx(void* p, long i, float v, int isb) {
  if (isb) ((bf16*)p)[i] = __float2bfloat16(v);
  else     ((float*)p)[i] = v;
}

// async global->LDS 16B (wave-uniform LDS base + lane*16; global addr per-lane)
DEV void async_copy16(const void* g, void* lds) {
  __builtin_amdgcn_global_load_lds(
      (const __attribute__((address_space(1))) unsigned int*)g,
      (__attribute__((address_space(3))) unsigned int*)lds, 16, 0, 0);
}

// ------------------------------------------------------------------
// dtype probe (1 = bf16 inputs, 0 = fp32)
// ------------------------------------------------------------------
__global__ __launch_bounds__(256)
void detect_dtype(const void* __restrict__ x, int* __restrict__ flag)
{
  __shared__ int bad;
  if (threadIdx.x == 0) bad = 0;
  __syncthreads();
  int mybad = 0;
  for (int j = 0; j < 16; j++) {
    long i = 2L * (threadIdx.x + 256L * j);
    unsigned short u = ((const unsigned short*)x)[i];
    int e = (u >> 7) & 0xff, mant = u & 0x7f;
    bool b = (e == 0xff) || (e >= 141) || (e <= 93 && !(e == 0 && mant == 0));
    mybad += b ? 1 : 0;
  }
  atomicAdd(&bad, mybad);
  __syncthreads();
  if (threadIdx.x == 0) *flag = (bad > 1024) ? 0 : 1;
}

// proj -> bf16 [FT32*32][256], zero rows past NBF
__global__ __launch_bounds__(256)
void conv_proj(const void* __restrict__ proj, bf16* __restrict__ projB,
               const int* __restrict__ dtFlag)
{
  const int fl = *dtFlag;
  int f = blockIdx.x, t = threadIdx.x;
  float v = (f < NBF) ? ldx(proj, (long)f * 256 + t, fl) : 0.f;
  projB[(long)f * 256 + t] = __float2bfloat16(v);
}

// generic activation convert -> bf16 (1M elements, grid 4096)
__global__ __launch_bounds__(256)
void conv_bf16(const void* __restrict__ src, bf16* __restrict__ dst,
               const int* __restrict__ dtFlag)
{
  const int fl = *dtFlag;
  long i = (long)blockIdx.x * 256 + threadIdx.x;
  dst[i] = __float2bfloat16(ldx(src, i, fl));
}

// ------------------------------------------------------------------
// Weight pre-transpose: W[k][n] -> WT[n][k] bf16. Wo folds the merged
// k-permutation. Grid (64,8,29): z 0..7 Wk, 8..15 Wv, 16..23 Wq,
// 24 Wo (kt 0..63), 25 W1, 26 W2, 27 W3, 28 Wmu.
// ------------------------------------------------------------------
__global__ __launch_bounds__(256)
void conv_wT(const void* __restrict__ Wk, const void* __restrict__ Wv,
             const void* __restrict__ Wq, const void* __restrict__ Wo,
             const void* __restrict__ W1, const void* __restrict__ W2,
             const void* __restrict__ W3, const void* __restrict__ Wmu,
             bf16* __restrict__ WkT, bf16* __restrict__ WvT,
             bf16* __restrict__ WqT, bf16* __restrict__ WoT,
             bf16* __restrict__ W1T, bf16* __restrict__ W2T,
             bf16* __restrict__ W3T, bf16* __restrict__ WmuT,
             const int* __restrict__ dtFlag)
{
  __shared__ float tile[32][33];
  const int fl = *dtFlag;
  const int kt = blockIdx.x, nt = blockIdx.y, z = blockIdx.z, t = threadIdx.x;
  const void* in; bf16* out; int K; int perm = 0; long off = 0;
  if (z < 8)        { in = Wk;  out = WkT;  K = 256; off = (long)z * 65536; }
  else if (z < 16)  { in = Wv;  out = WvT;  K = 256; off = (long)(z - 8) * 65536; }
  else if (z < 24)  { in = Wq;  out = WqT;  K = 256; off = (long)(z - 16) * 65536; }
  else if (z == 24) { in = Wo;  out = WoT;  K = 2048; perm = 1; }
  else if (z == 25) { in = W1;  out = W1T;  K = 256; }
  else if (z == 26) { in = W2;  out = W2T;  K = 256; }
  else if (z == 27) { in = W3;  out = W3T;  K = 256; }
  else              { in = Wmu; out = WmuT; K = 256; }
  if (K == 256 && kt >= 8) return;
  const int k0 = kt * 32, n0 = nt * 32;
  const int row = t >> 3, cb = (t & 7) * 4;
  {
    int kk = k0 + row;
    int krow = perm ? (((kk & 255) << 3) | (kk >> 8)) : kk;
#pragma unroll
    for (int j = 0; j < 4; j++)
      tile[row][cb + j] = ldx(in, off + (long)krow * 256 + n0 + cb + j, fl);
  }
  __syncthreads();
  us4 o;
#pragma unroll
  for (int j = 0; j < 4; j++) o[j] = f2bu(tile[cb + j][row]);
  *(us4*)(out + off + (long)(n0 + row) * K + k0 + cb) = o;
}

// zero the atomic-target region
__global__ __launch_bounds__(256)
void init_zero(float* __restrict__ p)
{
  p[blockIdx.x * 256 + threadIdx.x] = 0.f;
}

// ------------------------------------------------------------------
// Unified MFMA GEMM v2, 64x64 tile, K-step 64 (proven round 5).
// ------------------------------------------------------------------
__global__ __launch_bounds__(256)
void gemm_mfma(const bf16* __restrict__ A, const bf16* __restrict__ BT,
               const void* __restrict__ bias,
               void* __restrict__ C, int cMode, int epi, int cT,
               const int* __restrict__ dtFlag, float* __restrict__ diagOut,
               float* __restrict__ svOut,
               int M, int N, int K, long sA, int divA, long sB, int modB, long sBias)
{
  __shared__ alignas(16) bf16 As[2][64 * 64];
  __shared__ alignas(16) bf16 Bs[2][64 * 64];
  const int fl = *dtFlag;
  const int cB = (cMode == 2) ? fl : cMode;
  const int t = threadIdx.x;
  const int bz = blockIdx.z;
  const long aOff = (long)(bz / divA) * sA;
  const long bOff = (long)(bz % modB) * sB;
  const long biasOff = (long)(bz % modB) * sBias;
  const long cOff = (long)bz * (long)M * N;
  const int m0 = blockIdx.y * 64, n0 = blockIdx.x * 64;
  const int w = t >> 6, l = t & 63, quad = l >> 4, ln = l & 15;
  const bf16* Ab = A + aOff + (long)m0 * K;
  const bf16* Bb = BT + bOff + (long)n0 * K;
  const int srow = l >> 3;            // 0..7 within the wave's 8-row slab
  const int scc = (l & 7) ^ srow;     // XOR swizzle chunk (row&7 == srow)
  f32x4 acc[4] = {};

  auto stage = [&](int buf, int k0) {
#pragma unroll
    for (int j = 0; j < 2; j++) {
      const int rbase = 32 * j + 8 * w;         // rbase&7 == 0
      const int row = rbase + srow;
      async_copy16(Ab + (long)row * K + k0 + scc * 8, &As[buf][rbase * 64]);
      async_copy16(Bb + (long)row * K + k0 + scc * 8, &Bs[buf][rbase * 64]);
    }
  };

  stage(0, 0);
  __syncthreads();   // full drain: buffer 0 ready

  int cur = 0;
  for (int k0 = 0; k0 < K; k0 += 64) {
    if (k0 + 64 < K) stage(cur ^ 1, k0 + 64);
    const bf16* Ac = &As[cur][0];
    const bf16* Bc = &Bs[cur][0];
    const int arow = 16 * w + ln;
#pragma unroll
    for (int ks = 0; ks < 2; ks++) {
      short8 a = *(const short8*)(Ac + arow * 64 + (((ks * 4 + quad) ^ (arow & 7)) << 3));
#pragma unroll
      for (int i = 0; i < 4; i++) {
        const int brow = 16 * i + ln;
        short8 b = *(const short8*)(Bc + brow * 64 + (((ks * 4 + quad) ^ (brow & 7)) << 3));
        acc[i] = __builtin_amdgcn_mfma_f32_16x16x32_bf16(a, b, acc[i], 0, 0, 0);
      }
    }
    asm volatile("s_waitcnt vmcnt(0)" ::: "memory");
    __builtin_amdgcn_s_barrier();
    __builtin_amdgcn_sched_barrier(0);
    cur ^= 1;
  }

  float s2[4] = {0.f, 0.f, 0.f, 0.f};
  if (cT == 2) {
    const int mm = m0 + 16 * w + quad * 4;
    const int tile = mm >> 5, off = mm & 31;
#pragma unroll
    for (int i = 0; i < 4; i++) {
      int n = n0 + 16 * i + ln;
      us4 cv;
      float colsum = 0.f;
#pragma unroll
      for (int r = 0; r < 4; r++) {
        float c = acc[i][r];
        if (epi >= 1) c += ldx(bias, biasOff + n, fl);
        if (epi == 2) c = fmaxf(c, 0.f);
        colsum += c;
        cv[r] = f2bu(c);
      }
      *(us4*)((bf16*)C + cOff + ((long)tile * N + n) * 32 + off) = cv;
      if (svOut) {
        colsum += __shfl_xor(colsum, 16);
        colsum += __shfl_xor(colsum, 32);
        if (quad == 0) atomicAdd(&svOut[(long)bz * N + n], colsum);
      }
    }
  } else {
#pragma unroll
    for (int i = 0; i < 4; i++) {
#pragma unroll
      for (int r = 0; r < 4; r++) {
        int m = m0 + 16 * w + quad * 4 + r;
        int n = n0 + 16 * i + ln;
        float c = acc[i][r];
        if (epi >= 1) c += ldx(bias, biasOff + n, fl);
        if (epi == 2) c = fmaxf(c, 0.f);
        s2[r] += c * c;
        stx(C, cOff + (long)m * N + n, c, cB);
      }
    }
  }
  if (diagOut) {
#pragma unroll
    for (int r = 0; r < 4; r++) {
      float s = s2[r];
      s += __shfl_xor(s, 1); s += __shfl_xor(s, 2);
      s += __shfl_xor(s, 4); s += __shfl_xor(s, 8);
      if (ln == 0)
        atomicAdd(&diagOut[(long)bz * M + m0 + 16 * w + quad * 4 + r], DIAG_SC * s);
    }
  }
}

// ------------------------------------------------------------------
// Wo GEMM, split-K x2: partials traffic 8+8MB.
// ------------------------------------------------------------------
__global__ __launch_bounds__(256)
void gemm_wo_splitk(const bf16* __restrict__ A, const bf16* __restrict__ BT,
                    float* __restrict__ P, int M, int N, int K)
{
  __shared__ alignas(16) bf16 As[2][64 * 64];
  __shared__ alignas(16) bf16 Bs[2][64 * 64];
  const int t = threadIdx.x;
  const int z = blockIdx.z;
  const int m0 = blockIdx.y * 64, n0 = blockIdx.x * 64;
  const int w = t >> 6, l = t & 63, quad = l >> 4, ln = l & 15;
  const bf16* Ab = A + (long)m0 * K;
  const bf16* Bb = BT + (long)n0 * K;
  const int srow = l >> 3, scc = (l & 7) ^ srow;
  f32x4 acc[4] = {};
  const int kbase = z * 1024, kend = kbase + 1024;

  auto stage = [&](int buf, int k0) {
#pragma unroll
    for (int j = 0; j < 2; j++) {
      const int rbase = 32 * j + 8 * w;
      const int row = rbase + srow;
      async_copy16(Ab + (long)row * K + k0 + scc * 8, &As[buf][rbase * 64]);
      async_copy16(Bb + (long)row * K + k0 + scc * 8, &Bs[buf][rbase * 64]);
    }
  };

  stage(0, kbase);
  __syncthreads();

  int cur = 0;
  for (int k0 = kbase; k0 < kend; k0 += 64) {
    if (k0 + 64 < kend) stage(cur ^ 1, k0 + 64);
    const bf16* Ac = &As[cur][0];
    const bf16* Bc = &Bs[cur][0];
    const int arow = 16 * w + ln;
#pragma unroll
    for (int ks = 0; ks < 2; ks++) {
      short8 a = *(const short8*)(Ac + arow * 64 + (((ks * 4 + quad) ^ (arow & 7)) << 3));
#pragma unroll
      for (int i = 0; i < 4; i++) {
        const int brow = 16 * i + ln;
        short8 b = *(const short8*)(Bc + brow * 64 + (((ks * 4 + quad) ^ (brow & 7)) << 3));
        acc[i] = __builtin_amdgcn_mfma_f32_16x16x32_bf16(a, b, acc[i], 0, 0, 0);
      }
    }
    asm volatile("s_waitcnt vmcnt(0)" ::: "memory");
    __builtin_amdgcn_s_barrier();
    __builtin_amdgcn_sched_barrier(0);
    cur ^= 1;
  }

  float* Pz = P + (long)z * M * N;
#pragma unroll
  for (int i = 0; i < 4; i++) {
#pragma unroll
    for (int r = 0; r < 4; r++) {
      int m = m0 + 16 * w + quad * 4 + r;
      int n = n0 + 16 * i + ln;
      Pz[(long)m * N + n] = acc[i][r];
    }
  }
}

// rep[m][n] (bf16) = sum_z P[z][m][n] + bo[n]   (z = 2)
__global__ __launch_bounds__(256)
void reduce_partials(const float* __restrict__ P, const void* __restrict__ bo,
                     bf16* __restrict__ rep, const int* __restrict__ dtFlag)
{
  const int fl = *dtFlag;
  long idx = (long)blockIdx.x * 256 + threadIdx.x;
  int n = idx & 255;
  float s = ldx(bo, n, fl) + P[idx] + P[1048576 + idx];
  rep[idx] = __float2bfloat16(s);
}

__global__ __launch_bounds__(256)
void fixup_h1(bf16* __restrict__ h1, const void* __restrict__ label,
              const void* __restrict__ W1, const void* __restrict__ b1,
              const int* __restrict__ dtFlag)
{
  const int fl = *dtFlag;
  int idx = blockIdx.x * 256 + threadIdx.x;
  int m = idx >> 8, n = idx & 255;
  float c = tofloat(h1[idx]) + ldx(b1, n, fl);
#pragma unroll
  for (int j = 0; j < 3; j++)
    c += ldx(label, m * 3 + j, fl) * ldx(W1, (256 + j) * 256 + n, fl);
  h1[idx] = __float2bfloat16(fmaxf(c, 0.f));
}

// ------------------------------------------------------------------
// Key-side fused v8 = v5 staging (proven 87.7-88.2us across 3 rounds:
// kS[3] triple-buffer, stage distance 2, ONE barrier/iter with counted
// vmcnt(4) lgkmcnt(0), pS[2], setprio on MFMA clusters) + v7 epilogue
// (raw csR/ktotR reductions replacing ctx_finQ/ksum_fin).
// Round-6 lesson: distance-1/vmcnt(0) exposed staging latency (+30us);
// LDS-occupancy theory falsified (residency not LDS-capped).
// ------------------------------------------------------------------
__global__ __launch_bounds__(256)
void key_fused_mfma(const bf16* __restrict__ k, const bf16* __restrict__ vQ,
                    const bf16* __restrict__ projB, const float* __restrict__ diagk,
                    float* __restrict__ ksumE, bf16* __restrict__ ctxQ,
                    float* __restrict__ mpart, float* __restrict__ csR,
                    float* __restrict__ ktotR)
{
  __shared__ alignas(16) bf16 kS[3][32 * 256];
  __shared__ alignas(16) bf16 pS[2][64 * 40];
  __shared__ float wredM[4];

  const int bz = blockIdx.x, ft = blockIdx.y, f0 = ft * 64;
  const int t = threadIdx.x;
  const int w = t >> 6, l = t & 63, quad = l >> 4, ln = l & 15;
  const int fmine = f0 + 16 * w + ln;
  const bool fv = fmine < NBF;

  const bf16* kb = k + (long)bz * NC * 256;
  const bf16* vqb = vQ + (long)bz * 16 * 256 * 32;
  const float* db = diagk + bz * NC;

  auto stage = [&](int buf, int n0) {
#pragma unroll
    for (int j = 0; j < 4; j++) {
      int row = w * 8 + j * 2 + (l >> 5);
      int cc = (l & 31) ^ ((2 * j + (l >> 5)) & 7);   // = (l&31) ^ (row&7)
      async_copy16(kb + (long)(n0 + row) * 256 + cc * 8,
                   &kS[buf][w * 2048 + j * 512]);
    }
  };
  stage(0, 0);
  stage(1, 32);

  short8 pf[8];
  {
    const bf16* prow = projB + (long)fmine * 256;
#pragma unroll
    for (int kc = 0; kc < 8; kc++)
      pf[kc] = *(const short8*)(prow + kc * 32 + quad * 8);
  }

  f32x4 acc[4][4] = {};
  float ksumP = 0.f, mP = -1e30f;

  __syncthreads();   // full drain once: kS[0], kS[1] + pf ready

  int cur = 0;       // buffer holding tile `it`
  for (int it = 0; it < 16; it++) {
    const int n0 = it * 32;
    short8 bfr[4];
#pragma unroll
    for (int ei = 0; ei < 4; ei++) {
      int e = 64 * w + 16 * ei + ln;
      bfr[ei] = *(const short8*)(vqb + ((long)it * 256 + e) * 32 + quad * 8);
    }
    f32x4 dv0 = *(const f32x4*)(db + n0 + quad * 4);
    f32x4 dv1 = *(const f32x4*)(db + n0 + 16 + quad * 4);
    __builtin_amdgcn_sched_barrier(0);
    if (it + 2 < 16) {
      int nb = cur + 2; if (nb >= 3) nb -= 3;
      stage(nb, n0 + 64);
    }
    __builtin_amdgcn_sched_barrier(0);

    const bf16* kcur = &kS[cur][0];
    f32x4 dd[2][2] = {};
    __builtin_amdgcn_s_setprio(1);
#pragma unroll
    for (int kc = 0; kc < 8; kc++) {
      const int hf = kc & 1;
#pragma unroll
      for (int mi = 0; mi < 2; mi++) {
        short8 a = *(const short8*)(kcur + (16 * mi + ln) * 256 +
                                    (((kc * 4 + quad) ^ (ln & 7)) << 3));
        dd[mi][hf] = __builtin_amdgcn_mfma_f32_16x16x32_bf16(a, pf[kc], dd[mi][hf], 0, 0, 0);
      }
    }
    __builtin_amdgcn_s_setprio(0);
    bf16* pcur = &pS[it & 1][0];
#pragma unroll
    for (int mi = 0; mi < 2; mi++) {
      us4 ev;
      f32x4 dvv = mi ? dv1 : dv0;
#pragma unroll
      for (int r = 0; r < 4; r++) {
        float sc = DN * (dd[mi][0][r] + dd[mi][1][r]);
        float E = fv ? __expf(fminf(sc - dvv[r], 80.f)) : 0.f;
        unsigned short u = f2bu(E);
        ksumP += bf2f(u);
        if (fv) mP = fmaxf(mP, sc);
        ev[r] = u;
      }
      *(us4*)(pcur + (16 * w + ln) * 40 + 16 * mi + quad * 4) = ev;
    }
    // single barrier: pS visible (lgkmcnt 0), kS[it+1] complete (vmcnt 4:
    // everything older than the 4 stage(it+2) DMAs is done)
    asm volatile("s_waitcnt vmcnt(4) lgkmcnt(0)" ::: "memory");
    __builtin_amdgcn_s_barrier();
    __builtin_amdgcn_sched_barrier(0);

    __builtin_amdgcn_s_setprio(1);
#pragma unroll
    for (int fh = 0; fh < 4; fh++) {
      short8 a = *(const short8*)(pcur + (16 * fh + ln) * 40 + quad * 8);
#pragma unroll
      for (int ei = 0; ei < 4; ei++)
        acc[fh][ei] = __builtin_amdgcn_mfma_f32_16x16x32_bf16(a, bfr[ei], acc[fh][ei], 0, 0, 0);
    }
    __builtin_amdgcn_s_setprio(0);
    cur = (cur == 2) ? 0 : cur + 1;
  }
  __syncthreads();

#pragma unroll
  for (int fh = 0; fh < 4; fh++) {
    const int ft32 = 2 * ft + (fh >> 1);
    const int f32b = 16 * (fh & 1) + quad * 4;
#pragma unroll
    for (int ei = 0; ei < 4; ei++) {
      int e = 64 * w + 16 * ei + ln;
      us4 cv;
#pragma unroll
      for (int r = 0; r < 4; r++) cv[r] = f2bu(acc[fh][ei][r]);
      *(us4*)(&ctxQ[((long)(bz * FT32 + ft32) * 256 + e) * 32 + f32b]) = cv;
    }
  }

  // csR: column sum over this block's 64 f-rows per e (raw; invalid f = 0)
#pragma unroll
  for (int ei = 0; ei < 4; ei++) {
    float col = 0.f;
#pragma unroll
    for (int fh = 0; fh < 4; fh++)
#pragma unroll
      for (int r = 0; r < 4; r++) col += acc[fh][ei][r];
    col += __shfl_xor(col, 16);
    col += __shfl_xor(col, 32);
    if (quad == 0) atomicAdd(&csR[(long)bz * 256 + 64 * w + 16 * ei + ln], col);
  }

  float s = ksumP;
  s += __shfl_xor(s, 16); s += __shfl_xor(s, 32);
  if (quad == 0 && fv) ksumE[(long)bz * NBF + fmine] = s;
  // ktotR: sum of raw ksum over this block's f-rows (invalid-f lanes: s==0)
  float s2 = s;
  s2 += __shfl_xor(s2, 1); s2 += __shfl_xor(s2, 2);
  s2 += __shfl_xor(s2, 4); s2 += __shfl_xor(s2, 8);
  if (l == 0) atomicAdd(&ktotR[bz], s2);

  float m = mP;
#pragma unroll
  for (int off = 1; off < 64; off <<= 1) m = fmaxf(m, __shfl_xor(m, off));
  if (l == 0) wredM[w] = m;
  __syncthreads();
  if (t == 0)
    mpart[bz * 23 + ft] = fmaxf(fmaxf(wredM[0], wredM[1]), fmaxf(wredM[2], wredM[3]));
}

__global__ __launch_bounds__(64)
void mk_reduce(const float* __restrict__ mpart, float* __restrict__ mk)
{
  int bz = blockIdx.x, l = threadIdx.x;
  float m = (l < 23) ? mpart[bz * 23 + l] : -1e30f;
#pragma unroll
  for (int off = 32; off > 0; off >>= 1) m = fmaxf(m, __shfl_down(m, off));
  if (l == 0) mk[bz] = m;
}

// ------------------------------------------------------------------
// Query-side fused v7 (kept): reads RAW ctxQ/ksumE; finalizes folded:
//   A    = c*sE + NBF*EPS                        (sE = sum_f E_q)
//   num  = emk*(c*accR + EPS*csR[e]) + EPS*Sv[e]*A
//   den  = emk*(c*stR  + EPS*ktotR) + NC*EPS*A
// ------------------------------------------------------------------
__global__ __launch_bounds__(256)
void q_fused_mfma(const bf16* __restrict__ q, const bf16* __restrict__ projB,
                  const float* __restrict__ diagq, const bf16* __restrict__ ctxQ,
                  const float* __restrict__ ksum, const float* __restrict__ Sv,
                  const float* __restrict__ csR, const float* __restrict__ ktotR,
                  const float* __restrict__ mk, bf16* __restrict__ merged)
{
  __shared__ alignas(16) bf16 projS[2][32 * 256];
  __shared__ alignas(16) bf16 eS[64 * 40];
  __shared__ float dS[64];
  __shared__ float svS[256];
  __shared__ float crS[256];
  __shared__ float sS[64];
  __shared__ float mS[64];
  __shared__ float seS[64];

  const int bz = blockIdx.x, nt = blockIdx.y, t = threadIdx.x;
  const int w = t >> 6, l = t & 63, quad = l >> 4, ln = l & 15;
  const int tq = bz / H_, hh = bz % H_;
  const bf16* cqb = ctxQ + (long)bz * FT32 * 256 * 32;
  const bf16* qb = q + ((long)bz * NT + nt * 64) * 256;
  const float emk = __expf(-mk[bz]);

  auto stage_proj = [&](int buf, int f0n) {
#pragma unroll
    for (int j = 0; j < 4; j++) {
      int row = 8 * w + 2 * j + (l >> 5);
      int cc = (l & 31) ^ (row & 7);
      async_copy16(projB + (long)(f0n + row) * 256 + cc * 8,
                   &projS[buf][(8 * w + 2 * j) * 256]);
    }
  };
  stage_proj(0, 0);

  // q fragments: no ft dependence -> load once, keep in 32 VGPRs
  short8 qf[8];
  {
    const bf16* qrow = qb + (long)(16 * w + ln) * 256;
#pragma unroll
    for (int kc = 0; kc < 8; kc++)
      qf[kc] = *(const short8*)(qrow + kc * 32 + quad * 8);
  }
  if (t < 64) dS[t] = diagq[(long)bz * NT + nt * 64 + t];
  svS[t] = Sv[bz * 256 + t];
  crS[t] = csR[bz * 256 + t];

  f32x4 acc[4][4] = {};           // [mh][ei]: rows 16mh+quad*4+r, e=16(4w+ei)+ln
  float sPart[4] = {0.f, 0.f, 0.f, 0.f};   // stR partial (rows 16w+quad*4+r)
  float sEp[4] = {0.f, 0.f, 0.f, 0.f};     // sE partial
  float mPart[4] = {0.f, 0.f, 0.f, 0.f};
  __syncthreads();   // full drain: projS[0] + LDS scalars ready

  for (int ft = 0; ft < FT32; ft++) {
    const int f0 = ft * 32;
    const bf16* pcur = &projS[ft & 1][0];
    short8 cfr[4];
#pragma unroll
    for (int i = 0; i < 4; i++) {
      int e = 16 * (4 * w + i) + ln;
      cfr[i] = *(const short8*)(cqb + ((long)ft * 256 + e) * 32 + quad * 8);
    }
    const float kv0 = (f0 + ln < NBF) ? ksum[(long)bz * NBF + f0 + ln] : 0.f;
    const float kv1 = (f0 + 16 + ln < NBF) ? ksum[(long)bz * NBF + f0 + 16 + ln] : 0.f;
    if (ft + 1 < FT32) stage_proj((ft + 1) & 1, f0 + 32);

    // Phase A: wave w owns rows 16w..16w+15, both f-halves
    f32x4 dd0 = {}, dd1 = {};
#pragma unroll
    for (int kc = 0; kc < 8; kc++) {
      const int co = ((kc * 4 + quad) ^ (ln & 7)) << 3;
      short8 b0 = *(const short8*)(pcur + ln * 256 + co);
      dd0 = __builtin_amdgcn_mfma_f32_16x16x32_bf16(qf[kc], b0, dd0, 0, 0, 0);
      short8 b1 = *(const short8*)(pcur + (16 + ln) * 256 + co);
      dd1 = __builtin_amdgcn_mfma_f32_16x16x32_bf16(qf[kc], b1, dd1, 0, 0, 0);
    }
    const bool fv0 = (f0 + ln) < NBF;
    const bool fv1 = (f0 + 16 + ln) < NBF;
#pragma unroll
    for (int r = 0; r < 4; r++) {
      float E0 = fv0 ? __expf(fminf(DN * dd0[r], 80.f)) : 0.f;
      float E1 = fv1 ? __expf(fminf(DN * dd1[r], 80.f)) : 0.f;
      bf16 h0 = __float2bfloat16(E0), h1v = __float2bfloat16(E1);
      float e0 = tofloat(h0), e1 = tofloat(h1v);
      eS[(16 * w + quad * 4 + r) * 40 + ln] = h0;
      eS[(16 * w + quad * 4 + r) * 40 + 16 + ln] = h1v;
      sPart[r] += e0 * kv0 + e1 * kv1;
      sEp[r] += e0 + e1;
      mPart[r] = fmaxf(mPart[r], fmaxf(e0, e1));
    }
    // mid barrier: eS writes visible; proj prefetch stays in flight
    asm volatile("s_waitcnt lgkmcnt(0)" ::: "memory");
    __builtin_amdgcn_s_barrier();
    __builtin_amdgcn_sched_barrier(0);

    // Phase B: all 4 m-halves, 4 e-tiles each (cfr reused)
#pragma unroll
    for (int mh = 0; mh < 4; mh++) {
      short8 a = *(const short8*)(&eS[(16 * mh + ln) * 40 + quad * 8]);
#pragma unroll
      for (int i = 0; i < 4; i++)
        acc[mh][i] = __builtin_amdgcn_mfma_f32_16x16x32_bf16(a, cfr[i], acc[mh][i], 0, 0, 0);
    }
    // end barrier: next projS buffer complete (vmcnt covers global_load_lds)
    asm volatile("s_waitcnt vmcnt(0) lgkmcnt(0)" ::: "memory");
    __builtin_amdgcn_s_barrier();
    __builtin_amdgcn_sched_barrier(0);
  }
  __syncthreads();

  // wave-private row stats: reduce over 16 lanes
#pragma unroll
  for (int r = 0; r < 4; r++) {
    float s = sPart[r], m = mPart[r], se = sEp[r];
#pragma unroll
    for (int off = 1; off < 16; off <<= 1) {
      s += __shfl_xor(s, off);
      m = fmaxf(m, __shfl_xor(m, off));
      se += __shfl_xor(se, off);
    }
    if (ln == 0) {
      sS[16 * w + quad * 4 + r] = s;
      mS[16 * w + quad * 4 + r] = m;
      seS[16 * w + quad * 4 + r] = se;
    }
  }
  __syncthreads();

  const float ktotv = ktotR[bz];
#pragma unroll
  for (int mh = 0; mh < 4; mh++) {
#pragma unroll
    for (int r = 0; r < 4; r++) {
      int row = 16 * mh + quad * 4 + r;
      float st = sS[row];
      float se = seS[row];
      float mt = fmaxf(mS[row], 1e-30f);
      float c = __expf(-dS[row]) / mt;
      float A = c * se + (float)NBF * EPS_;
      float den = emk * (c * st + EPS_ * ktotv) + (float)NC * EPS_ * A;
      float inv = 1.f / den;
#pragma unroll
      for (int i = 0; i < 4; i++) {
        int e = 16 * (4 * w + i) + ln;
        float val = (emk * (c * acc[mh][i][r] + EPS_ * crS[e]) + EPS_ * svS[e] * A) * inv;
        merged[((long)tq * NT + nt * 64 + row) * 2048 + hh * 256 + e] =
            __float2bfloat16(val);
      }
    }
  }
}

// ------------------------------------------------------------------
extern "C" void kernel_launch(void* const* d_in, const int* in_sizes, int n_in,
                              void* d_out, int out_size, void* d_ws, size_t ws_size,
                              hipStream_t stream)
{
  const void* x_ctx = d_in[0];
  const void* label = d_in[1];
  const void* x_tgt = d_in[2];
  const void* W1 = d_in[3];
  const void* b1 = d_in[4];
  const void* W2 = d_in[5];
  const void* b2 = d_in[6];
  const void* W3 = d_in[7];
  const void* b3 = d_in[8];
  const void* Wk = d_in[9];
  const void* bk = d_in[10];
  const void* Wv = d_in[11];
  const void* bv = d_in[12];
  const void* Wq = d_in[13];
  const void* bq = d_in[14];
  const void* Wo = d_in[15];
  const void* bo = d_in[16];
  const void* Wmu = d_in[17];
  const void* bmu = d_in[18];
  const void* proj = d_in[19];

  // Arena (floats), peak ~89 MB. Overlays:
  //  xcB @ F2+1572864 (after cf; dead before ctxQ is written by key_fused)
  //  xtB @ F1 (vQ region; vQ dead after key_fused, merged written after q-proj)
  float* W = (float*)d_ws;
  const long F0 = 0, F1 = 4194304, F2 = 8388608;
  const long CTXQ_F = (long)64 * FT32 * 256 * 32 / 2;
  const long F3 = F2 + CTXQ_F;
  bf16* kB = (bf16*)(W + F0);
  bf16* qB = (bf16*)(W + F0);
  bf16* rep = (bf16*)(W + F0);
  bf16* vQ = (bf16*)(W + F1);
  bf16* merged = (bf16*)(W + F1);
  bf16* xtB = (bf16*)(W + F1);
  bf16* h1 = (bf16*)(W + F2);
  bf16* h2 = (bf16*)(W + F2 + 524288);
  bf16* cf = (bf16*)(W + F2 + 1048576);
  bf16* xcB = (bf16*)(W + F2 + 1572864);
  bf16* ctxQ = (bf16*)(W + F2);
  float* woP = W + F2;
  long o = F3;
  auto alloc = [&](long n) { float* p = W + o; o += n; return p; };
  float* zbase = W + o;
  float* dgk = alloc(32768);
  float* dgq = alloc(32768);
  float* Sv = alloc(64 * 256);
  float* csR = alloc(64 * 256);
  float* ktotR = alloc(64);
  alloc(192);
  float* ksumE = alloc((long)64 * NBF);
  float* mpart = alloc(64 * 23);
  float* mk = alloc(64);
  int* dtFlag = (int*)alloc(64);
  bf16* projB = (bf16*)alloc((long)FT32 * 32 * 256 / 2);
  bf16* WkT = (bf16*)alloc(262144);   // 8 x 256 x 256 bf16
  bf16* WvT = (bf16*)alloc(262144);
  bf16* WqT = (bf16*)alloc(262144);
  bf16* WoT = (bf16*)alloc(262144);   // 256 x 2048 bf16 (perm folded)
  bf16* W1T = (bf16*)alloc(32768);    // 256 x 256 bf16
  bf16* W2T = (bf16*)alloc(32768);
  bf16* W3T = (bf16*)alloc(32768);
  bf16* WmuT = (bf16*)alloc(32768);
  (void)ws_size; (void)in_sizes; (void)n_in; (void)out_size;

  const dim3 B(256);
  detect_dtype<<<1, B, 0, stream>>>(x_ctx, dtFlag);
  conv_proj<<<FT32 * 32, B, 0, stream>>>(proj, projB, dtFlag);
  conv_wT<<<dim3(64, 8, 29), B, 0, stream>>>(Wk, Wv, Wq, Wo, W1, W2, W3, Wmu,
                                             WkT, WvT, WqT, WoT, W1T, W2T, W3T, WmuT, dtFlag);
  conv_bf16<<<4096, B, 0, stream>>>(x_ctx, xcB, dtFlag);
  init_zero<<<385, B, 0, stream>>>(zbase);
  // 1. task-encoder MLP (unified async gemm)
  gemm_mfma<<<dim3(4, 64, 1), B, 0, stream>>>(
      xcB, W1T, nullptr, h1, 1, 0, 0, dtFlag, nullptr, nullptr,
      4096, 256, 256, 0L, 1, 0L, 1, 0L);
  fixup_h1<<<4096, B, 0, stream>>>(h1, label, W1, b1, dtFlag);
  gemm_mfma<<<dim3(4, 64, 1), B, 0, stream>>>(
      h1, W2T, b2, h2, 1, 2, 0, dtFlag, nullptr, nullptr,
      4096, 256, 256, 0L, 1, 0L, 1, 0L);
  gemm_mfma<<<dim3(4, 64, 1), B, 0, stream>>>(
      h2, W3T, b3, cf, 1, 2, 0, dtFlag, nullptr, nullptr,
      4096, 256, 256, 0L, 1, 0L, 1, 0L);
  // 2. k projection (fused diag), v projection (tiled -> vQ, fused Sv)
  gemm_mfma<<<dim3(4, 8, 64), B, 0, stream>>>(
      xcB, WkT, bk, kB, 1, 1, 0, dtFlag, dgk, nullptr,
      512, 256, 256, 131072L, 8, 65536L, 8, 256L);
  gemm_mfma<<<dim3(4, 8, 64), B, 0, stream>>>(
      cf, WvT, bv, vQ, 1, 1, 2, dtFlag, nullptr, Sv,
      512, 256, 256, 131072L, 8, 65536L, 8, 256L);
  // 3. key side (also emits raw csR / ktotR reductions)
  key_fused_mfma<<<dim3(64, 23), B, 0, stream>>>(kB, vQ, projB, dgk, ksumE, ctxQ,
                                                 mpart, csR, ktotR);
  mk_reduce<<<64, 64, 0, stream>>>(mpart, mk);
  // 4. q projection (fused diag); xtB converted now (vQ region is dead)
  conv_bf16<<<4096, B, 0, stream>>>(x_tgt, xtB, dtFlag);
  gemm_mfma<<<dim3(4, 8, 64), B, 0, stream>>>(
      xtB, WqT, bq, qB, 1, 1, 0, dtFlag, dgq, nullptr,
      512, 256, 256, 131072L, 8, 65536L, 8, 256L);
  // 5. query side (finalize folded in) -> merged [t][n][h][e]
  q_fused_mfma<<<dim3(64, 8), B, 0, stream>>>(qB, projB, dgq, ctxQ, ksumE,
                                              Sv, csR, ktotR, mk, merged);
  // 6. Wo split-K x2 -> fp32 partials, reduce, Wmu
  gemm_wo_splitk<<<dim3(4, 64, 2), B, 0, stream>>>(merged, WoT, woP, 4096, 256, 2048);
  reduce_partials<<<4096, B, 0, stream>>>(woP, bo, rep, dtFlag);
  gemm_mfma<<<dim3(4, 64, 1), B, 0, stream>>>(
      rep, WmuT, bmu, d_out, 2, 1, 0, dtFlag, nullptr, nullptr,
      4096, 256, 256, 0L, 1, 0L, 1, 0L);
}

// Round 9
// 387.749 us; speedup vs baseline: 1.9157x; 1.0397x over previous
//
#include <hip/hip_runtime.h>
#include <hip/hip_bf16.h>

typedef __hip_bfloat16 bf16;
typedef __attribute__((ext_vector_type(8))) short short8;
typedef __attribute__((ext_vector_type(4))) float f32x4;
typedef __attribute__((ext_vector_type(4))) unsigned short us4;
#define DEV __device__ __forceinline__

static constexpr int T_ = 8, NC = 512, NT = 512, D_ = 256, H_ = 8, NBF = 1419;
static constexpr int FT32 = 46;             // 46 f-tiles of 32 (padded 1472)
static constexpr float EPS_ = 1e-4f;
static constexpr float DN = 0.25f;          // D^-0.25
static constexpr float DIAG_SC = 0.03125f;  // 0.5 * DN^2

DEV float bf2f(unsigned short u) { return __uint_as_float(((unsigned)u) << 16); }
DEV float tofloat(bf16 x) { return __bfloat162float(x); }
DEV unsigned short f2bu(float x) { bf16 h = __float2bfloat16(x); return *(unsigned short*)&h; }

DEV float ldx(const void* p, long i, int isb) {
  if (isb) return bf2f(((const unsigned short*)p)[i]);
  return ((const float*)p)[i];
}
DEV void stx(void* p, long i, float v, int isb) {
  if (isb) ((bf16*)p)[i] = __float2bfloat16(v);
  else     ((float*)p)[i] = v;
}

// async global->LDS 16B (wave-uniform LDS base + lane*16; global addr per-lane)
DEV void async_copy16(const void* g, void* lds) {
  __builtin_amdgcn_global_load_lds(
      (const __attribute__((address_space(1))) unsigned int*)g,
      (__attribute__((address_space(3))) unsigned int*)lds, 16, 0, 0);
}

// ------------------------------------------------------------------
// dtype probe (1 = bf16 inputs, 0 = fp32)
// ------------------------------------------------------------------
__global__ __launch_bounds__(256)
void detect_dtype(const void* __restrict__ x, int* __restrict__ flag)
{
  __shared__ int bad;
  if (threadIdx.x == 0) bad = 0;
  __syncthreads();
  int mybad = 0;
  for (int j = 0; j < 16; j++) {
    long i = 2L * (threadIdx.x + 256L * j);
    unsigned short u = ((const unsigned short*)x)[i];
    int e = (u >> 7) & 0xff, mant = u & 0x7f;
    bool b = (e == 0xff) || (e >= 141) || (e <= 93 && !(e == 0 && mant == 0));
    mybad += b ? 1 : 0;
  }
  atomicAdd(&bad, mybad);
  __syncthreads();
  if (threadIdx.x == 0) *flag = (bad > 1024) ? 0 : 1;
}

// proj -> bf16 [FT32*32][256], zero rows past NBF
__global__ __launch_bounds__(256)
void conv_proj(const void* __restrict__ proj, bf16* __restrict__ projB,
               const int* __restrict__ dtFlag)
{
  const int fl = *dtFlag;
  int f = blockIdx.x, t = threadIdx.x;
  float v = (f < NBF) ? ldx(proj, (long)f * 256 + t, fl) : 0.f;
  projB[(long)f * 256 + t] = __float2bfloat16(v);
}

// generic activation convert -> bf16 (1M elements, grid 4096)
__global__ __launch_bounds__(256)
void conv_bf16(const void* __restrict__ src, bf16* __restrict__ dst,
               const int* __restrict__ dtFlag)
{
  const int fl = *dtFlag;
  long i = (long)blockIdx.x * 256 + threadIdx.x;
  dst[i] = __float2bfloat16(ldx(src, i, fl));
}

// ------------------------------------------------------------------
// Weight pre-transpose: W[k][n] -> WT[n][k] bf16. Wo folds the merged
// k-permutation. Grid (64,8,29): z 0..7 Wk, 8..15 Wv, 16..23 Wq,
// 24 Wo (kt 0..63), 25 W1, 26 W2, 27 W3, 28 Wmu.
// ------------------------------------------------------------------
__global__ __launch_bounds__(256)
void conv_wT(const void* __restrict__ Wk, const void* __restrict__ Wv,
             const void* __restrict__ Wq, const void* __restrict__ Wo,
             const void* __restrict__ W1, const void* __restrict__ W2,
             const void* __restrict__ W3, const void* __restrict__ Wmu,
             bf16* __restrict__ WkT, bf16* __restrict__ WvT,
             bf16* __restrict__ WqT, bf16* __restrict__ WoT,
             bf16* __restrict__ W1T, bf16* __restrict__ W2T,
             bf16* __restrict__ W3T, bf16* __restrict__ WmuT,
             const int* __restrict__ dtFlag)
{
  __shared__ float tile[32][33];
  const int fl = *dtFlag;
  const int kt = blockIdx.x, nt = blockIdx.y, z = blockIdx.z, t = threadIdx.x;
  const void* in; bf16* out; int K; int perm = 0; long off = 0;
  if (z < 8)        { in = Wk;  out = WkT;  K = 256; off = (long)z * 65536; }
  else if (z < 16)  { in = Wv;  out = WvT;  K = 256; off = (long)(z - 8) * 65536; }
  else if (z < 24)  { in = Wq;  out = WqT;  K = 256; off = (long)(z - 16) * 65536; }
  else if (z == 24) { in = Wo;  out = WoT;  K = 2048; perm = 1; }
  else if (z == 25) { in = W1;  out = W1T;  K = 256; }
  else if (z == 26) { in = W2;  out = W2T;  K = 256; }
  else if (z == 27) { in = W3;  out = W3T;  K = 256; }
  else              { in = Wmu; out = WmuT; K = 256; }
  if (K == 256 && kt >= 8) return;
  const int k0 = kt * 32, n0 = nt * 32;
  const int row = t >> 3, cb = (t & 7) * 4;
  {
    int kk = k0 + row;
    int krow = perm ? (((kk & 255) << 3) | (kk >> 8)) : kk;
#pragma unroll
    for (int j = 0; j < 4; j++)
      tile[row][cb + j] = ldx(in, off + (long)krow * 256 + n0 + cb + j, fl);
  }
  __syncthreads();
  us4 o;
#pragma unroll
  for (int j = 0; j < 4; j++) o[j] = f2bu(tile[cb + j][row]);
  *(us4*)(out + off + (long)(n0 + row) * K + k0 + cb) = o;
}

// zero the atomic-target region (dgk + dgq + Sv only)
__global__ __launch_bounds__(256)
void init_zero(float* __restrict__ p)
{
  p[blockIdx.x * 256 + threadIdx.x] = 0.f;
}

// ------------------------------------------------------------------
// Unified MFMA GEMM v2, 64x64 tile, K-step 64 (proven round 5).
// ------------------------------------------------------------------
__global__ __launch_bounds__(256)
void gemm_mfma(const bf16* __restrict__ A, const bf16* __restrict__ BT,
               const void* __restrict__ bias,
               void* __restrict__ C, int cMode, int epi, int cT,
               const int* __restrict__ dtFlag, float* __restrict__ diagOut,
               float* __restrict__ svOut,
               int M, int N, int K, long sA, int divA, long sB, int modB, long sBias)
{
  __shared__ alignas(16) bf16 As[2][64 * 64];
  __shared__ alignas(16) bf16 Bs[2][64 * 64];
  const int fl = *dtFlag;
  const int cB = (cMode == 2) ? fl : cMode;
  const int t = threadIdx.x;
  const int bz = blockIdx.z;
  const long aOff = (long)(bz / divA) * sA;
  const long bOff = (long)(bz % modB) * sB;
  const long biasOff = (long)(bz % modB) * sBias;
  const long cOff = (long)bz * (long)M * N;
  const int m0 = blockIdx.y * 64, n0 = blockIdx.x * 64;
  const int w = t >> 6, l = t & 63, quad = l >> 4, ln = l & 15;
  const bf16* Ab = A + aOff + (long)m0 * K;
  const bf16* Bb = BT + bOff + (long)n0 * K;
  const int srow = l >> 3;            // 0..7 within the wave's 8-row slab
  const int scc = (l & 7) ^ srow;     // XOR swizzle chunk (row&7 == srow)
  f32x4 acc[4] = {};

  auto stage = [&](int buf, int k0) {
#pragma unroll
    for (int j = 0; j < 2; j++) {
      const int rbase = 32 * j + 8 * w;         // rbase&7 == 0
      const int row = rbase + srow;
      async_copy16(Ab + (long)row * K + k0 + scc * 8, &As[buf][rbase * 64]);
      async_copy16(Bb + (long)row * K + k0 + scc * 8, &Bs[buf][rbase * 64]);
    }
  };

  stage(0, 0);
  __syncthreads();   // full drain: buffer 0 ready

  int cur = 0;
  for (int k0 = 0; k0 < K; k0 += 64) {
    if (k0 + 64 < K) stage(cur ^ 1, k0 + 64);
    const bf16* Ac = &As[cur][0];
    const bf16* Bc = &Bs[cur][0];
    const int arow = 16 * w + ln;
#pragma unroll
    for (int ks = 0; ks < 2; ks++) {
      short8 a = *(const short8*)(Ac + arow * 64 + (((ks * 4 + quad) ^ (arow & 7)) << 3));
#pragma unroll
      for (int i = 0; i < 4; i++) {
        const int brow = 16 * i + ln;
        short8 b = *(const short8*)(Bc + brow * 64 + (((ks * 4 + quad) ^ (brow & 7)) << 3));
        acc[i] = __builtin_amdgcn_mfma_f32_16x16x32_bf16(a, b, acc[i], 0, 0, 0);
      }
    }
    asm volatile("s_waitcnt vmcnt(0)" ::: "memory");
    __builtin_amdgcn_s_barrier();
    __builtin_amdgcn_sched_barrier(0);
    cur ^= 1;
  }

  float s2[4] = {0.f, 0.f, 0.f, 0.f};
  if (cT == 2) {
    const int mm = m0 + 16 * w + quad * 4;
    const int tile = mm >> 5, off = mm & 31;
#pragma unroll
    for (int i = 0; i < 4; i++) {
      int n = n0 + 16 * i + ln;
      us4 cv;
      float colsum = 0.f;
#pragma unroll
      for (int r = 0; r < 4; r++) {
        float c = acc[i][r];
        if (epi >= 1) c += ldx(bias, biasOff + n, fl);
        if (epi == 2) c = fmaxf(c, 0.f);
        colsum += c;
        cv[r] = f2bu(c);
      }
      *(us4*)((bf16*)C + cOff + ((long)tile * N + n) * 32 + off) = cv;
      if (svOut) {
        colsum += __shfl_xor(colsum, 16);
        colsum += __shfl_xor(colsum, 32);
        if (quad == 0) atomicAdd(&svOut[(long)bz * N + n], colsum);
      }
    }
  } else {
#pragma unroll
    for (int i = 0; i < 4; i++) {
#pragma unroll
      for (int r = 0; r < 4; r++) {
        int m = m0 + 16 * w + quad * 4 + r;
        int n = n0 + 16 * i + ln;
        float c = acc[i][r];
        if (epi >= 1) c += ldx(bias, biasOff + n, fl);
        if (epi == 2) c = fmaxf(c, 0.f);
        s2[r] += c * c;
        stx(C, cOff + (long)m * N + n, c, cB);
      }
    }
  }
  if (diagOut) {
#pragma unroll
    for (int r = 0; r < 4; r++) {
      float s = s2[r];
      s += __shfl_xor(s, 1); s += __shfl_xor(s, 2);
      s += __shfl_xor(s, 4); s += __shfl_xor(s, 8);
      if (ln == 0)
        atomicAdd(&diagOut[(long)bz * M + m0 + 16 * w + quad * 4 + r], DIAG_SC * s);
    }
  }
}

// ------------------------------------------------------------------
// BM=32 GEMM (v2 staging): for the skinny grid-(4,64) dispatches
// (MLP x3, Wmu) that ran at 1 block/CU. 32x64 tile -> grid (4,128)
// = 512 blocks = 2/CU. LDS 24KB. Same swizzle/barrier schedule.
// ------------------------------------------------------------------
__global__ __launch_bounds__(256)
void gemm_mfma32v2(const bf16* __restrict__ A, const bf16* __restrict__ BT,
                   const void* __restrict__ bias,
                   void* __restrict__ C, int cMode, int epi,
                   const int* __restrict__ dtFlag, int M, int N, int K)
{
  __shared__ alignas(16) bf16 As[2][32 * 64];
  __shared__ alignas(16) bf16 Bs[2][64 * 64];
  const int fl = *dtFlag;
  const int cB = (cMode == 2) ? fl : cMode;
  const int t = threadIdx.x;
  const int m0 = blockIdx.y * 32, n0 = blockIdx.x * 64;
  const int w = t >> 6, l = t & 63, quad = l >> 4, ln = l & 15;
  const int mi = w & 1, nh = w >> 1;
  const bf16* Ab = A + (long)m0 * K;
  const bf16* Bb = BT + (long)n0 * K;
  const int srow = l >> 3;
  const int scc = (l & 7) ^ srow;
  f32x4 acc[2] = {};

  auto stage = [&](int buf, int k0) {
    // A: wave w stages rows 8w..8w+7 (one slab)
    async_copy16(Ab + (long)(8 * w + srow) * K + k0 + scc * 8, &As[buf][(8 * w) * 64]);
#pragma unroll
    for (int j = 0; j < 2; j++) {
      const int rbase = 32 * j + 8 * w;
      async_copy16(Bb + (long)(rbase + srow) * K + k0 + scc * 8, &Bs[buf][rbase * 64]);
    }
  };

  stage(0, 0);
  __syncthreads();

  int cur = 0;
  for (int k0 = 0; k0 < K; k0 += 64) {
    if (k0 + 64 < K) stage(cur ^ 1, k0 + 64);
    const bf16* Ac = &As[cur][0];
    const bf16* Bc = &Bs[cur][0];
    const int arow = 16 * mi + ln;
#pragma unroll
    for (int ks = 0; ks < 2; ks++) {
      short8 a = *(const short8*)(Ac + arow * 64 + (((ks * 4 + quad) ^ (arow & 7)) << 3));
#pragma unroll
      for (int i = 0; i < 2; i++) {
        const int brow = 16 * (2 * nh + i) + ln;
        short8 b = *(const short8*)(Bc + brow * 64 + (((ks * 4 + quad) ^ (brow & 7)) << 3));
        acc[i] = __builtin_amdgcn_mfma_f32_16x16x32_bf16(a, b, acc[i], 0, 0, 0);
      }
    }
    asm volatile("s_waitcnt vmcnt(0)" ::: "memory");
    __builtin_amdgcn_s_barrier();
    __builtin_amdgcn_sched_barrier(0);
    cur ^= 1;
  }

#pragma unroll
  for (int i = 0; i < 2; i++) {
#pragma unroll
    for (int r = 0; r < 4; r++) {
      int m = m0 + 16 * mi + quad * 4 + r;
      int n = n0 + 16 * (2 * nh + i) + ln;
      float c = acc[i][r];
      if (epi >= 1) c += ldx(bias, n, fl);
      if (epi == 2) c = fmaxf(c, 0.f);
      stx(C, (long)m * N + n, c, cB);
    }
  }
}

// ------------------------------------------------------------------
// Wo GEMM, split-K x2: partials traffic 8+8MB.
// ------------------------------------------------------------------
__global__ __launch_bounds__(256)
void gemm_wo_splitk(const bf16* __restrict__ A, const bf16* __restrict__ BT,
                    float* __restrict__ P, int M, int N, int K)
{
  __shared__ alignas(16) bf16 As[2][64 * 64];
  __shared__ alignas(16) bf16 Bs[2][64 * 64];
  const int t = threadIdx.x;
  const int z = blockIdx.z;
  const int m0 = blockIdx.y * 64, n0 = blockIdx.x * 64;
  const int w = t >> 6, l = t & 63, quad = l >> 4, ln = l & 15;
  const bf16* Ab = A + (long)m0 * K;
  const bf16* Bb = BT + (long)n0 * K;
  const int srow = l >> 3, scc = (l & 7) ^ srow;
  f32x4 acc[4] = {};
  const int kbase = z * 1024, kend = kbase + 1024;

  auto stage = [&](int buf, int k0) {
#pragma unroll
    for (int j = 0; j < 2; j++) {
      const int rbase = 32 * j + 8 * w;
      const int row = rbase + srow;
      async_copy16(Ab + (long)row * K + k0 + scc * 8, &As[buf][rbase * 64]);
      async_copy16(Bb + (long)row * K + k0 + scc * 8, &Bs[buf][rbase * 64]);
    }
  };

  stage(0, kbase);
  __syncthreads();

  int cur = 0;
  for (int k0 = kbase; k0 < kend; k0 += 64) {
    if (k0 + 64 < kend) stage(cur ^ 1, k0 + 64);
    const bf16* Ac = &As[cur][0];
    const bf16* Bc = &Bs[cur][0];
    const int arow = 16 * w + ln;
#pragma unroll
    for (int ks = 0; ks < 2; ks++) {
      short8 a = *(const short8*)(Ac + arow * 64 + (((ks * 4 + quad) ^ (arow & 7)) << 3));
#pragma unroll
      for (int i = 0; i < 4; i++) {
        const int brow = 16 * i + ln;
        short8 b = *(const short8*)(Bc + brow * 64 + (((ks * 4 + quad) ^ (brow & 7)) << 3));
        acc[i] = __builtin_amdgcn_mfma_f32_16x16x32_bf16(a, b, acc[i], 0, 0, 0);
      }
    }
    asm volatile("s_waitcnt vmcnt(0)" ::: "memory");
    __builtin_amdgcn_s_barrier();
    __builtin_amdgcn_sched_barrier(0);
    cur ^= 1;
  }

  float* Pz = P + (long)z * M * N;
#pragma unroll
  for (int i = 0; i < 4; i++) {
#pragma unroll
    for (int r = 0; r < 4; r++) {
      int m = m0 + 16 * w + quad * 4 + r;
      int n = n0 + 16 * i + ln;
      Pz[(long)m * N + n] = acc[i][r];
    }
  }
}

// rep[m][n] (bf16) = sum_z P[z][m][n] + bo[n]   (z = 2)
__global__ __launch_bounds__(256)
void reduce_partials(const float* __restrict__ P, const void* __restrict__ bo,
                     bf16* __restrict__ rep, const int* __restrict__ dtFlag)
{
  const int fl = *dtFlag;
  long idx = (long)blockIdx.x * 256 + threadIdx.x;
  int n = idx & 255;
  float s = ldx(bo, n, fl) + P[idx] + P[1048576 + idx];
  rep[idx] = __float2bfloat16(s);
}

__global__ __launch_bounds__(256)
void fixup_h1(bf16* __restrict__ h1, const void* __restrict__ label,
              const void* __restrict__ W1, const void* __restrict__ b1,
              const int* __restrict__ dtFlag)
{
  const int fl = *dtFlag;
  int idx = blockIdx.x * 256 + threadIdx.x;
  int m = idx >> 8, n = idx & 255;
  float c = tofloat(h1[idx]) + ldx(b1, n, fl);
#pragma unroll
  for (int j = 0; j < 3; j++)
    c += ldx(label, m * 3 + j, fl) * ldx(W1, (256 + j) * 256 + n, fl);
  h1[idx] = __float2bfloat16(fmaxf(c, 0.f));
}

// ------------------------------------------------------------------
// Key-side fused v9 = v5 staging (proven 87.7-88.2us) + DE-ATOMIZED
// epilogue: csR/ktotR atomics (round-7: +12us tail, 377K contended
// device atomics draining at endpgm) replaced with per-block partial
// STORES (csRp[bz][ft][e] written exactly once; ktotp[bz][ft] via a
// 4-float LDS wave-sum piggybacked on the existing mpart barrier).
// finalize_red reduces partials -> csR/ktotR/mk.
// ------------------------------------------------------------------
__global__ __launch_bounds__(256)
void key_fused_mfma(const bf16* __restrict__ k, const bf16* __restrict__ vQ,
                    const bf16* __restrict__ projB, const float* __restrict__ diagk,
                    float* __restrict__ ksumE, bf16* __restrict__ ctxQ,
                    float* __restrict__ mpart, float* __restrict__ csRp,
                    float* __restrict__ ktotp)
{
  __shared__ alignas(16) bf16 kS[3][32 * 256];
  __shared__ alignas(16) bf16 pS[2][64 * 40];
  __shared__ float wredM[4];
  __shared__ float wredK[4];

  const int bz = blockIdx.x, ft = blockIdx.y, f0 = ft * 64;
  const int t = threadIdx.x;
  const int w = t >> 6, l = t & 63, quad = l >> 4, ln = l & 15;
  const int fmine = f0 + 16 * w + ln;
  const bool fv = fmine < NBF;

  const bf16* kb = k + (long)bz * NC * 256;
  const bf16* vqb = vQ + (long)bz * 16 * 256 * 32;
  const float* db = diagk + bz * NC;

  auto stage = [&](int buf, int n0) {
#pragma unroll
    for (int j = 0; j < 4; j++) {
      int row = w * 8 + j * 2 + (l >> 5);
      int cc = (l & 31) ^ ((2 * j + (l >> 5)) & 7);   // = (l&31) ^ (row&7)
      async_copy16(kb + (long)(n0 + row) * 256 + cc * 8,
                   &kS[buf][w * 2048 + j * 512]);
    }
  };
  stage(0, 0);
  stage(1, 32);

  short8 pf[8];
  {
    const bf16* prow = projB + (long)fmine * 256;
#pragma unroll
    for (int kc = 0; kc < 8; kc++)
      pf[kc] = *(const short8*)(prow + kc * 32 + quad * 8);
  }

  f32x4 acc[4][4] = {};
  float ksumP = 0.f, mP = -1e30f;

  __syncthreads();   // full drain once: kS[0], kS[1] + pf ready

  int cur = 0;       // buffer holding tile `it`
  for (int it = 0; it < 16; it++) {
    const int n0 = it * 32;
    short8 bfr[4];
#pragma unroll
    for (int ei = 0; ei < 4; ei++) {
      int e = 64 * w + 16 * ei + ln;
      bfr[ei] = *(const short8*)(vqb + ((long)it * 256 + e) * 32 + quad * 8);
    }
    f32x4 dv0 = *(const f32x4*)(db + n0 + quad * 4);
    f32x4 dv1 = *(const f32x4*)(db + n0 + 16 + quad * 4);
    __builtin_amdgcn_sched_barrier(0);
    if (it + 2 < 16) {
      int nb = cur + 2; if (nb >= 3) nb -= 3;
      stage(nb, n0 + 64);
    }
    __builtin_amdgcn_sched_barrier(0);

    const bf16* kcur = &kS[cur][0];
    f32x4 dd[2][2] = {};
    __builtin_amdgcn_s_setprio(1);
#pragma unroll
    for (int kc = 0; kc < 8; kc++) {
      const int hf = kc & 1;
#pragma unroll
      for (int mi = 0; mi < 2; mi++) {
        short8 a = *(const short8*)(kcur + (16 * mi + ln) * 256 +
                                    (((kc * 4 + quad) ^ (ln & 7)) << 3));
        dd[mi][hf] = __builtin_amdgcn_mfma_f32_16x16x32_bf16(a, pf[kc], dd[mi][hf], 0, 0, 0);
      }
    }
    __builtin_amdgcn_s_setprio(0);
    bf16* pcur = &pS[it & 1][0];
#pragma unroll
    for (int mi = 0; mi < 2; mi++) {
      us4 ev;
      f32x4 dvv = mi ? dv1 : dv0;
#pragma unroll
      for (int r = 0; r < 4; r++) {
        float sc = DN * (dd[mi][0][r] + dd[mi][1][r]);
        float E = fv ? __expf(fminf(sc - dvv[r], 80.f)) : 0.f;
        unsigned short u = f2bu(E);
        ksumP += bf2f(u);
        if (fv) mP = fmaxf(mP, sc);
        ev[r] = u;
      }
      *(us4*)(pcur + (16 * w + ln) * 40 + 16 * mi + quad * 4) = ev;
    }
    // single barrier: pS visible (lgkmcnt 0), kS[it+1] complete (vmcnt 4:
    // everything older than the 4 stage(it+2) DMAs is done)
    asm volatile("s_waitcnt vmcnt(4) lgkmcnt(0)" ::: "memory");
    __builtin_amdgcn_s_barrier();
    __builtin_amdgcn_sched_barrier(0);

    __builtin_amdgcn_s_setprio(1);
#pragma unroll
    for (int fh = 0; fh < 4; fh++) {
      short8 a = *(const short8*)(pcur + (16 * fh + ln) * 40 + quad * 8);
#pragma unroll
      for (int ei = 0; ei < 4; ei++)
        acc[fh][ei] = __builtin_amdgcn_mfma_f32_16x16x32_bf16(a, bfr[ei], acc[fh][ei], 0, 0, 0);
    }
    __builtin_amdgcn_s_setprio(0);
    cur = (cur == 2) ? 0 : cur + 1;
  }
  __syncthreads();

#pragma unroll
  for (int fh = 0; fh < 4; fh++) {
    const int ft32 = 2 * ft + (fh >> 1);
    const int f32b = 16 * (fh & 1) + quad * 4;
#pragma unroll
    for (int ei = 0; ei < 4; ei++) {
      int e = 64 * w + 16 * ei + ln;
      us4 cv;
#pragma unroll
      for (int r = 0; r < 4; r++) cv[r] = f2bu(acc[fh][ei][r]);
      *(us4*)(&ctxQ[((long)(bz * FT32 + ft32) * 256 + e) * 32 + f32b]) = cv;
    }
  }

  // csRp partial: column sum over this block's 64 f-rows per e (plain store)
#pragma unroll
  for (int ei = 0; ei < 4; ei++) {
    float col = 0.f;
#pragma unroll
    for (int fh = 0; fh < 4; fh++)
#pragma unroll
      for (int r = 0; r < 4; r++) col += acc[fh][ei][r];
    col += __shfl_xor(col, 16);
    col += __shfl_xor(col, 32);
    if (quad == 0)
      csRp[((long)bz * 23 + ft) * 256 + 64 * w + 16 * ei + ln] = col;
  }

  float s = ksumP;
  s += __shfl_xor(s, 16); s += __shfl_xor(s, 32);
  if (quad == 0 && fv) ksumE[(long)bz * NBF + fmine] = s;
  // ktotp partial: per-wave sum over its 16 f-rows, combined via LDS
  float s2 = s;
  s2 += __shfl_xor(s2, 1); s2 += __shfl_xor(s2, 2);
  s2 += __shfl_xor(s2, 4); s2 += __shfl_xor(s2, 8);
  if (l == 0) wredK[w] = s2;

  float m = mP;
#pragma unroll
  for (int off = 1; off < 64; off <<= 1) m = fmaxf(m, __shfl_xor(m, off));
  if (l == 0) wredM[w] = m;
  __syncthreads();
  if (t == 0) {
    mpart[bz * 23 + ft] = fmaxf(fmaxf(wredM[0], wredM[1]), fmaxf(wredM[2], wredM[3]));
    ktotp[bz * 23 + ft] = wredK[0] + wredK[1] + wredK[2] + wredK[3];
  }
}

// ------------------------------------------------------------------
// finalize_red: partials -> mk (max), csR (sum over ft), ktotR (sum).
// Grid 64 blocks x 256 threads.
// ------------------------------------------------------------------
__global__ __launch_bounds__(256)
void finalize_red(const float* __restrict__ mpart, const float* __restrict__ csRp,
                  const float* __restrict__ ktotp, float* __restrict__ mk,
                  float* __restrict__ csR, float* __restrict__ ktotR)
{
  int bz = blockIdx.x, t = threadIdx.x;
  float s = 0.f;
  for (int ft = 0; ft < 23; ft++)
    s += csRp[((long)bz * 23 + ft) * 256 + t];
  csR[bz * 256 + t] = s;
  int w = t >> 6, l = t & 63;
  if (w == 0) {
    float m = (l < 23) ? mpart[bz * 23 + l] : -1e30f;
#pragma unroll
    for (int off = 32; off > 0; off >>= 1) m = fmaxf(m, __shfl_down(m, off));
    if (l == 0) mk[bz] = m;
  } else if (w == 1) {
    float kk = (l < 23) ? ktotp[bz * 23 + l] : 0.f;
#pragma unroll
    for (int off = 32; off > 0; off >>= 1) kk += __shfl_down(kk, off);
    if (l == 0) ktotR[bz] = kk;
  }
}

// ------------------------------------------------------------------
// Query-side fused v7 (kept): reads RAW ctxQ/ksumE; finalizes folded:
//   A    = c*sE + NBF*EPS                        (sE = sum_f E_q)
//   num  = emk*(c*accR + EPS*csR[e]) + EPS*Sv[e]*A
//   den  = emk*(c*stR  + EPS*ktotR) + NC*EPS*A
// ------------------------------------------------------------------
__global__ __launch_bounds__(256)
void q_fused_mfma(const bf16* __restrict__ q, const bf16* __restrict__ projB,
                  const float* __restrict__ diagq, const bf16* __restrict__ ctxQ,
                  const float* __restrict__ ksum, const float* __restrict__ Sv,
                  const float* __restrict__ csR, const float* __restrict__ ktotR,
                  const float* __restrict__ mk, bf16* __restrict__ merged)
{
  __shared__ alignas(16) bf16 projS[2][32 * 256];
  __shared__ alignas(16) bf16 eS[64 * 40];
  __shared__ float dS[64];
  __shared__ float svS[256];
  __shared__ float crS[256];
  __shared__ float sS[64];
  __shared__ float mS[64];
  __shared__ float seS[64];

  const int bz = blockIdx.x, nt = blockIdx.y, t = threadIdx.x;
  const int w = t >> 6, l = t & 63, quad = l >> 4, ln = l & 15;
  const int tq = bz / H_, hh = bz % H_;
  const bf16* cqb = ctxQ + (long)bz * FT32 * 256 * 32;
  const bf16* qb = q + ((long)bz * NT + nt * 64) * 256;
  const float emk = __expf(-mk[bz]);

  auto stage_proj = [&](int buf, int f0n) {
#pragma unroll
    for (int j = 0; j < 4; j++) {
      int row = 8 * w + 2 * j + (l >> 5);
      int cc = (l & 31) ^ (row & 7);
      async_copy16(projB + (long)(f0n + row) * 256 + cc * 8,
                   &projS[buf][(8 * w + 2 * j) * 256]);
    }
  };
  stage_proj(0, 0);

  // q fragments: no ft dependence -> load once, keep in 32 VGPRs
  short8 qf[8];
  {
    const bf16* qrow = qb + (long)(16 * w + ln) * 256;
#pragma unroll
    for (int kc = 0; kc < 8; kc++)
      qf[kc] = *(const short8*)(qrow + kc * 32 + quad * 8);
  }
  if (t < 64) dS[t] = diagq[(long)bz * NT + nt * 64 + t];
  svS[t] = Sv[bz * 256 + t];
  crS[t] = csR[bz * 256 + t];

  f32x4 acc[4][4] = {};           // [mh][ei]: rows 16mh+quad*4+r, e=16(4w+ei)+ln
  float sPart[4] = {0.f, 0.f, 0.f, 0.f};   // stR partial (rows 16w+quad*4+r)
  float sEp[4] = {0.f, 0.f, 0.f, 0.f};     // sE partial
  float mPart[4] = {0.f, 0.f, 0.f, 0.f};
  __syncthreads();   // full drain: projS[0] + LDS scalars ready

  for (int ft = 0; ft < FT32; ft++) {
    const int f0 = ft * 32;
    const bf16* pcur = &projS[ft & 1][0];
    short8 cfr[4];
#pragma unroll
    for (int i = 0; i < 4; i++) {
      int e = 16 * (4 * w + i) + ln;
      cfr[i] = *(const short8*)(cqb + ((long)ft * 256 + e) * 32 + quad * 8);
    }
    const float kv0 = (f0 + ln < NBF) ? ksum[(long)bz * NBF + f0 + ln] : 0.f;
    const float kv1 = (f0 + 16 + ln < NBF) ? ksum[(long)bz * NBF + f0 + 16 + ln] : 0.f;
    if (ft + 1 < FT32) stage_proj((ft + 1) & 1, f0 + 32);

    // Phase A: wave w owns rows 16w..16w+15, both f-halves
    f32x4 dd0 = {}, dd1 = {};
#pragma unroll
    for (int kc = 0; kc < 8; kc++) {
      const int co = ((kc * 4 + quad) ^ (ln & 7)) << 3;
      short8 b0 = *(const short8*)(pcur + ln * 256 + co);
      dd0 = __builtin_amdgcn_mfma_f32_16x16x32_bf16(qf[kc], b0, dd0, 0, 0, 0);
      short8 b1 = *(const short8*)(pcur + (16 + ln) * 256 + co);
      dd1 = __builtin_amdgcn_mfma_f32_16x16x32_bf16(qf[kc], b1, dd1, 0, 0, 0);
    }
    const bool fv0 = (f0 + ln) < NBF;
    const bool fv1 = (f0 + 16 + ln) < NBF;
#pragma unroll
    for (int r = 0; r < 4; r++) {
      float E0 = fv0 ? __expf(fminf(DN * dd0[r], 80.f)) : 0.f;
      float E1 = fv1 ? __expf(fminf(DN * dd1[r], 80.f)) : 0.f;
      bf16 h0 = __float2bfloat16(E0), h1v = __float2bfloat16(E1);
      float e0 = tofloat(h0), e1 = tofloat(h1v);
      eS[(16 * w + quad * 4 + r) * 40 + ln] = h0;
      eS[(16 * w + quad * 4 + r) * 40 + 16 + ln] = h1v;
      sPart[r] += e0 * kv0 + e1 * kv1;
      sEp[r] += e0 + e1;
      mPart[r] = fmaxf(mPart[r], fmaxf(e0, e1));
    }
    // mid barrier: eS writes visible; proj prefetch stays in flight
    asm volatile("s_waitcnt lgkmcnt(0)" ::: "memory");
    __builtin_amdgcn_s_barrier();
    __builtin_amdgcn_sched_barrier(0);

    // Phase B: all 4 m-halves, 4 e-tiles each (cfr reused)
#pragma unroll
    for (int mh = 0; mh < 4; mh++) {
      short8 a = *(const short8*)(&eS[(16 * mh + ln) * 40 + quad * 8]);
#pragma unroll
      for (int i = 0; i < 4; i++)
        acc[mh][i] = __builtin_amdgcn_mfma_f32_16x16x32_bf16(a, cfr[i], acc[mh][i], 0, 0, 0);
    }
    // end barrier: next projS buffer complete (vmcnt covers global_load_lds)
    asm volatile("s_waitcnt vmcnt(0) lgkmcnt(0)" ::: "memory");
    __builtin_amdgcn_s_barrier();
    __builtin_amdgcn_sched_barrier(0);
  }
  __syncthreads();

  // wave-private row stats: reduce over 16 lanes
#pragma unroll
  for (int r = 0; r < 4; r++) {
    float s = sPart[r], m = mPart[r], se = sEp[r];
#pragma unroll
    for (int off = 1; off < 16; off <<= 1) {
      s += __shfl_xor(s, off);
      m = fmaxf(m, __shfl_xor(m, off));
      se += __shfl_xor(se, off);
    }
    if (ln == 0) {
      sS[16 * w + quad * 4 + r] = s;
      mS[16 * w + quad * 4 + r] = m;
      seS[16 * w + quad * 4 + r] = se;
    }
  }
  __syncthreads();

  const float ktotv = ktotR[bz];
#pragma unroll
  for (int mh = 0; mh < 4; mh++) {
#pragma unroll
    for (int r = 0; r < 4; r++) {
      int row = 16 * mh + quad * 4 + r;
      float st = sS[row];
      float se = seS[row];
      float mt = fmaxf(mS[row], 1e-30f);
      float c = __expf(-dS[row]) / mt;
      float A = c * se + (float)NBF * EPS_;
      float den = emk * (c * st + EPS_ * ktotv) + (float)NC * EPS_ * A;
      float inv = 1.f / den;
#pragma unroll
      for (int i = 0; i < 4; i++) {
        int e = 16 * (4 * w + i) + ln;
        float val = (emk * (c * acc[mh][i][r] + EPS_ * crS[e]) + EPS_ * svS[e] * A) * inv;
        merged[((long)tq * NT + nt * 64 + row) * 2048 + hh * 256 + e] =
            __float2bfloat16(val);
      }
    }
  }
}

// ------------------------------------------------------------------
extern "C" void kernel_launch(void* const* d_in, const int* in_sizes, int n_in,
                              void* d_out, int out_size, void* d_ws, size_t ws_size,
                              hipStream_t stream)
{
  const void* x_ctx = d_in[0];
  const void* label = d_in[1];
  const void* x_tgt = d_in[2];
  const void* W1 = d_in[3];
  const void* b1 = d_in[4];
  const void* W2 = d_in[5];
  const void* b2 = d_in[6];
  const void* W3 = d_in[7];
  const void* b3 = d_in[8];
  const void* Wk = d_in[9];
  const void* bk = d_in[10];
  const void* Wv = d_in[11];
  const void* bv = d_in[12];
  const void* Wq = d_in[13];
  const void* bq = d_in[14];
  const void* Wo = d_in[15];
  const void* bo = d_in[16];
  const void* Wmu = d_in[17];
  const void* bmu = d_in[18];
  const void* proj = d_in[19];

  // Arena (floats), peak ~91 MB. Overlays:
  //  xcB @ F2+1572864 (after cf; dead before ctxQ is written by key_fused)
  //  xtB @ F1 (vQ region; vQ dead after key_fused, merged written after q-proj)
  float* W = (float*)d_ws;
  const long F0 = 0, F1 = 4194304, F2 = 8388608;
  const long CTXQ_F = (long)64 * FT32 * 256 * 32 / 2;
  const long F3 = F2 + CTXQ_F;
  bf16* kB = (bf16*)(W + F0);
  bf16* qB = (bf16*)(W + F0);
  bf16* rep = (bf16*)(W + F0);
  bf16* vQ = (bf16*)(W + F1);
  bf16* merged = (bf16*)(W + F1);
  bf16* xtB = (bf16*)(W + F1);
  bf16* h1 = (bf16*)(W + F2);
  bf16* h2 = (bf16*)(W + F2 + 524288);
  bf16* cf = (bf16*)(W + F2 + 1048576);
  bf16* xcB = (bf16*)(W + F2 + 1572864);
  bf16* ctxQ = (bf16*)(W + F2);
  float* woP = W + F2;
  long o = F3;
  auto alloc = [&](long n) { float* p = W + o; o += n; return p; };
  float* zbase = W + o;
  float* dgk = alloc(32768);
  float* dgq = alloc(32768);
  float* Sv = alloc(64 * 256);          // end of zeroed region (320 blocks)
  float* csR = alloc(64 * 256);
  float* ktotR = alloc(64);
  alloc(192);
  float* ksumE = alloc((long)64 * NBF);
  float* mpart = alloc(64 * 23);
  float* mk = alloc(64);
  int* dtFlag = (int*)alloc(64);
  float* csRp = alloc((long)64 * 23 * 256);
  float* ktotp = alloc(64 * 23);
  bf16* projB = (bf16*)alloc((long)FT32 * 32 * 256 / 2);
  bf16* WkT = (bf16*)alloc(262144);   // 8 x 256 x 256 bf16
  bf16* WvT = (bf16*)alloc(262144);
  bf16* WqT = (bf16*)alloc(262144);
  bf16* WoT = (bf16*)alloc(262144);   // 256 x 2048 bf16 (perm folded)
  bf16* W1T = (bf16*)alloc(32768);    // 256 x 256 bf16
  bf16* W2T = (bf16*)alloc(32768);
  bf16* W3T = (bf16*)alloc(32768);
  bf16* WmuT = (bf16*)alloc(32768);
  (void)ws_size; (void)in_sizes; (void)n_in; (void)out_size;

  const dim3 B(256);
  detect_dtype<<<1, B, 0, stream>>>(x_ctx, dtFlag);
  conv_proj<<<FT32 * 32, B, 0, stream>>>(proj, projB, dtFlag);
  conv_wT<<<dim3(64, 8, 29), B, 0, stream>>>(Wk, Wv, Wq, Wo, W1, W2, W3, Wmu,
                                             WkT, WvT, WqT, WoT, W1T, W2T, W3T, WmuT, dtFlag);
  conv_bf16<<<4096, B, 0, stream>>>(x_ctx, xcB, dtFlag);
  init_zero<<<320, B, 0, stream>>>(zbase);
  // 1. task-encoder MLP (BM=32 async gemm, 512 blocks = 2/CU)
  gemm_mfma32v2<<<dim3(4, 128), B, 0, stream>>>(
      xcB, W1T, nullptr, h1, 1, 0, dtFlag, 4096, 256, 256);
  fixup_h1<<<4096, B, 0, stream>>>(h1, label, W1, b1, dtFlag);
  gemm_mfma32v2<<<dim3(4, 128), B, 0, stream>>>(
      h1, W2T, b2, h2, 1, 2, dtFlag, 4096, 256, 256);
  gemm_mfma32v2<<<dim3(4, 128), B, 0, stream>>>(
      h2, W3T, b3, cf, 1, 2, dtFlag, 4096, 256, 256);
  // 2. k projection (fused diag), v projection (tiled -> vQ, fused Sv)
  gemm_mfma<<<dim3(4, 8, 64), B, 0, stream>>>(
      xcB, WkT, bk, kB, 1, 1, 0, dtFlag, dgk, nullptr,
      512, 256, 256, 131072L, 8, 65536L, 8, 256L);
  gemm_mfma<<<dim3(4, 8, 64), B, 0, stream>>>(
      cf, WvT, bv, vQ, 1, 1, 2, dtFlag, nullptr, Sv,
      512, 256, 256, 131072L, 8, 65536L, 8, 256L);
  // 3. key side (emits csRp / ktotp partials, no atomics)
  key_fused_mfma<<<dim3(64, 23), B, 0, stream>>>(kB, vQ, projB, dgk, ksumE, ctxQ,
                                                 mpart, csRp, ktotp);
  finalize_red<<<64, B, 0, stream>>>(mpart, csRp, ktotp, mk, csR, ktotR);
  // 4. q projection (fused diag); xtB converted now (vQ region is dead)
  conv_bf16<<<4096, B, 0, stream>>>(x_tgt, xtB, dtFlag);
  gemm_mfma<<<dim3(4, 8, 64), B, 0, stream>>>(
      xtB, WqT, bq, qB, 1, 1, 0, dtFlag, dgq, nullptr,
      512, 256, 256, 131072L, 8, 65536L, 8, 256L);
  // 5. query side (finalize folded in) -> merged [t][n][h][e]
  q_fused_mfma<<<dim3(64, 8), B, 0, stream>>>(qB, projB, dgq, ctxQ, ksumE,
                                              Sv, csR, ktotR, mk, merged);
  // 6. Wo split-K x2 -> fp32 partials, reduce, Wmu
  gemm_wo_splitk<<<dim3(4, 64, 2), B, 0, stream>>>(merged, WoT, woP, 4096, 256, 2048);
  reduce_partials<<<4096, B, 0, stream>>>(woP, bo, rep, dtFlag);
  gemm_mfma32v2<<<dim3(4, 128), B, 0, stream>>>(
      rep, WmuT, bmu, d_out, 2, 1, dtFlag, 4096, 256, 256);
}

// Round 10
// 376.705 us; speedup vs baseline: 1.9719x; 1.0293x over previous
//
#include <hip/hip_runtime.h>
#include <hip/hip_bf16.h>

typedef __hip_bfloat16 bf16;
typedef __attribute__((ext_vector_type(8))) short short8;
typedef __attribute__((ext_vector_type(4))) float f32x4;
typedef __attribute__((ext_vector_type(4))) unsigned short us4;
#define DEV __device__ __forceinline__

static constexpr int T_ = 8, NC = 512, NT = 512, D_ = 256, H_ = 8, NBF = 1419;
static constexpr int FT32 = 46;             // 46 f-tiles of 32 (padded 1472)
static constexpr float EPS_ = 1e-4f;
static constexpr float DN = 0.25f;          // D^-0.25
static constexpr float DIAG_SC = 0.03125f;  // 0.5 * DN^2

DEV float bf2f(unsigned short u) { return __uint_as_float(((unsigned)u) << 16); }
DEV float tofloat(bf16 x) { return __bfloat162float(x); }
DEV unsigned short f2bu(float x) { bf16 h = __float2bfloat16(x); return *(unsigned short*)&h; }

DEV float ldx(const void* p, long i, int isb) {
  if (isb) return bf2f(((const unsigned short*)p)[i]);
  return ((const float*)p)[i];
}
DEV void stx(void* p, long i, float v, int isb) {
  if (isb) ((bf16*)p)[i] = __float2bfloat16(v);
  else     ((float*)p)[i] = v;
}

// async global->LDS 16B (wave-uniform LDS base + lane*16; global addr per-lane)
DEV void async_copy16(const void* g, void* lds) {
  __builtin_amdgcn_global_load_lds(
      (const __attribute__((address_space(1))) unsigned int*)g,
      (__attribute__((address_space(3))) unsigned int*)lds, 16, 0, 0);
}

// ------------------------------------------------------------------
// dtype probe (1 = bf16 inputs, 0 = fp32)
// ------------------------------------------------------------------
__global__ __launch_bounds__(256)
void detect_dtype(const void* __restrict__ x, int* __restrict__ flag)
{
  __shared__ int bad;
  if (threadIdx.x == 0) bad = 0;
  __syncthreads();
  int mybad = 0;
  for (int j = 0; j < 16; j++) {
    long i = 2L * (threadIdx.x + 256L * j);
    unsigned short u = ((const unsigned short*)x)[i];
    int e = (u >> 7) & 0xff, mant = u & 0x7f;
    bool b = (e == 0xff) || (e >= 141) || (e <= 93 && !(e == 0 && mant == 0));
    mybad += b ? 1 : 0;
  }
  atomicAdd(&bad, mybad);
  __syncthreads();
  if (threadIdx.x == 0) *flag = (bad > 1024) ? 0 : 1;
}

// generic activation convert -> bf16 (1M elements, grid 4096) — xtB only
__global__ __launch_bounds__(256)
void conv_bf16(const void* __restrict__ src, bf16* __restrict__ dst,
               const int* __restrict__ dtFlag)
{
  const int fl = *dtFlag;
  long i = (long)blockIdx.x * 256 + threadIdx.x;
  dst[i] = __float2bfloat16(ldx(src, i, fl));
}

// ------------------------------------------------------------------
// prep_all: merged prep (saves 3 dispatch gaps). Grid (64,8,31):
//  z 0..28 : weight pre-transpose W[k][n]->WT[n][k] bf16 (Wo folds the
//            merged-k permutation), as before.
//  z == 29 : conv_proj — 3 f-rows per block (b=nt*64+kt, f=3b+r<1472).
//  z == 30 : xcB bf16 convert (2048 elems/block) + zero of the
//            dgk/dgq/Sv atomic region (b<320).
// ------------------------------------------------------------------
__global__ __launch_bounds__(256)
void prep_all(const void* __restrict__ Wk, const void* __restrict__ Wv,
              const void* __restrict__ Wq, const void* __restrict__ Wo,
              const void* __restrict__ W1, const void* __restrict__ W2,
              const void* __restrict__ W3, const void* __restrict__ Wmu,
              const void* __restrict__ proj, const void* __restrict__ x_ctx,
              bf16* __restrict__ WkT, bf16* __restrict__ WvT,
              bf16* __restrict__ WqT, bf16* __restrict__ WoT,
              bf16* __restrict__ W1T, bf16* __restrict__ W2T,
              bf16* __restrict__ W3T, bf16* __restrict__ WmuT,
              bf16* __restrict__ projB, bf16* __restrict__ xcB,
              float* __restrict__ zbase, const int* __restrict__ dtFlag)
{
  __shared__ float tile[32][33];
  const int fl = *dtFlag;
  const int kt = blockIdx.x, nt = blockIdx.y, z = blockIdx.z, t = threadIdx.x;

  if (z == 29) {              // conv_proj
    int b = nt * 64 + kt;
#pragma unroll
    for (int r = 0; r < 3; r++) {
      int f = b * 3 + r;
      if (f < FT32 * 32) {
        float v = (f < NBF) ? ldx(proj, (long)f * 256 + t, fl) : 0.f;
        projB[(long)f * 256 + t] = __float2bfloat16(v);
      }
    }
    return;
  }
  if (z == 30) {              // xcB convert + atomic-region zero
    int b = nt * 64 + kt;
#pragma unroll
    for (int j = 0; j < 8; j++) {
      long i = (long)b * 2048 + j * 256 + t;
      xcB[i] = __float2bfloat16(ldx(x_ctx, i, fl));
    }
    if (b < 320) zbase[b * 256 + t] = 0.f;
    return;
  }

  const void* in; bf16* out; int K; int perm = 0; long off = 0;
  if (z < 8)        { in = Wk;  out = WkT;  K = 256; off = (long)z * 65536; }
  else if (z < 16)  { in = Wv;  out = WvT;  K = 256; off = (long)(z - 8) * 65536; }
  else if (z < 24)  { in = Wq;  out = WqT;  K = 256; off = (long)(z - 16) * 65536; }
  else if (z == 24) { in = Wo;  out = WoT;  K = 2048; perm = 1; }
  else if (z == 25) { in = W1;  out = W1T;  K = 256; }
  else if (z == 26) { in = W2;  out = W2T;  K = 256; }
  else if (z == 27) { in = W3;  out = W3T;  K = 256; }
  else              { in = Wmu; out = WmuT; K = 256; }
  if (K == 256 && kt >= 8) return;
  const int k0 = kt * 32, n0 = nt * 32;
  const int row = t >> 3, cb = (t & 7) * 4;
  {
    int kk = k0 + row;
    int krow = perm ? (((kk & 255) << 3) | (kk >> 8)) : kk;
#pragma unroll
    for (int j = 0; j < 4; j++)
      tile[row][cb + j] = ldx(in, off + (long)krow * 256 + n0 + cb + j, fl);
  }
  __syncthreads();
  us4 o;
#pragma unroll
  for (int j = 0; j < 4; j++) o[j] = f2bu(tile[cb + j][row]);
  *(us4*)(out + off + (long)(n0 + row) * K + k0 + cb) = o;
}

// ------------------------------------------------------------------
// Unified MFMA GEMM v2, 64x64 tile, K-step 64 (proven round 5).
// ------------------------------------------------------------------
__global__ __launch_bounds__(256)
void gemm_mfma(const bf16* __restrict__ A, const bf16* __restrict__ BT,
               const void* __restrict__ bias,
               void* __restrict__ C, int cMode, int epi, int cT,
               const int* __restrict__ dtFlag, float* __restrict__ diagOut,
               float* __restrict__ svOut,
               int M, int N, int K, long sA, int divA, long sB, int modB, long sBias)
{
  __shared__ alignas(16) bf16 As[2][64 * 64];
  __shared__ alignas(16) bf16 Bs[2][64 * 64];
  const int fl = *dtFlag;
  const int cB = (cMode == 2) ? fl : cMode;
  const int t = threadIdx.x;
  const int bz = blockIdx.z;
  const long aOff = (long)(bz / divA) * sA;
  const long bOff = (long)(bz % modB) * sB;
  const long biasOff = (long)(bz % modB) * sBias;
  const long cOff = (long)bz * (long)M * N;
  const int m0 = blockIdx.y * 64, n0 = blockIdx.x * 64;
  const int w = t >> 6, l = t & 63, quad = l >> 4, ln = l & 15;
  const bf16* Ab = A + aOff + (long)m0 * K;
  const bf16* Bb = BT + bOff + (long)n0 * K;
  const int srow = l >> 3;            // 0..7 within the wave's 8-row slab
  const int scc = (l & 7) ^ srow;     // XOR swizzle chunk (row&7 == srow)
  f32x4 acc[4] = {};

  auto stage = [&](int buf, int k0) {
#pragma unroll
    for (int j = 0; j < 2; j++) {
      const int rbase = 32 * j + 8 * w;         // rbase&7 == 0
      const int row = rbase + srow;
      async_copy16(Ab + (long)row * K + k0 + scc * 8, &As[buf][rbase * 64]);
      async_copy16(Bb + (long)row * K + k0 + scc * 8, &Bs[buf][rbase * 64]);
    }
  };

  stage(0, 0);
  __syncthreads();   // full drain: buffer 0 ready

  int cur = 0;
  for (int k0 = 0; k0 < K; k0 += 64) {
    if (k0 + 64 < K) stage(cur ^ 1, k0 + 64);
    const bf16* Ac = &As[cur][0];
    const bf16* Bc = &Bs[cur][0];
    const int arow = 16 * w + ln;
#pragma unroll
    for (int ks = 0; ks < 2; ks++) {
      short8 a = *(const short8*)(Ac + arow * 64 + (((ks * 4 + quad) ^ (arow & 7)) << 3));
#pragma unroll
      for (int i = 0; i < 4; i++) {
        const int brow = 16 * i + ln;
        short8 b = *(const short8*)(Bc + brow * 64 + (((ks * 4 + quad) ^ (brow & 7)) << 3));
        acc[i] = __builtin_amdgcn_mfma_f32_16x16x32_bf16(a, b, acc[i], 0, 0, 0);
      }
    }
    asm volatile("s_waitcnt vmcnt(0)" ::: "memory");
    __builtin_amdgcn_s_barrier();
    __builtin_amdgcn_sched_barrier(0);
    cur ^= 1;
  }

  float s2[4] = {0.f, 0.f, 0.f, 0.f};
  if (cT == 2) {
    const int mm = m0 + 16 * w + quad * 4;
    const int tile = mm >> 5, off = mm & 31;
#pragma unroll
    for (int i = 0; i < 4; i++) {
      int n = n0 + 16 * i + ln;
      us4 cv;
      float colsum = 0.f;
#pragma unroll
      for (int r = 0; r < 4; r++) {
        float c = acc[i][r];
        if (epi >= 1) c += ldx(bias, biasOff + n, fl);
        if (epi == 2) c = fmaxf(c, 0.f);
        colsum += c;
        cv[r] = f2bu(c);
      }
      *(us4*)((bf16*)C + cOff + ((long)tile * N + n) * 32 + off) = cv;
      if (svOut) {
        colsum += __shfl_xor(colsum, 16);
        colsum += __shfl_xor(colsum, 32);
        if (quad == 0) atomicAdd(&svOut[(long)bz * N + n], colsum);
      }
    }
  } else {
#pragma unroll
    for (int i = 0; i < 4; i++) {
#pragma unroll
      for (int r = 0; r < 4; r++) {
        int m = m0 + 16 * w + quad * 4 + r;
        int n = n0 + 16 * i + ln;
        float c = acc[i][r];
        if (epi >= 1) c += ldx(bias, biasOff + n, fl);
        if (epi == 2) c = fmaxf(c, 0.f);
        s2[r] += c * c;
        stx(C, cOff + (long)m * N + n, c, cB);
      }
    }
  }
  if (diagOut) {
#pragma unroll
    for (int r = 0; r < 4; r++) {
      float s = s2[r];
      s += __shfl_xor(s, 1); s += __shfl_xor(s, 2);
      s += __shfl_xor(s, 4); s += __shfl_xor(s, 8);
      if (ln == 0)
        atomicAdd(&diagOut[(long)bz * M + m0 + 16 * w + quad * 4 + r], DIAG_SC * s);
    }
  }
}

// ------------------------------------------------------------------
// BM=32 GEMM (v2 staging) for the skinny dispatches. Optional label
// fold (labp != null): c += sum_{j<3} label[m*3+j]*labW[(256+j)*256+n]
// before the relu — replaces the fixup_h1 dispatch + h1 round-trip.
// ------------------------------------------------------------------
__global__ __launch_bounds__(256)
void gemm_mfma32v2(const bf16* __restrict__ A, const bf16* __restrict__ BT,
                   const void* __restrict__ bias,
                   void* __restrict__ C, int cMode, int epi,
                   const int* __restrict__ dtFlag, int M, int N, int K,
                   const void* __restrict__ labp, const void* __restrict__ labW)
{
  __shared__ alignas(16) bf16 As[2][32 * 64];
  __shared__ alignas(16) bf16 Bs[2][64 * 64];
  const int fl = *dtFlag;
  const int cB = (cMode == 2) ? fl : cMode;
  const int t = threadIdx.x;
  const int m0 = blockIdx.y * 32, n0 = blockIdx.x * 64;
  const int w = t >> 6, l = t & 63, quad = l >> 4, ln = l & 15;
  const int mi = w & 1, nh = w >> 1;
  const bf16* Ab = A + (long)m0 * K;
  const bf16* Bb = BT + (long)n0 * K;
  const int srow = l >> 3;
  const int scc = (l & 7) ^ srow;
  f32x4 acc[2] = {};

  auto stage = [&](int buf, int k0) {
    async_copy16(Ab + (long)(8 * w + srow) * K + k0 + scc * 8, &As[buf][(8 * w) * 64]);
#pragma unroll
    for (int j = 0; j < 2; j++) {
      const int rbase = 32 * j + 8 * w;
      async_copy16(Bb + (long)(rbase + srow) * K + k0 + scc * 8, &Bs[buf][rbase * 64]);
    }
  };

  stage(0, 0);
  __syncthreads();

  int cur = 0;
  for (int k0 = 0; k0 < K; k0 += 64) {
    if (k0 + 64 < K) stage(cur ^ 1, k0 + 64);
    const bf16* Ac = &As[cur][0];
    const bf16* Bc = &Bs[cur][0];
    const int arow = 16 * mi + ln;
#pragma unroll
    for (int ks = 0; ks < 2; ks++) {
      short8 a = *(const short8*)(Ac + arow * 64 + (((ks * 4 + quad) ^ (arow & 7)) << 3));
#pragma unroll
      for (int i = 0; i < 2; i++) {
        const int brow = 16 * (2 * nh + i) + ln;
        short8 b = *(const short8*)(Bc + brow * 64 + (((ks * 4 + quad) ^ (brow & 7)) << 3));
        acc[i] = __builtin_amdgcn_mfma_f32_16x16x32_bf16(a, b, acc[i], 0, 0, 0);
      }
    }
    asm volatile("s_waitcnt vmcnt(0)" ::: "memory");
    __builtin_amdgcn_s_barrier();
    __builtin_amdgcn_sched_barrier(0);
    cur ^= 1;
  }

#pragma unroll
  for (int i = 0; i < 2; i++) {
#pragma unroll
    for (int r = 0; r < 4; r++) {
      int m = m0 + 16 * mi + quad * 4 + r;
      int n = n0 + 16 * (2 * nh + i) + ln;
      float c = acc[i][r];
      if (epi >= 1) c += ldx(bias, n, fl);
      if (labp) {
#pragma unroll
        for (int j = 0; j < 3; j++)
          c += ldx(labp, (long)m * 3 + j, fl) * ldx(labW, (long)(256 + j) * 256 + n, fl);
      }
      if (epi == 2) c = fmaxf(c, 0.f);
      stx(C, (long)m * N + n, c, cB);
    }
  }
}

// ------------------------------------------------------------------
// Wo GEMM, split-K x2: partials traffic 8+8MB.
// ------------------------------------------------------------------
__global__ __launch_bounds__(256)
void gemm_wo_splitk(const bf16* __restrict__ A, const bf16* __restrict__ BT,
                    float* __restrict__ P, int M, int N, int K)
{
  __shared__ alignas(16) bf16 As[2][64 * 64];
  __shared__ alignas(16) bf16 Bs[2][64 * 64];
  const int t = threadIdx.x;
  const int z = blockIdx.z;
  const int m0 = blockIdx.y * 64, n0 = blockIdx.x * 64;
  const int w = t >> 6, l = t & 63, quad = l >> 4, ln = l & 15;
  const bf16* Ab = A + (long)m0 * K;
  const bf16* Bb = BT + (long)n0 * K;
  const int srow = l >> 3, scc = (l & 7) ^ srow;
  f32x4 acc[4] = {};
  const int kbase = z * 1024, kend = kbase + 1024;

  auto stage = [&](int buf, int k0) {
#pragma unroll
    for (int j = 0; j < 2; j++) {
      const int rbase = 32 * j + 8 * w;
      const int row = rbase + srow;
      async_copy16(Ab + (long)row * K + k0 + scc * 8, &As[buf][rbase * 64]);
      async_copy16(Bb + (long)row * K + k0 + scc * 8, &Bs[buf][rbase * 64]);
    }
  };

  stage(0, kbase);
  __syncthreads();

  int cur = 0;
  for (int k0 = kbase; k0 < kend; k0 += 64) {
    if (k0 + 64 < kend) stage(cur ^ 1, k0 + 64);
    const bf16* Ac = &As[cur][0];
    const bf16* Bc = &Bs[cur][0];
    const int arow = 16 * w + ln;
#pragma unroll
    for (int ks = 0; ks < 2; ks++) {
      short8 a = *(const short8*)(Ac + arow * 64 + (((ks * 4 + quad) ^ (arow & 7)) << 3));
#pragma unroll
      for (int i = 0; i < 4; i++) {
        const int brow = 16 * i + ln;
        short8 b = *(const short8*)(Bc + brow * 64 + (((ks * 4 + quad) ^ (brow & 7)) << 3));
        acc[i] = __builtin_amdgcn_mfma_f32_16x16x32_bf16(a, b, acc[i], 0, 0, 0);
      }
    }
    asm volatile("s_waitcnt vmcnt(0)" ::: "memory");
    __builtin_amdgcn_s_barrier();
    __builtin_amdgcn_sched_barrier(0);
    cur ^= 1;
  }

  float* Pz = P + (long)z * M * N;
#pragma unroll
  for (int i = 0; i < 4; i++) {
#pragma unroll
    for (int r = 0; r < 4; r++) {
      int m = m0 + 16 * w + quad * 4 + r;
      int n = n0 + 16 * i + ln;
      Pz[(long)m * N + n] = acc[i][r];
    }
  }
}

// rep[m][n] (bf16) = sum_z P[z][m][n] + bo[n]   (z = 2)
__global__ __launch_bounds__(256)
void reduce_partials(const float* __restrict__ P, const void* __restrict__ bo,
                     bf16* __restrict__ rep, const int* __restrict__ dtFlag)
{
  const int fl = *dtFlag;
  long idx = (long)blockIdx.x * 256 + threadIdx.x;
  int n = idx & 255;
  float s = ldx(bo, n, fl) + P[idx] + P[1048576 + idx];
  rep[idx] = __float2bfloat16(s);
}

// ------------------------------------------------------------------
// Key-side fused v9 (round-8 proven, 91.2us): v5 staging (kS[3],
// distance-2, one barrier/iter with vmcnt(4) lgkmcnt(0)) + de-atomized
// csRp/ktotp partial-store epilogue.
// ------------------------------------------------------------------
__global__ __launch_bounds__(256)
void key_fused_mfma(const bf16* __restrict__ k, const bf16* __restrict__ vQ,
                    const bf16* __restrict__ projB, const float* __restrict__ diagk,
                    float* __restrict__ ksumE, bf16* __restrict__ ctxQ,
                    float* __restrict__ mpart, float* __restrict__ csRp,
                    float* __restrict__ ktotp)
{
  __shared__ alignas(16) bf16 kS[3][32 * 256];
  __shared__ alignas(16) bf16 pS[2][64 * 40];
  __shared__ float wredM[4];
  __shared__ float wredK[4];

  const int bz = blockIdx.x, ft = blockIdx.y, f0 = ft * 64;
  const int t = threadIdx.x;
  const int w = t >> 6, l = t & 63, quad = l >> 4, ln = l & 15;
  const int fmine = f0 + 16 * w + ln;
  const bool fv = fmine < NBF;

  const bf16* kb = k + (long)bz * NC * 256;
  const bf16* vqb = vQ + (long)bz * 16 * 256 * 32;
  const float* db = diagk + bz * NC;

  auto stage = [&](int buf, int n0) {
#pragma unroll
    for (int j = 0; j < 4; j++) {
      int row = w * 8 + j * 2 + (l >> 5);
      int cc = (l & 31) ^ ((2 * j + (l >> 5)) & 7);   // = (l&31) ^ (row&7)
      async_copy16(kb + (long)(n0 + row) * 256 + cc * 8,
                   &kS[buf][w * 2048 + j * 512]);
    }
  };
  stage(0, 0);
  stage(1, 32);

  short8 pf[8];
  {
    const bf16* prow = projB + (long)fmine * 256;
#pragma unroll
    for (int kc = 0; kc < 8; kc++)
      pf[kc] = *(const short8*)(prow + kc * 32 + quad * 8);
  }

  f32x4 acc[4][4] = {};
  float ksumP = 0.f, mP = -1e30f;

  __syncthreads();   // full drain once: kS[0], kS[1] + pf ready

  int cur = 0;       // buffer holding tile `it`
  for (int it = 0; it < 16; it++) {
    const int n0 = it * 32;
    short8 bfr[4];
#pragma unroll
    for (int ei = 0; ei < 4; ei++) {
      int e = 64 * w + 16 * ei + ln;
      bfr[ei] = *(const short8*)(vqb + ((long)it * 256 + e) * 32 + quad * 8);
    }
    f32x4 dv0 = *(const f32x4*)(db + n0 + quad * 4);
    f32x4 dv1 = *(const f32x4*)(db + n0 + 16 + quad * 4);
    __builtin_amdgcn_sched_barrier(0);
    if (it + 2 < 16) {
      int nb = cur + 2; if (nb >= 3) nb -= 3;
      stage(nb, n0 + 64);
    }
    __builtin_amdgcn_sched_barrier(0);

    const bf16* kcur = &kS[cur][0];
    f32x4 dd[2][2] = {};
    __builtin_amdgcn_s_setprio(1);
#pragma unroll
    for (int kc = 0; kc < 8; kc++) {
      const int hf = kc & 1;
#pragma unroll
      for (int mi = 0; mi < 2; mi++) {
        short8 a = *(const short8*)(kcur + (16 * mi + ln) * 256 +
                                    (((kc * 4 + quad) ^ (ln & 7)) << 3));
        dd[mi][hf] = __builtin_amdgcn_mfma_f32_16x16x32_bf16(a, pf[kc], dd[mi][hf], 0, 0, 0);
      }
    }
    __builtin_amdgcn_s_setprio(0);
    bf16* pcur = &pS[it & 1][0];
#pragma unroll
    for (int mi = 0; mi < 2; mi++) {
      us4 ev;
      f32x4 dvv = mi ? dv1 : dv0;
#pragma unroll
      for (int r = 0; r < 4; r++) {
        float sc = DN * (dd[mi][0][r] + dd[mi][1][r]);
        float E = fv ? __expf(fminf(sc - dvv[r], 80.f)) : 0.f;
        unsigned short u = f2bu(E);
        ksumP += bf2f(u);
        if (fv) mP = fmaxf(mP, sc);
        ev[r] = u;
      }
      *(us4*)(pcur + (16 * w + ln) * 40 + 16 * mi + quad * 4) = ev;
    }
    // single barrier: pS visible (lgkmcnt 0), kS[it+1] complete (vmcnt 4:
    // everything older than the 4 stage(it+2) DMAs is done)
    asm volatile("s_waitcnt vmcnt(4) lgkmcnt(0)" ::: "memory");
    __builtin_amdgcn_s_barrier();
    __builtin_amdgcn_sched_barrier(0);

    __builtin_amdgcn_s_setprio(1);
#pragma unroll
    for (int fh = 0; fh < 4; fh++) {
      short8 a = *(const short8*)(pcur + (16 * fh + ln) * 40 + quad * 8);
#pragma unroll
      for (int ei = 0; ei < 4; ei++)
        acc[fh][ei] = __builtin_amdgcn_mfma_f32_16x16x32_bf16(a, bfr[ei], acc[fh][ei], 0, 0, 0);
    }
    __builtin_amdgcn_s_setprio(0);
    cur = (cur == 2) ? 0 : cur + 1;
  }
  __syncthreads();

#pragma unroll
  for (int fh = 0; fh < 4; fh++) {
    const int ft32 = 2 * ft + (fh >> 1);
    const int f32b = 16 * (fh & 1) + quad * 4;
#pragma unroll
    for (int ei = 0; ei < 4; ei++) {
      int e = 64 * w + 16 * ei + ln;
      us4 cv;
#pragma unroll
      for (int r = 0; r < 4; r++) cv[r] = f2bu(acc[fh][ei][r]);
      *(us4*)(&ctxQ[((long)(bz * FT32 + ft32) * 256 + e) * 32 + f32b]) = cv;
    }
  }

  // csRp partial: column sum over this block's 64 f-rows per e (plain store)
#pragma unroll
  for (int ei = 0; ei < 4; ei++) {
    float col = 0.f;
#pragma unroll
    for (int fh = 0; fh < 4; fh++)
#pragma unroll
      for (int r = 0; r < 4; r++) col += acc[fh][ei][r];
    col += __shfl_xor(col, 16);
    col += __shfl_xor(col, 32);
    if (quad == 0)
      csRp[((long)bz * 23 + ft) * 256 + 64 * w + 16 * ei + ln] = col;
  }

  float s = ksumP;
  s += __shfl_xor(s, 16); s += __shfl_xor(s, 32);
  if (quad == 0 && fv) ksumE[(long)bz * NBF + fmine] = s;
  // ktotp partial: per-wave sum over its 16 f-rows, combined via LDS
  float s2 = s;
  s2 += __shfl_xor(s2, 1); s2 += __shfl_xor(s2, 2);
  s2 += __shfl_xor(s2, 4); s2 += __shfl_xor(s2, 8);
  if (l == 0) wredK[w] = s2;

  float m = mP;
#pragma unroll
  for (int off = 1; off < 64; off <<= 1) m = fmaxf(m, __shfl_xor(m, off));
  if (l == 0) wredM[w] = m;
  __syncthreads();
  if (t == 0) {
    mpart[bz * 23 + ft] = fmaxf(fmaxf(wredM[0], wredM[1]), fmaxf(wredM[2], wredM[3]));
    ktotp[bz * 23 + ft] = wredK[0] + wredK[1] + wredK[2] + wredK[3];
  }
}

// ------------------------------------------------------------------
// finalize_red: partials -> mk (max), csR (sum over ft), ktotR (sum).
// ------------------------------------------------------------------
__global__ __launch_bounds__(256)
void finalize_red(const float* __restrict__ mpart, const float* __restrict__ csRp,
                  const float* __restrict__ ktotp, float* __restrict__ mk,
                  float* __restrict__ csR, float* __restrict__ ktotR)
{
  int bz = blockIdx.x, t = threadIdx.x;
  float s = 0.f;
  for (int ft = 0; ft < 23; ft++)
    s += csRp[((long)bz * 23 + ft) * 256 + t];
  csR[bz * 256 + t] = s;
  int w = t >> 6, l = t & 63;
  if (w == 0) {
    float m = (l < 23) ? mpart[bz * 23 + l] : -1e30f;
#pragma unroll
    for (int off = 32; off > 0; off >>= 1) m = fmaxf(m, __shfl_down(m, off));
    if (l == 0) mk[bz] = m;
  } else if (w == 1) {
    float kk = (l < 23) ? ktotp[bz * 23 + l] : 0.f;
#pragma unroll
    for (int off = 32; off > 0; off >>= 1) kk += __shfl_down(kk, off);
    if (l == 0) ktotR[bz] = kk;
  }
}

// ------------------------------------------------------------------
// Query-side fused v8: the proven v5 schedule ported from key_fused —
// projS[3] triple-buffer, stage distance 2, eS[2] double-buffer, ONE
// barrier per iteration with counted vmcnt(4) lgkmcnt(0), setprio on
// both MFMA clusters. 46 barriers (was 92); stage latency hidden a
// full iteration ahead. Safety: eS[ft&1] overwrite at ft+2 is behind
// barrier(ft+1) which all waves reach only after Phase B(ft); the
// projS buffer staged at ft (for ft+2) was last read in PhaseA(ft-1),
// behind barrier(ft-1). LDS ~61KB, residency VGPR-capped at 2 blocks
// either way (no occupancy loss). Finalize-fold algebra unchanged.
// ------------------------------------------------------------------
__global__ __launch_bounds__(256)
void q_fused_mfma(const bf16* __restrict__ q, const bf16* __restrict__ projB,
                  const float* __restrict__ diagq, const bf16* __restrict__ ctxQ,
                  const float* __restrict__ ksum, const float* __restrict__ Sv,
                  const float* __restrict__ csR, const float* __restrict__ ktotR,
                  const float* __restrict__ mk, bf16* __restrict__ merged)
{
  __shared__ alignas(16) bf16 projS[3][32 * 256];
  __shared__ alignas(16) bf16 eS[2][64 * 40];
  __shared__ float dS[64];
  __shared__ float svS[256];
  __shared__ float crS[256];
  __shared__ float sS[64];
  __shared__ float mS[64];
  __shared__ float seS[64];

  const int bz = blockIdx.x, nt = blockIdx.y, t = threadIdx.x;
  const int w = t >> 6, l = t & 63, quad = l >> 4, ln = l & 15;
  const int tq = bz / H_, hh = bz % H_;
  const bf16* cqb = ctxQ + (long)bz * FT32 * 256 * 32;
  const bf16* qb = q + ((long)bz * NT + nt * 64) * 256;
  const float emk = __expf(-mk[bz]);

  auto stage_proj = [&](int buf, int f0n) {
#pragma unroll
    for (int j = 0; j < 4; j++) {
      int row = 8 * w + 2 * j + (l >> 5);
      int cc = (l & 31) ^ (row & 7);
      async_copy16(projB + (long)(f0n + row) * 256 + cc * 8,
                   &projS[buf][(8 * w + 2 * j) * 256]);
    }
  };
  stage_proj(0, 0);
  stage_proj(1, 32);

  // q fragments: no ft dependence -> load once, keep in 32 VGPRs
  short8 qf[8];
  {
    const bf16* qrow = qb + (long)(16 * w + ln) * 256;
#pragma unroll
    for (int kc = 0; kc < 8; kc++)
      qf[kc] = *(const short8*)(qrow + kc * 32 + quad * 8);
  }
  if (t < 64) dS[t] = diagq[(long)bz * NT + nt * 64 + t];
  svS[t] = Sv[bz * 256 + t];
  crS[t] = csR[bz * 256 + t];

  f32x4 acc[4][4] = {};           // [mh][ei]: rows 16mh+quad*4+r, e=16(4w+ei)+ln
  float sPart[4] = {0.f, 0.f, 0.f, 0.f};   // stR partial (rows 16w+quad*4+r)
  float sEp[4] = {0.f, 0.f, 0.f, 0.f};     // sE partial
  float mPart[4] = {0.f, 0.f, 0.f, 0.f};
  __syncthreads();   // full drain: projS[0..1] + LDS scalars ready

  int cur = 0;       // buffer holding tile `ft`
  for (int ft = 0; ft < FT32; ft++) {
    const int f0 = ft * 32;
    const bf16* pcur = &projS[cur][0];
    short8 cfr[4];
#pragma unroll
    for (int i = 0; i < 4; i++) {
      int e = 16 * (4 * w + i) + ln;
      cfr[i] = *(const short8*)(cqb + ((long)ft * 256 + e) * 32 + quad * 8);
    }
    const float kv0 = (f0 + ln < NBF) ? ksum[(long)bz * NBF + f0 + ln] : 0.f;
    const float kv1 = (f0 + 16 + ln < NBF) ? ksum[(long)bz * NBF + f0 + 16 + ln] : 0.f;
    __builtin_amdgcn_sched_barrier(0);
    if (ft + 2 < FT32) {
      int nb = cur + 2; if (nb >= 3) nb -= 3;
      stage_proj(nb, f0 + 64);
    }
    __builtin_amdgcn_sched_barrier(0);

    // Phase A: wave w owns rows 16w..16w+15, both f-halves
    f32x4 dd0 = {}, dd1 = {};
    __builtin_amdgcn_s_setprio(1);
#pragma unroll
    for (int kc = 0; kc < 8; kc++) {
      const int co = ((kc * 4 + quad) ^ (ln & 7)) << 3;
      short8 b0 = *(const short8*)(pcur + ln * 256 + co);
      dd0 = __builtin_amdgcn_mfma_f32_16x16x32_bf16(qf[kc], b0, dd0, 0, 0, 0);
      short8 b1 = *(const short8*)(pcur + (16 + ln) * 256 + co);
      dd1 = __builtin_amdgcn_mfma_f32_16x16x32_bf16(qf[kc], b1, dd1, 0, 0, 0);
    }
    __builtin_amdgcn_s_setprio(0);
    const bool fv0 = (f0 + ln) < NBF;
    const bool fv1 = (f0 + 16 + ln) < NBF;
    bf16* ecur = &eS[ft & 1][0];
#pragma unroll
    for (int r = 0; r < 4; r++) {
      float E0 = fv0 ? __expf(fminf(DN * dd0[r], 80.f)) : 0.f;
      float E1 = fv1 ? __expf(fminf(DN * dd1[r], 80.f)) : 0.f;
      bf16 h0 = __float2bfloat16(E0), h1v = __float2bfloat16(E1);
      float e0 = tofloat(h0), e1 = tofloat(h1v);
      ecur[(16 * w + quad * 4 + r) * 40 + ln] = h0;
      ecur[(16 * w + quad * 4 + r) * 40 + 16 + ln] = h1v;
      sPart[r] += e0 * kv0 + e1 * kv1;
      sEp[r] += e0 + e1;
      mPart[r] = fmaxf(mPart[r], fmaxf(e0, e1));
    }
    // single barrier: eS visible (lgkmcnt 0), projS for ft+1 complete
    // (vmcnt 4: everything older than the 4 stage(ft+2) DMAs is done)
    asm volatile("s_waitcnt vmcnt(4) lgkmcnt(0)" ::: "memory");
    __builtin_amdgcn_s_barrier();
    __builtin_amdgcn_sched_barrier(0);

    // Phase B: all 4 m-halves, 4 e-tiles each (cfr reused)
    __builtin_amdgcn_s_setprio(1);
#pragma unroll
    for (int mh = 0; mh < 4; mh++) {
      short8 a = *(const short8*)(ecur + (16 * mh + ln) * 40 + quad * 8);
#pragma unroll
      for (int i = 0; i < 4; i++)
        acc[mh][i] = __builtin_amdgcn_mfma_f32_16x16x32_bf16(a, cfr[i], acc[mh][i], 0, 0, 0);
    }
    __builtin_amdgcn_s_setprio(0);
    cur = (cur == 2) ? 0 : cur + 1;
  }
  __syncthreads();

  // wave-private row stats: reduce over 16 lanes
#pragma unroll
  for (int r = 0; r < 4; r++) {
    float s = sPart[r], m = mPart[r], se = sEp[r];
#pragma unroll
    for (int off = 1; off < 16; off <<= 1) {
      s += __shfl_xor(s, off);
      m = fmaxf(m, __shfl_xor(m, off));
      se += __shfl_xor(se, off);
    }
    if (ln == 0) {
      sS[16 * w + quad * 4 + r] = s;
      mS[16 * w + quad * 4 + r] = m;
      seS[16 * w + quad * 4 + r] = se;
    }
  }
  __syncthreads();

  const float ktotv = ktotR[bz];
#pragma unroll
  for (int mh = 0; mh < 4; mh++) {
#pragma unroll
    for (int r = 0; r < 4; r++) {
      int row = 16 * mh + quad * 4 + r;
      float st = sS[row];
      float se = seS[row];
      float mt = fmaxf(mS[row], 1e-30f);
      float c = __expf(-dS[row]) / mt;
      float A = c * se + (float)NBF * EPS_;
      float den = emk * (c * st + EPS_ * ktotv) + (float)NC * EPS_ * A;
      float inv = 1.f / den;
#pragma unroll
      for (int i = 0; i < 4; i++) {
        int e = 16 * (4 * w + i) + ln;
        float val = (emk * (c * acc[mh][i][r] + EPS_ * crS[e]) + EPS_ * svS[e] * A) * inv;
        merged[((long)tq * NT + nt * 64 + row) * 2048 + hh * 256 + e] =
            __float2bfloat16(val);
      }
    }
  }
}

// ------------------------------------------------------------------
extern "C" void kernel_launch(void* const* d_in, const int* in_sizes, int n_in,
                              void* d_out, int out_size, void* d_ws, size_t ws_size,
                              hipStream_t stream)
{
  const void* x_ctx = d_in[0];
  const void* label = d_in[1];
  const void* x_tgt = d_in[2];
  const void* W1 = d_in[3];
  const void* b1 = d_in[4];
  const void* W2 = d_in[5];
  const void* b2 = d_in[6];
  const void* W3 = d_in[7];
  const void* b3 = d_in[8];
  const void* Wk = d_in[9];
  const void* bk = d_in[10];
  const void* Wv = d_in[11];
  const void* bv = d_in[12];
  const void* Wq = d_in[13];
  const void* bq = d_in[14];
  const void* Wo = d_in[15];
  const void* bo = d_in[16];
  const void* Wmu = d_in[17];
  const void* bmu = d_in[18];
  const void* proj = d_in[19];

  // Arena (floats), peak ~91 MB. Overlays:
  //  xcB @ F2+1572864 (after cf; dead before ctxQ is written by key_fused)
  //  xtB @ F1 (vQ region; vQ dead after key_fused, merged written after q-proj)
  float* W = (float*)d_ws;
  const long F0 = 0, F1 = 4194304, F2 = 8388608;
  const long CTXQ_F = (long)64 * FT32 * 256 * 32 / 2;
  const long F3 = F2 + CTXQ_F;
  bf16* kB = (bf16*)(W + F0);
  bf16* qB = (bf16*)(W + F0);
  bf16* rep = (bf16*)(W + F0);
  bf16* vQ = (bf16*)(W + F1);
  bf16* merged = (bf16*)(W + F1);
  bf16* xtB = (bf16*)(W + F1);
  bf16* h1 = (bf16*)(W + F2);
  bf16* h2 = (bf16*)(W + F2 + 524288);
  bf16* cf = (bf16*)(W + F2 + 1048576);
  bf16* xcB = (bf16*)(W + F2 + 1572864);
  bf16* ctxQ = (bf16*)(W + F2);
  float* woP = W + F2;
  long o = F3;
  auto alloc = [&](long n) { float* p = W + o; o += n; return p; };
  float* zbase = W + o;
  float* dgk = alloc(32768);
  float* dgq = alloc(32768);
  float* Sv = alloc(64 * 256);          // end of zeroed region (320 blocks)
  float* csR = alloc(64 * 256);
  float* ktotR = alloc(64);
  alloc(192);
  float* ksumE = alloc((long)64 * NBF);
  float* mpart = alloc(64 * 23);
  float* mk = alloc(64);
  int* dtFlag = (int*)alloc(64);
  float* csRp = alloc((long)64 * 23 * 256);
  float* ktotp = alloc(64 * 23);
  bf16* projB = (bf16*)alloc((long)FT32 * 32 * 256 / 2);
  bf16* WkT = (bf16*)alloc(262144);   // 8 x 256 x 256 bf16
  bf16* WvT = (bf16*)alloc(262144);
  bf16* WqT = (bf16*)alloc(262144);
  bf16* WoT = (bf16*)alloc(262144);   // 256 x 2048 bf16 (perm folded)
  bf16* W1T = (bf16*)alloc(32768);    // 256 x 256 bf16
  bf16* W2T = (bf16*)alloc(32768);
  bf16* W3T = (bf16*)alloc(32768);
  bf16* WmuT = (bf16*)alloc(32768);
  (void)ws_size; (void)in_sizes; (void)n_in; (void)out_size;

  const dim3 B(256);
  detect_dtype<<<1, B, 0, stream>>>(x_ctx, dtFlag);
  // merged prep: weight transposes + conv_proj + xcB convert + zeroing
  prep_all<<<dim3(64, 8, 31), B, 0, stream>>>(
      Wk, Wv, Wq, Wo, W1, W2, W3, Wmu, proj, x_ctx,
      WkT, WvT, WqT, WoT, W1T, W2T, W3T, WmuT, projB, xcB, zbase, dtFlag);
  // 1. task-encoder MLP (BM=32 async gemm; layer 1 folds label+relu)
  gemm_mfma32v2<<<dim3(4, 128), B, 0, stream>>>(
      xcB, W1T, b1, h1, 1, 2, dtFlag, 4096, 256, 256, label, W1);
  gemm_mfma32v2<<<dim3(4, 128), B, 0, stream>>>(
      h1, W2T, b2, h2, 1, 2, dtFlag, 4096, 256, 256, nullptr, nullptr);
  gemm_mfma32v2<<<dim3(4, 128), B, 0, stream>>>(
      h2, W3T, b3, cf, 1, 2, dtFlag, 4096, 256, 256, nullptr, nullptr);
  // 2. k projection (fused diag), v projection (tiled -> vQ, fused Sv)
  gemm_mfma<<<dim3(4, 8, 64), B, 0, stream>>>(
      xcB, WkT, bk, kB, 1, 1, 0, dtFlag, dgk, nullptr,
      512, 256, 256, 131072L, 8, 65536L, 8, 256L);
  gemm_mfma<<<dim3(4, 8, 64), B, 0, stream>>>(
      cf, WvT, bv, vQ, 1, 1, 2, dtFlag, nullptr, Sv,
      512, 256, 256, 131072L, 8, 65536L, 8, 256L);
  // 3. key side (emits csRp / ktotp partials, no atomics)
  key_fused_mfma<<<dim3(64, 23), B, 0, stream>>>(kB, vQ, projB, dgk, ksumE, ctxQ,
                                                 mpart, csRp, ktotp);
  finalize_red<<<64, B, 0, stream>>>(mpart, csRp, ktotp, mk, csR, ktotR);
  // 4. q projection (fused diag); xtB converted now (vQ region is dead)
  conv_bf16<<<4096, B, 0, stream>>>(x_tgt, xtB, dtFlag);
  gemm_mfma<<<dim3(4, 8, 64), B, 0, stream>>>(
      xtB, WqT, bq, qB, 1, 1, 0, dtFlag, dgq, nullptr,
      512, 256, 256, 131072L, 8, 65536L, 8, 256L);
  // 5. query side v8 (single-barrier schedule) -> merged [t][n][h][e]
  q_fused_mfma<<<dim3(64, 8), B, 0, stream>>>(qB, projB, dgq, ctxQ, ksumE,
                                              Sv, csR, ktotR, mk, merged);
  // 6. Wo split-K x2 -> fp32 partials, reduce, Wmu
  gemm_wo_splitk<<<dim3(4, 64, 2), B, 0, stream>>>(merged, WoT, woP, 4096, 256, 2048);
  reduce_partials<<<4096, B, 0, stream>>>(woP, bo, rep, dtFlag);
  gemm_mfma32v2<<<dim3(4, 128), B, 0, stream>>>(
      rep, WmuT, bmu, d_out, 2, 1, dtFlag, 4096, 256, 256, nullptr, nullptr);
}

// Round 11
// 368.516 us; speedup vs baseline: 2.0157x; 1.0222x over previous
//
#include <hip/hip_runtime.h>
#include <hip/hip_bf16.h>

typedef __hip_bfloat16 bf16;
typedef __attribute__((ext_vector_type(8))) short short8;
typedef __attribute__((ext_vector_type(4))) float f32x4;
typedef __attribute__((ext_vector_type(4))) unsigned short us4;
#define DEV __device__ __forceinline__

static constexpr int T_ = 8, NC = 512, NT = 512, D_ = 256, H_ = 8, NBF = 1419;
static constexpr int FT32 = 46;             // 46 f-tiles of 32 (padded 1472)
static constexpr float EPS_ = 1e-4f;
static constexpr float DN = 0.25f;          // D^-0.25
static constexpr float DIAG_SC = 0.03125f;  // 0.5 * DN^2

DEV float bf2f(unsigned short u) { return __uint_as_float(((unsigned)u) << 16); }
DEV float tofloat(bf16 x) { return __bfloat162float(x); }
DEV unsigned short f2bu(float x) { bf16 h = __float2bfloat16(x); return *(unsigned short*)&h; }

DEV float ldx(const void* p, long i, int isb) {
  if (isb) return bf2f(((const unsigned short*)p)[i]);
  return ((const float*)p)[i];
}
DEV void stx(void* p, long i, float v, int isb) {
  if (isb) ((bf16*)p)[i] = __float2bfloat16(v);
  else     ((float*)p)[i] = v;
}

// async global->LDS 16B (wave-uniform LDS base + lane*16; global addr per-lane)
DEV void async_copy16(const void* g, void* lds) {
  __builtin_amdgcn_global_load_lds(
      (const __attribute__((address_space(1))) unsigned int*)g,
      (__attribute__((address_space(3))) unsigned int*)lds, 16, 0, 0);
}

// ------------------------------------------------------------------
// dtype probe (1 = bf16 inputs, 0 = fp32)
// ------------------------------------------------------------------
__global__ __launch_bounds__(256)
void detect_dtype(const void* __restrict__ x, int* __restrict__ flag)
{
  __shared__ int bad;
  if (threadIdx.x == 0) bad = 0;
  __syncthreads();
  int mybad = 0;
  for (int j = 0; j < 16; j++) {
    long i = 2L * (threadIdx.x + 256L * j);
    unsigned short u = ((const unsigned short*)x)[i];
    int e = (u >> 7) & 0xff, mant = u & 0x7f;
    bool b = (e == 0xff) || (e >= 141) || (e <= 93 && !(e == 0 && mant == 0));
    mybad += b ? 1 : 0;
  }
  atomicAdd(&bad, mybad);
  __syncthreads();
  if (threadIdx.x == 0) *flag = (bad > 1024) ? 0 : 1;
}

// generic activation convert -> bf16 (1M elements, grid 4096) — xtB only
__global__ __launch_bounds__(256)
void conv_bf16(const void* __restrict__ src, bf16* __restrict__ dst,
               const int* __restrict__ dtFlag)
{
  const int fl = *dtFlag;
  long i = (long)blockIdx.x * 256 + threadIdx.x;
  dst[i] = __float2bfloat16(ldx(src, i, fl));
}

// ------------------------------------------------------------------
// prep_all: merged prep. Grid (64,8,31):
//  z 0..28 : weight pre-transpose W[k][n]->WT[n][k] bf16 (Wo folds the
//            merged-k permutation).
//  z == 29 : conv_proj — 3 f-rows per block.
//  z == 30 : xcB bf16 convert + zero of dgk/dgq/Sv atomic region.
// ------------------------------------------------------------------
__global__ __launch_bounds__(256)
void prep_all(const void* __restrict__ Wk, const void* __restrict__ Wv,
              const void* __restrict__ Wq, const void* __restrict__ Wo,
              const void* __restrict__ W1, const void* __restrict__ W2,
              const void* __restrict__ W3, const void* __restrict__ Wmu,
              const void* __restrict__ proj, const void* __restrict__ x_ctx,
              bf16* __restrict__ WkT, bf16* __restrict__ WvT,
              bf16* __restrict__ WqT, bf16* __restrict__ WoT,
              bf16* __restrict__ W1T, bf16* __restrict__ W2T,
              bf16* __restrict__ W3T, bf16* __restrict__ WmuT,
              bf16* __restrict__ projB, bf16* __restrict__ xcB,
              float* __restrict__ zbase, const int* __restrict__ dtFlag)
{
  __shared__ float tile[32][33];
  const int fl = *dtFlag;
  const int kt = blockIdx.x, nt = blockIdx.y, z = blockIdx.z, t = threadIdx.x;

  if (z == 29) {              // conv_proj
    int b = nt * 64 + kt;
#pragma unroll
    for (int r = 0; r < 3; r++) {
      int f = b * 3 + r;
      if (f < FT32 * 32) {
        float v = (f < NBF) ? ldx(proj, (long)f * 256 + t, fl) : 0.f;
        projB[(long)f * 256 + t] = __float2bfloat16(v);
      }
    }
    return;
  }
  if (z == 30) {              // xcB convert + atomic-region zero
    int b = nt * 64 + kt;
#pragma unroll
    for (int j = 0; j < 8; j++) {
      long i = (long)b * 2048 + j * 256 + t;
      xcB[i] = __float2bfloat16(ldx(x_ctx, i, fl));
    }
    if (b < 320) zbase[b * 256 + t] = 0.f;
    return;
  }

  const void* in; bf16* out; int K; int perm = 0; long off = 0;
  if (z < 8)        { in = Wk;  out = WkT;  K = 256; off = (long)z * 65536; }
  else if (z < 16)  { in = Wv;  out = WvT;  K = 256; off = (long)(z - 8) * 65536; }
  else if (z < 24)  { in = Wq;  out = WqT;  K = 256; off = (long)(z - 16) * 65536; }
  else if (z == 24) { in = Wo;  out = WoT;  K = 2048; perm = 1; }
  else if (z == 25) { in = W1;  out = W1T;  K = 256; }
  else if (z == 26) { in = W2;  out = W2T;  K = 256; }
  else if (z == 27) { in = W3;  out = W3T;  K = 256; }
  else              { in = Wmu; out = WmuT; K = 256; }
  if (K == 256 && kt >= 8) return;
  const int k0 = kt * 32, n0 = nt * 32;
  const int row = t >> 3, cb = (t & 7) * 4;
  {
    int kk = k0 + row;
    int krow = perm ? (((kk & 255) << 3) | (kk >> 8)) : kk;
#pragma unroll
    for (int j = 0; j < 4; j++)
      tile[row][cb + j] = ldx(in, off + (long)krow * 256 + n0 + cb + j, fl);
  }
  __syncthreads();
  us4 o;
#pragma unroll
  for (int j = 0; j < 4; j++) o[j] = f2bu(tile[cb + j][row]);
  *(us4*)(out + off + (long)(n0 + row) * K + k0 + cb) = o;
}

// ------------------------------------------------------------------
// Unified MFMA GEMM v2, 64x64 tile, K-step 64 (proven round 5).
// ------------------------------------------------------------------
__global__ __launch_bounds__(256)
void gemm_mfma(const bf16* __restrict__ A, const bf16* __restrict__ BT,
               const void* __restrict__ bias,
               void* __restrict__ C, int cMode, int epi, int cT,
               const int* __restrict__ dtFlag, float* __restrict__ diagOut,
               float* __restrict__ svOut,
               int M, int N, int K, long sA, int divA, long sB, int modB, long sBias)
{
  __shared__ alignas(16) bf16 As[2][64 * 64];
  __shared__ alignas(16) bf16 Bs[2][64 * 64];
  const int fl = *dtFlag;
  const int cB = (cMode == 2) ? fl : cMode;
  const int t = threadIdx.x;
  const int bz = blockIdx.z;
  const long aOff = (long)(bz / divA) * sA;
  const long bOff = (long)(bz % modB) * sB;
  const long biasOff = (long)(bz % modB) * sBias;
  const long cOff = (long)bz * (long)M * N;
  const int m0 = blockIdx.y * 64, n0 = blockIdx.x * 64;
  const int w = t >> 6, l = t & 63, quad = l >> 4, ln = l & 15;
  const bf16* Ab = A + aOff + (long)m0 * K;
  const bf16* Bb = BT + bOff + (long)n0 * K;
  const int srow = l >> 3;            // 0..7 within the wave's 8-row slab
  const int scc = (l & 7) ^ srow;     // XOR swizzle chunk (row&7 == srow)
  f32x4 acc[4] = {};

  auto stage = [&](int buf, int k0) {
#pragma unroll
    for (int j = 0; j < 2; j++) {
      const int rbase = 32 * j + 8 * w;         // rbase&7 == 0
      const int row = rbase + srow;
      async_copy16(Ab + (long)row * K + k0 + scc * 8, &As[buf][rbase * 64]);
      async_copy16(Bb + (long)row * K + k0 + scc * 8, &Bs[buf][rbase * 64]);
    }
  };

  stage(0, 0);
  __syncthreads();   // full drain: buffer 0 ready

  int cur = 0;
  for (int k0 = 0; k0 < K; k0 += 64) {
    if (k0 + 64 < K) stage(cur ^ 1, k0 + 64);
    const bf16* Ac = &As[cur][0];
    const bf16* Bc = &Bs[cur][0];
    const int arow = 16 * w + ln;
#pragma unroll
    for (int ks = 0; ks < 2; ks++) {
      short8 a = *(const short8*)(Ac + arow * 64 + (((ks * 4 + quad) ^ (arow & 7)) << 3));
#pragma unroll
      for (int i = 0; i < 4; i++) {
        const int brow = 16 * i + ln;
        short8 b = *(const short8*)(Bc + brow * 64 + (((ks * 4 + quad) ^ (brow & 7)) << 3));
        acc[i] = __builtin_amdgcn_mfma_f32_16x16x32_bf16(a, b, acc[i], 0, 0, 0);
      }
    }
    asm volatile("s_waitcnt vmcnt(0)" ::: "memory");
    __builtin_amdgcn_s_barrier();
    __builtin_amdgcn_sched_barrier(0);
    cur ^= 1;
  }

  float s2[4] = {0.f, 0.f, 0.f, 0.f};
  if (cT == 2) {
    const int mm = m0 + 16 * w + quad * 4;
    const int tile = mm >> 5, off = mm & 31;
#pragma unroll
    for (int i = 0; i < 4; i++) {
      int n = n0 + 16 * i + ln;
      us4 cv;
      float colsum = 0.f;
#pragma unroll
      for (int r = 0; r < 4; r++) {
        float c = acc[i][r];
        if (epi >= 1) c += ldx(bias, biasOff + n, fl);
        if (epi == 2) c = fmaxf(c, 0.f);
        colsum += c;
        cv[r] = f2bu(c);
      }
      *(us4*)((bf16*)C + cOff + ((long)tile * N + n) * 32 + off) = cv;
      if (svOut) {
        colsum += __shfl_xor(colsum, 16);
        colsum += __shfl_xor(colsum, 32);
        if (quad == 0) atomicAdd(&svOut[(long)bz * N + n], colsum);
      }
    }
  } else {
#pragma unroll
    for (int i = 0; i < 4; i++) {
#pragma unroll
      for (int r = 0; r < 4; r++) {
        int m = m0 + 16 * w + quad * 4 + r;
        int n = n0 + 16 * i + ln;
        float c = acc[i][r];
        if (epi >= 1) c += ldx(bias, biasOff + n, fl);
        if (epi == 2) c = fmaxf(c, 0.f);
        s2[r] += c * c;
        stx(C, cOff + (long)m * N + n, c, cB);
      }
    }
  }
  if (diagOut) {
#pragma unroll
    for (int r = 0; r < 4; r++) {
      float s = s2[r];
      s += __shfl_xor(s, 1); s += __shfl_xor(s, 2);
      s += __shfl_xor(s, 4); s += __shfl_xor(s, 8);
      if (ln == 0)
        atomicAdd(&diagOut[(long)bz * M + m0 + 16 * w + quad * 4 + r], DIAG_SC * s);
    }
  }
}

// ------------------------------------------------------------------
// BM=32 GEMM (v2 staging) for skinny dispatches. Optional label fold.
// Generic K (used with K=2048 for the Wo GEMM, replacing splitk+reduce).
// ------------------------------------------------------------------
__global__ __launch_bounds__(256)
void gemm_mfma32v2(const bf16* __restrict__ A, const bf16* __restrict__ BT,
                   const void* __restrict__ bias,
                   void* __restrict__ C, int cMode, int epi,
                   const int* __restrict__ dtFlag, int M, int N, int K,
                   const void* __restrict__ labp, const void* __restrict__ labW)
{
  __shared__ alignas(16) bf16 As[2][32 * 64];
  __shared__ alignas(16) bf16 Bs[2][64 * 64];
  const int fl = *dtFlag;
  const int cB = (cMode == 2) ? fl : cMode;
  const int t = threadIdx.x;
  const int m0 = blockIdx.y * 32, n0 = blockIdx.x * 64;
  const int w = t >> 6, l = t & 63, quad = l >> 4, ln = l & 15;
  const int mi = w & 1, nh = w >> 1;
  const bf16* Ab = A + (long)m0 * K;
  const bf16* Bb = BT + (long)n0 * K;
  const int srow = l >> 3;
  const int scc = (l & 7) ^ srow;
  f32x4 acc[2] = {};

  auto stage = [&](int buf, int k0) {
    async_copy16(Ab + (long)(8 * w + srow) * K + k0 + scc * 8, &As[buf][(8 * w) * 64]);
#pragma unroll
    for (int j = 0; j < 2; j++) {
      const int rbase = 32 * j + 8 * w;
      async_copy16(Bb + (long)(rbase + srow) * K + k0 + scc * 8, &Bs[buf][rbase * 64]);
    }
  };

  stage(0, 0);
  __syncthreads();

  int cur = 0;
  for (int k0 = 0; k0 < K; k0 += 64) {
    if (k0 + 64 < K) stage(cur ^ 1, k0 + 64);
    const bf16* Ac = &As[cur][0];
    const bf16* Bc = &Bs[cur][0];
    const int arow = 16 * mi + ln;
#pragma unroll
    for (int ks = 0; ks < 2; ks++) {
      short8 a = *(const short8*)(Ac + arow * 64 + (((ks * 4 + quad) ^ (arow & 7)) << 3));
#pragma unroll
      for (int i = 0; i < 2; i++) {
        const int brow = 16 * (2 * nh + i) + ln;
        short8 b = *(const short8*)(Bc + brow * 64 + (((ks * 4 + quad) ^ (brow & 7)) << 3));
        acc[i] = __builtin_amdgcn_mfma_f32_16x16x32_bf16(a, b, acc[i], 0, 0, 0);
      }
    }
    asm volatile("s_waitcnt vmcnt(0)" ::: "memory");
    __builtin_amdgcn_s_barrier();
    __builtin_amdgcn_sched_barrier(0);
    cur ^= 1;
  }

#pragma unroll
  for (int i = 0; i < 2; i++) {
#pragma unroll
    for (int r = 0; r < 4; r++) {
      int m = m0 + 16 * mi + quad * 4 + r;
      int n = n0 + 16 * (2 * nh + i) + ln;
      float c = acc[i][r];
      if (epi >= 1) c += ldx(bias, n, fl);
      if (labp) {
#pragma unroll
        for (int j = 0; j < 3; j++)
          c += ldx(labp, (long)m * 3 + j, fl) * ldx(labW, (long)(256 + j) * 256 + n, fl);
      }
      if (epi == 2) c = fmaxf(c, 0.f);
      stx(C, (long)m * N + n, c, cB);
    }
  }
}

// ------------------------------------------------------------------
// Key-side fused v9 (round-8/9 proven): v5 staging (kS[3], distance-2,
// one barrier/iter with vmcnt(4) lgkmcnt(0)) + de-atomized partial
// store epilogue (csRp/ktotp).
// ------------------------------------------------------------------
__global__ __launch_bounds__(256)
void key_fused_mfma(const bf16* __restrict__ k, const bf16* __restrict__ vQ,
                    const bf16* __restrict__ projB, const float* __restrict__ diagk,
                    float* __restrict__ ksumE, bf16* __restrict__ ctxQ,
                    float* __restrict__ mpart, float* __restrict__ csRp,
                    float* __restrict__ ktotp)
{
  __shared__ alignas(16) bf16 kS[3][32 * 256];
  __shared__ alignas(16) bf16 pS[2][64 * 40];
  __shared__ float wredM[4];
  __shared__ float wredK[4];

  const int bz = blockIdx.x, ft = blockIdx.y, f0 = ft * 64;
  const int t = threadIdx.x;
  const int w = t >> 6, l = t & 63, quad = l >> 4, ln = l & 15;
  const int fmine = f0 + 16 * w + ln;
  const bool fv = fmine < NBF;

  const bf16* kb = k + (long)bz * NC * 256;
  const bf16* vqb = vQ + (long)bz * 16 * 256 * 32;
  const float* db = diagk + bz * NC;

  auto stage = [&](int buf, int n0) {
#pragma unroll
    for (int j = 0; j < 4; j++) {
      int row = w * 8 + j * 2 + (l >> 5);
      int cc = (l & 31) ^ ((2 * j + (l >> 5)) & 7);   // = (l&31) ^ (row&7)
      async_copy16(kb + (long)(n0 + row) * 256 + cc * 8,
                   &kS[buf][w * 2048 + j * 512]);
    }
  };
  stage(0, 0);
  stage(1, 32);

  short8 pf[8];
  {
    const bf16* prow = projB + (long)fmine * 256;
#pragma unroll
    for (int kc = 0; kc < 8; kc++)
      pf[kc] = *(const short8*)(prow + kc * 32 + quad * 8);
  }

  f32x4 acc[4][4] = {};
  float ksumP = 0.f, mP = -1e30f;

  __syncthreads();   // full drain once: kS[0], kS[1] + pf ready

  int cur = 0;       // buffer holding tile `it`
  for (int it = 0; it < 16; it++) {
    const int n0 = it * 32;
    short8 bfr[4];
#pragma unroll
    for (int ei = 0; ei < 4; ei++) {
      int e = 64 * w + 16 * ei + ln;
      bfr[ei] = *(const short8*)(vqb + ((long)it * 256 + e) * 32 + quad * 8);
    }
    f32x4 dv0 = *(const f32x4*)(db + n0 + quad * 4);
    f32x4 dv1 = *(const f32x4*)(db + n0 + 16 + quad * 4);
    __builtin_amdgcn_sched_barrier(0);
    if (it + 2 < 16) {
      int nb = cur + 2; if (nb >= 3) nb -= 3;
      stage(nb, n0 + 64);
    }
    __builtin_amdgcn_sched_barrier(0);

    const bf16* kcur = &kS[cur][0];
    f32x4 dd[2][2] = {};
    __builtin_amdgcn_s_setprio(1);
#pragma unroll
    for (int kc = 0; kc < 8; kc++) {
      const int hf = kc & 1;
#pragma unroll
      for (int mi = 0; mi < 2; mi++) {
        short8 a = *(const short8*)(kcur + (16 * mi + ln) * 256 +
                                    (((kc * 4 + quad) ^ (ln & 7)) << 3));
        dd[mi][hf] = __builtin_amdgcn_mfma_f32_16x16x32_bf16(a, pf[kc], dd[mi][hf], 0, 0, 0);
      }
    }
    __builtin_amdgcn_s_setprio(0);
    bf16* pcur = &pS[it & 1][0];
#pragma unroll
    for (int mi = 0; mi < 2; mi++) {
      us4 ev;
      f32x4 dvv = mi ? dv1 : dv0;
#pragma unroll
      for (int r = 0; r < 4; r++) {
        float sc = DN * (dd[mi][0][r] + dd[mi][1][r]);
        float E = fv ? __expf(fminf(sc - dvv[r], 80.f)) : 0.f;
        unsigned short u = f2bu(E);
        ksumP += bf2f(u);
        if (fv) mP = fmaxf(mP, sc);
        ev[r] = u;
      }
      *(us4*)(pcur + (16 * w + ln) * 40 + 16 * mi + quad * 4) = ev;
    }
    // single barrier: pS visible (lgkmcnt 0), kS[it+1] complete (vmcnt 4)
    asm volatile("s_waitcnt vmcnt(4) lgkmcnt(0)" ::: "memory");
    __builtin_amdgcn_s_barrier();
    __builtin_amdgcn_sched_barrier(0);

    __builtin_amdgcn_s_setprio(1);
#pragma unroll
    for (int fh = 0; fh < 4; fh++) {
      short8 a = *(const short8*)(pcur + (16 * fh + ln) * 40 + quad * 8);
#pragma unroll
      for (int ei = 0; ei < 4; ei++)
        acc[fh][ei] = __builtin_amdgcn_mfma_f32_16x16x32_bf16(a, bfr[ei], acc[fh][ei], 0, 0, 0);
    }
    __builtin_amdgcn_s_setprio(0);
    cur = (cur == 2) ? 0 : cur + 1;
  }
  __syncthreads();

#pragma unroll
  for (int fh = 0; fh < 4; fh++) {
    const int ft32 = 2 * ft + (fh >> 1);
    const int f32b = 16 * (fh & 1) + quad * 4;
#pragma unroll
    for (int ei = 0; ei < 4; ei++) {
      int e = 64 * w + 16 * ei + ln;
      us4 cv;
#pragma unroll
      for (int r = 0; r < 4; r++) cv[r] = f2bu(acc[fh][ei][r]);
      *(us4*)(&ctxQ[((long)(bz * FT32 + ft32) * 256 + e) * 32 + f32b]) = cv;
    }
  }

  // csRp partial: column sum over this block's 64 f-rows per e (plain store)
#pragma unroll
  for (int ei = 0; ei < 4; ei++) {
    float col = 0.f;
#pragma unroll
    for (int fh = 0; fh < 4; fh++)
#pragma unroll
      for (int r = 0; r < 4; r++) col += acc[fh][ei][r];
    col += __shfl_xor(col, 16);
    col += __shfl_xor(col, 32);
    if (quad == 0)
      csRp[((long)bz * 23 + ft) * 256 + 64 * w + 16 * ei + ln] = col;
  }

  float s = ksumP;
  s += __shfl_xor(s, 16); s += __shfl_xor(s, 32);
  if (quad == 0 && fv) ksumE[(long)bz * NBF + fmine] = s;
  float s2 = s;
  s2 += __shfl_xor(s2, 1); s2 += __shfl_xor(s2, 2);
  s2 += __shfl_xor(s2, 4); s2 += __shfl_xor(s2, 8);
  if (l == 0) wredK[w] = s2;

  float m = mP;
#pragma unroll
  for (int off = 1; off < 64; off <<= 1) m = fmaxf(m, __shfl_xor(m, off));
  if (l == 0) wredM[w] = m;
  __syncthreads();
  if (t == 0) {
    mpart[bz * 23 + ft] = fmaxf(fmaxf(wredM[0], wredM[1]), fmaxf(wredM[2], wredM[3]));
    ktotp[bz * 23 + ft] = wredK[0] + wredK[1] + wredK[2] + wredK[3];
  }
}

// ------------------------------------------------------------------
// finalize_red: partials -> mk (max), csR (sum over ft), ktotR (sum).
// ------------------------------------------------------------------
__global__ __launch_bounds__(256)
void finalize_red(const float* __restrict__ mpart, const float* __restrict__ csRp,
                  const float* __restrict__ ktotp, float* __restrict__ mk,
                  float* __restrict__ csR, float* __restrict__ ktotR)
{
  int bz = blockIdx.x, t = threadIdx.x;
  float s = 0.f;
  for (int ft = 0; ft < 23; ft++)
    s += csRp[((long)bz * 23 + ft) * 256 + t];
  csR[bz * 256 + t] = s;
  int w = t >> 6, l = t & 63;
  if (w == 0) {
    float m = (l < 23) ? mpart[bz * 23 + l] : -1e30f;
#pragma unroll
    for (int off = 32; off > 0; off >>= 1) m = fmaxf(m, __shfl_down(m, off));
    if (l == 0) mk[bz] = m;
  } else if (w == 1) {
    float kk = (l < 23) ? ktotp[bz * 23 + l] : 0.f;
#pragma unroll
    for (int off = 32; off > 0; off >>= 1) kk += __shfl_down(kk, off);
    if (l == 0) ktotR[bz] = kk;
  }
}

// ------------------------------------------------------------------
// Query-side fused v9: q-PROJECTION FUSED IN (each (bz,nt) block needs
// a disjoint 64-row q slice -> zero duplicated FLOPs). Prologue: 4
// single-buffered k-steps of the v2 DMA-staged GEMM computing
// q = xtB . WqT[hh] + bq in fp32 (As/Bs carved from projS LDS, same
// XOR swizzle); dS computed in-register (DIAG_SC * sum q^2, pre-round,
// bias included - identical math to the old fused-diag epilogue);
// q-tile rounded bf16 -> LDS stride 264 -> qf fragments (same-wave
// rows: lgkmcnt ordering only). Then the round-9 v8 main loop
// (projS[3] distance-2, one barrier/iter vmcnt(4)) unchanged.
// Deletes qproj dispatch + qB 32MB round-trip + dgq atomics.
// ------------------------------------------------------------------
__global__ __launch_bounds__(256)
void q_fused_mfma(const bf16* __restrict__ xtB, const bf16* __restrict__ WqT,
                  const void* __restrict__ bq, const bf16* __restrict__ projB,
                  const bf16* __restrict__ ctxQ,
                  const float* __restrict__ ksum, const float* __restrict__ Sv,
                  const float* __restrict__ csR, const float* __restrict__ ktotR,
                  const float* __restrict__ mk, const int* __restrict__ dtFlag,
                  bf16* __restrict__ merged)
{
  __shared__ alignas(16) bf16 projS[3][32 * 256];
  __shared__ alignas(16) bf16 eS[2][64 * 40];
  __shared__ float dS[64];
  __shared__ float svS[256];
  __shared__ float crS[256];
  __shared__ float sS[64];
  __shared__ float mS[64];
  __shared__ float seS[64];

  const int fl = *dtFlag;
  const int bz = blockIdx.x, nt = blockIdx.y, t = threadIdx.x;
  const int w = t >> 6, l = t & 63, quad = l >> 4, ln = l & 15;
  const int tq = bz / H_, hh = bz % H_;
  const bf16* cqb = ctxQ + (long)bz * FT32 * 256 * 32;
  const float emk = __expf(-mk[bz]);
  const int srow = l >> 3, scc = (l & 7) ^ srow;

  // ---- fused q-projection prologue (uses projS as scratch) ----
  bf16* scr = &projS[0][0];
  bf16* Asq = scr;             // [64][64] swizzled
  bf16* Bsq = scr + 4096;      // [256][64] swizzled
  const bf16* xq = xtB + ((long)tq * NT + nt * 64) * 256;
  const bf16* wq = WqT + (long)hh * 65536;
  f32x4 qacc[16] = {};

  for (int k0 = 0; k0 < 256; k0 += 64) {
    // A: 2 slabs/wave (rows 16w+8j), B: 8 slabs/wave (rows 64w+8j)
#pragma unroll
    for (int j = 0; j < 2; j++) {
      const int rbase = 16 * w + 8 * j;
      async_copy16(xq + (long)(rbase + srow) * 256 + k0 + scc * 8, Asq + rbase * 64);
    }
#pragma unroll
    for (int j = 0; j < 8; j++) {
      const int rbase = 64 * w + 8 * j;
      async_copy16(wq + (long)(rbase + srow) * 256 + k0 + scc * 8, Bsq + rbase * 64);
    }
    asm volatile("s_waitcnt vmcnt(0)" ::: "memory");
    __builtin_amdgcn_s_barrier();
    __builtin_amdgcn_sched_barrier(0);
    const int arow = 16 * w + ln;
#pragma unroll
    for (int ks = 0; ks < 2; ks++) {
      short8 a = *(const short8*)(Asq + arow * 64 + (((ks * 4 + quad) ^ (arow & 7)) << 3));
#pragma unroll
      for (int g = 0; g < 16; g++) {
        const int brow = 16 * g + ln;
        short8 b = *(const short8*)(Bsq + brow * 64 + (((ks * 4 + quad) ^ (brow & 7)) << 3));
        qacc[g] = __builtin_amdgcn_mfma_f32_16x16x32_bf16(a, b, qacc[g], 0, 0, 0);
      }
    }
    __syncthreads();   // protect single-buffered restage / final scratch reuse
  }
  // bias + diag + bf16 q-tile into scr (stride 264)
  {
    float sum2[4] = {0.f, 0.f, 0.f, 0.f};
#pragma unroll
    for (int g = 0; g < 16; g++) {
      float bias = ldx(bq, (long)hh * 256 + 16 * g + ln, fl);
#pragma unroll
      for (int r = 0; r < 4; r++) {
        float v = qacc[g][r] + bias;
        sum2[r] += v * v;
        scr[(16 * w + quad * 4 + r) * 264 + 16 * g + ln] = __float2bfloat16(v);
      }
    }
#pragma unroll
    for (int r = 0; r < 4; r++) {
      float s = sum2[r];
      s += __shfl_xor(s, 1); s += __shfl_xor(s, 2);
      s += __shfl_xor(s, 4); s += __shfl_xor(s, 8);
      if (ln == 0) dS[16 * w + quad * 4 + r] = DIAG_SC * s;
    }
  }
  asm volatile("s_waitcnt lgkmcnt(0)" ::: "memory");
  __builtin_amdgcn_sched_barrier(0);
  // qf fragments (rows 16w+ln: written by THIS wave -> no barrier needed)
  short8 qf[8];
#pragma unroll
  for (int kc = 0; kc < 8; kc++)
    qf[kc] = *(const short8*)(scr + (16 * w + ln) * 264 + kc * 32 + quad * 8);
  __syncthreads();   // all reads done before stage_proj DMA overwrites scr

  auto stage_proj = [&](int buf, int f0n) {
#pragma unroll
    for (int j = 0; j < 4; j++) {
      int row = 8 * w + 2 * j + (l >> 5);
      int cc = (l & 31) ^ (row & 7);
      async_copy16(projB + (long)(f0n + row) * 256 + cc * 8,
                   &projS[buf][(8 * w + 2 * j) * 256]);
    }
  };
  stage_proj(0, 0);
  stage_proj(1, 32);
  svS[t] = Sv[bz * 256 + t];
  crS[t] = csR[bz * 256 + t];

  f32x4 acc[4][4] = {};           // [mh][ei]: rows 16mh+quad*4+r, e=16(4w+ei)+ln
  float sPart[4] = {0.f, 0.f, 0.f, 0.f};   // stR partial (rows 16w+quad*4+r)
  float sEp[4] = {0.f, 0.f, 0.f, 0.f};     // sE partial
  float mPart[4] = {0.f, 0.f, 0.f, 0.f};
  __syncthreads();   // full drain: projS[0..1] + LDS scalars ready

  int cur = 0;       // buffer holding tile `ft`
  for (int ft = 0; ft < FT32; ft++) {
    const int f0 = ft * 32;
    const bf16* pcur = &projS[cur][0];
    short8 cfr[4];
#pragma unroll
    for (int i = 0; i < 4; i++) {
      int e = 16 * (4 * w + i) + ln;
      cfr[i] = *(const short8*)(cqb + ((long)ft * 256 + e) * 32 + quad * 8);
    }
    const float kv0 = (f0 + ln < NBF) ? ksum[(long)bz * NBF + f0 + ln] : 0.f;
    const float kv1 = (f0 + 16 + ln < NBF) ? ksum[(long)bz * NBF + f0 + 16 + ln] : 0.f;
    __builtin_amdgcn_sched_barrier(0);
    if (ft + 2 < FT32) {
      int nb = cur + 2; if (nb >= 3) nb -= 3;
      stage_proj(nb, f0 + 64);
    }
    __builtin_amdgcn_sched_barrier(0);

    // Phase A: wave w owns rows 16w..16w+15, both f-halves
    f32x4 dd0 = {}, dd1 = {};
    __builtin_amdgcn_s_setprio(1);
#pragma unroll
    for (int kc = 0; kc < 8; kc++) {
      const int co = ((kc * 4 + quad) ^ (ln & 7)) << 3;
      short8 b0 = *(const short8*)(pcur + ln * 256 + co);
      dd0 = __builtin_amdgcn_mfma_f32_16x16x32_bf16(qf[kc], b0, dd0, 0, 0, 0);
      short8 b1 = *(const short8*)(pcur + (16 + ln) * 256 + co);
      dd1 = __builtin_amdgcn_mfma_f32_16x16x32_bf16(qf[kc], b1, dd1, 0, 0, 0);
    }
    __builtin_amdgcn_s_setprio(0);
    const bool fv0 = (f0 + ln) < NBF;
    const bool fv1 = (f0 + 16 + ln) < NBF;
    bf16* ecur = &eS[ft & 1][0];
#pragma unroll
    for (int r = 0; r < 4; r++) {
      float E0 = fv0 ? __expf(fminf(DN * dd0[r], 80.f)) : 0.f;
      float E1 = fv1 ? __expf(fminf(DN * dd1[r], 80.f)) : 0.f;
      bf16 h0 = __float2bfloat16(E0), h1v = __float2bfloat16(E1);
      float e0 = tofloat(h0), e1 = tofloat(h1v);
      ecur[(16 * w + quad * 4 + r) * 40 + ln] = h0;
      ecur[(16 * w + quad * 4 + r) * 40 + 16 + ln] = h1v;
      sPart[r] += e0 * kv0 + e1 * kv1;
      sEp[r] += e0 + e1;
      mPart[r] = fmaxf(mPart[r], fmaxf(e0, e1));
    }
    // single barrier: eS visible, projS for ft+1 complete (vmcnt 4)
    asm volatile("s_waitcnt vmcnt(4) lgkmcnt(0)" ::: "memory");
    __builtin_amdgcn_s_barrier();
    __builtin_amdgcn_sched_barrier(0);

    // Phase B: all 4 m-halves, 4 e-tiles each (cfr reused)
    __builtin_amdgcn_s_setprio(1);
#pragma unroll
    for (int mh = 0; mh < 4; mh++) {
      short8 a = *(const short8*)(ecur + (16 * mh + ln) * 40 + quad * 8);
#pragma unroll
      for (int i = 0; i < 4; i++)
        acc[mh][i] = __builtin_amdgcn_mfma_f32_16x16x32_bf16(a, cfr[i], acc[mh][i], 0, 0, 0);
    }
    __builtin_amdgcn_s_setprio(0);
    cur = (cur == 2) ? 0 : cur + 1;
  }
  __syncthreads();

  // wave-private row stats: reduce over 16 lanes
#pragma unroll
  for (int r = 0; r < 4; r++) {
    float s = sPart[r], m = mPart[r], se = sEp[r];
#pragma unroll
    for (int off = 1; off < 16; off <<= 1) {
      s += __shfl_xor(s, off);
      m = fmaxf(m, __shfl_xor(m, off));
      se += __shfl_xor(se, off);
    }
    if (ln == 0) {
      sS[16 * w + quad * 4 + r] = s;
      mS[16 * w + quad * 4 + r] = m;
      seS[16 * w + quad * 4 + r] = se;
    }
  }
  __syncthreads();

  const float ktotv = ktotR[bz];
#pragma unroll
  for (int mh = 0; mh < 4; mh++) {
#pragma unroll
    for (int r = 0; r < 4; r++) {
      int row = 16 * mh + quad * 4 + r;
      float st = sS[row];
      float se = seS[row];
      float mt = fmaxf(mS[row], 1e-30f);
      float c = __expf(-dS[row]) / mt;
      float A = c * se + (float)NBF * EPS_;
      float den = emk * (c * st + EPS_ * ktotv) + (float)NC * EPS_ * A;
      float inv = 1.f / den;
#pragma unroll
      for (int i = 0; i < 4; i++) {
        int e = 16 * (4 * w + i) + ln;
        float val = (emk * (c * acc[mh][i][r] + EPS_ * crS[e]) + EPS_ * svS[e] * A) * inv;
        merged[((long)tq * NT + nt * 64 + row) * 2048 + hh * 256 + e] =
            __float2bfloat16(val);
      }
    }
  }
}

// ------------------------------------------------------------------
extern "C" void kernel_launch(void* const* d_in, const int* in_sizes, int n_in,
                              void* d_out, int out_size, void* d_ws, size_t ws_size,
                              hipStream_t stream)
{
  const void* x_ctx = d_in[0];
  const void* label = d_in[1];
  const void* x_tgt = d_in[2];
  const void* W1 = d_in[3];
  const void* b1 = d_in[4];
  const void* W2 = d_in[5];
  const void* b2 = d_in[6];
  const void* W3 = d_in[7];
  const void* b3 = d_in[8];
  const void* Wk = d_in[9];
  const void* bk = d_in[10];
  const void* Wv = d_in[11];
  const void* bv = d_in[12];
  const void* Wq = d_in[13];
  const void* bq = d_in[14];
  const void* Wo = d_in[15];
  const void* bo = d_in[16];
  const void* Wmu = d_in[17];
  const void* bmu = d_in[18];
  const void* proj = d_in[19];

  // Arena (floats), peak ~91 MB. Overlays:
  //  xcB @ F2+1572864 (dead before ctxQ written by key_fused)
  //  xtB @ F0 (kB region; kB dead after key_fused; read by q_fused)
  //  rep @ F0+1048576 (written by wo GEMM after q_fused)
  float* W = (float*)d_ws;
  const long F0 = 0, F1 = 4194304, F2 = 8388608;
  const long CTXQ_F = (long)64 * FT32 * 256 * 32 / 2;
  const long F3 = F2 + CTXQ_F;
  bf16* kB = (bf16*)(W + F0);
  bf16* xtB = (bf16*)(W + F0);
  bf16* rep = (bf16*)(W + F0 + 1048576);
  bf16* vQ = (bf16*)(W + F1);
  bf16* merged = (bf16*)(W + F1);
  bf16* h1 = (bf16*)(W + F2);
  bf16* h2 = (bf16*)(W + F2 + 524288);
  bf16* cf = (bf16*)(W + F2 + 1048576);
  bf16* xcB = (bf16*)(W + F2 + 1572864);
  bf16* ctxQ = (bf16*)(W + F2);
  long o = F3;
  auto alloc = [&](long n) { float* p = W + o; o += n; return p; };
  float* zbase = W + o;
  float* dgk = alloc(32768);
  float* dgq = alloc(32768);            // unused now; keeps zero-region layout
  float* Sv = alloc(64 * 256);          // end of zeroed region (320 blocks)
  float* csR = alloc(64 * 256);
  float* ktotR = alloc(64);
  alloc(192);
  float* ksumE = alloc((long)64 * NBF);
  float* mpart = alloc(64 * 23);
  float* mk = alloc(64);
  int* dtFlag = (int*)alloc(64);
  float* csRp = alloc((long)64 * 23 * 256);
  float* ktotp = alloc(64 * 23);
  bf16* projB = (bf16*)alloc((long)FT32 * 32 * 256 / 2);
  bf16* WkT = (bf16*)alloc(262144);   // 8 x 256 x 256 bf16
  bf16* WvT = (bf16*)alloc(262144);
  bf16* WqT = (bf16*)alloc(262144);
  bf16* WoT = (bf16*)alloc(262144);   // 256 x 2048 bf16 (perm folded)
  bf16* W1T = (bf16*)alloc(32768);    // 256 x 256 bf16
  bf16* W2T = (bf16*)alloc(32768);
  bf16* W3T = (bf16*)alloc(32768);
  bf16* WmuT = (bf16*)alloc(32768);
  (void)ws_size; (void)in_sizes; (void)n_in; (void)out_size; (void)dgq;

  const dim3 B(256);
  detect_dtype<<<1, B, 0, stream>>>(x_ctx, dtFlag);
  // merged prep: weight transposes + conv_proj + xcB convert + zeroing
  prep_all<<<dim3(64, 8, 31), B, 0, stream>>>(
      Wk, Wv, Wq, Wo, W1, W2, W3, Wmu, proj, x_ctx,
      WkT, WvT, WqT, WoT, W1T, W2T, W3T, WmuT, projB, xcB, zbase, dtFlag);
  // 1. task-encoder MLP (BM=32 async gemm; layer 1 folds label+relu)
  gemm_mfma32v2<<<dim3(4, 128), B, 0, stream>>>(
      xcB, W1T, b1, h1, 1, 2, dtFlag, 4096, 256, 256, label, W1);
  gemm_mfma32v2<<<dim3(4, 128), B, 0, stream>>>(
      h1, W2T, b2, h2, 1, 2, dtFlag, 4096, 256, 256, nullptr, nullptr);
  gemm_mfma32v2<<<dim3(4, 128), B, 0, stream>>>(
      h2, W3T, b3, cf, 1, 2, dtFlag, 4096, 256, 256, nullptr, nullptr);
  // 2. k projection (fused diag), v projection (tiled -> vQ, fused Sv)
  gemm_mfma<<<dim3(4, 8, 64), B, 0, stream>>>(
      xcB, WkT, bk, kB, 1, 1, 0, dtFlag, dgk, nullptr,
      512, 256, 256, 131072L, 8, 65536L, 8, 256L);
  gemm_mfma<<<dim3(4, 8, 64), B, 0, stream>>>(
      cf, WvT, bv, vQ, 1, 1, 2, dtFlag, nullptr, Sv,
      512, 256, 256, 131072L, 8, 65536L, 8, 256L);
  // 3. key side (emits csRp / ktotp partials, no atomics)
  key_fused_mfma<<<dim3(64, 23), B, 0, stream>>>(kB, vQ, projB, dgk, ksumE, ctxQ,
                                                 mpart, csRp, ktotp);
  finalize_red<<<64, B, 0, stream>>>(mpart, csRp, ktotp, mk, csR, ktotR);
  // 4. xtB convert (kB region now dead); q-projection is fused into q_fused
  conv_bf16<<<4096, B, 0, stream>>>(x_tgt, xtB, dtFlag);
  // 5. query side v9 (q-proj + finalize folded in) -> merged [t][n][h][e]
  q_fused_mfma<<<dim3(64, 8), B, 0, stream>>>(xtB, WqT, bq, projB, ctxQ, ksumE,
                                              Sv, csR, ktotR, mk, dtFlag, merged);
  // 6. Wo GEMM (single pass, K=2048, bias bo, bf16 out) then Wmu
  gemm_mfma32v2<<<dim3(4, 128), B, 0, stream>>>(
      merged, WoT, bo, rep, 1, 1, dtFlag, 4096, 256, 2048, nullptr, nullptr);
  gemm_mfma32v2<<<dim3(4, 128), B, 0, stream>>>(
      rep, WmuT, bmu, d_out, 2, 1, dtFlag, 4096, 256, 256, nullptr, nullptr);
}

// Round 13
// 360.080 us; speedup vs baseline: 2.0629x; 1.0234x over previous
//
#include <hip/hip_runtime.h>
#include <hip/hip_bf16.h>

typedef __hip_bfloat16 bf16;
typedef __attribute__((ext_vector_type(8))) short short8;
typedef __attribute__((ext_vector_type(4))) float f32x4;
typedef __attribute__((ext_vector_type(4))) unsigned short us4;
#define DEV __device__ __forceinline__

static constexpr int T_ = 8, NC = 512, NT = 512, D_ = 256, H_ = 8, NBF = 1419;
static constexpr int FT32 = 46;             // 46 f-tiles of 32 (padded 1472)
static constexpr float EPS_ = 1e-4f;
static constexpr float DN = 0.25f;          // D^-0.25
static constexpr float DIAG_SC = 0.03125f;  // 0.5 * DN^2

DEV float bf2f(unsigned short u) { return __uint_as_float(((unsigned)u) << 16); }
DEV float tofloat(bf16 x) { return __bfloat162float(x); }
DEV unsigned short f2bu(float x) { bf16 h = __float2bfloat16(x); return *(unsigned short*)&h; }

DEV float ldx(const void* p, long i, int isb) {
  if (isb) return bf2f(((const unsigned short*)p)[i]);
  return ((const float*)p)[i];
}
DEV void stx(void* p, long i, float v, int isb) {
  if (isb) ((bf16*)p)[i] = __float2bfloat16(v);
  else     ((float*)p)[i] = v;
}

// async global->LDS 16B (wave-uniform LDS base + lane*16; global addr per-lane)
DEV void async_copy16(const void* g, void* lds) {
  __builtin_amdgcn_global_load_lds(
      (const __attribute__((address_space(1))) unsigned int*)g,
      (__attribute__((address_space(3))) unsigned int*)lds, 16, 0, 0);
}

// ------------------------------------------------------------------
// dtype probe (1 = bf16 inputs, 0 = fp32)
// ------------------------------------------------------------------
__global__ __launch_bounds__(256)
void detect_dtype(const void* __restrict__ x, int* __restrict__ flag)
{
  __shared__ int bad;
  if (threadIdx.x == 0) bad = 0;
  __syncthreads();
  int mybad = 0;
  for (int j = 0; j < 16; j++) {
    long i = 2L * (threadIdx.x + 256L * j);
    unsigned short u = ((const unsigned short*)x)[i];
    int e = (u >> 7) & 0xff, mant = u & 0x7f;
    bool b = (e == 0xff) || (e >= 141) || (e <= 93 && !(e == 0 && mant == 0));
    mybad += b ? 1 : 0;
  }
  atomicAdd(&bad, mybad);
  __syncthreads();
  if (threadIdx.x == 0) *flag = (bad > 1024) ? 0 : 1;
}

// ------------------------------------------------------------------
// prep_all: merged prep. Grid (64,8,32):
//  z 0..28 : weight pre-transpose W[k][n]->WT[n][k] bf16 (Wo folds the
//            merged-k permutation).
//  z == 29 : conv_proj — 3 f-rows per block.
//  z == 30 : xcB bf16 convert + zero of dgk/dgq/Sv atomic region.
//  z == 31 : xtB bf16 convert (replaces the conv_bf16 dispatch).
// ------------------------------------------------------------------
__global__ __launch_bounds__(256)
void prep_all(const void* __restrict__ Wk, const void* __restrict__ Wv,
              const void* __restrict__ Wq, const void* __restrict__ Wo,
              const void* __restrict__ W1, const void* __restrict__ W2,
              const void* __restrict__ W3, const void* __restrict__ Wmu,
              const void* __restrict__ proj, const void* __restrict__ x_ctx,
              const void* __restrict__ x_tgt,
              bf16* __restrict__ WkT, bf16* __restrict__ WvT,
              bf16* __restrict__ WqT, bf16* __restrict__ WoT,
              bf16* __restrict__ W1T, bf16* __restrict__ W2T,
              bf16* __restrict__ W3T, bf16* __restrict__ WmuT,
              bf16* __restrict__ projB, bf16* __restrict__ xcB,
              bf16* __restrict__ xtB,
              float* __restrict__ zbase, const int* __restrict__ dtFlag)
{
  __shared__ float tile[32][33];
  const int fl = *dtFlag;
  const int kt = blockIdx.x, nt = blockIdx.y, z = blockIdx.z, t = threadIdx.x;

  if (z == 29) {              // conv_proj
    int b = nt * 64 + kt;
#pragma unroll
    for (int r = 0; r < 3; r++) {
      int f = b * 3 + r;
      if (f < FT32 * 32) {
        float v = (f < NBF) ? ldx(proj, (long)f * 256 + t, fl) : 0.f;
        projB[(long)f * 256 + t] = __float2bfloat16(v);
      }
    }
    return;
  }
  if (z == 30) {              // xcB convert + atomic-region zero
    int b = nt * 64 + kt;
#pragma unroll
    for (int j = 0; j < 8; j++) {
      long i = (long)b * 2048 + j * 256 + t;
      xcB[i] = __float2bfloat16(ldx(x_ctx, i, fl));
    }
    if (b < 320) zbase[b * 256 + t] = 0.f;
    return;
  }
  if (z == 31) {              // xtB convert
    int b = nt * 64 + kt;
#pragma unroll
    for (int j = 0; j < 8; j++) {
      long i = (long)b * 2048 + j * 256 + t;
      xtB[i] = __float2bfloat16(ldx(x_tgt, i, fl));
    }
    return;
  }

  const void* in; bf16* out; int K; int perm = 0; long off = 0;
  if (z < 8)        { in = Wk;  out = WkT;  K = 256; off = (long)z * 65536; }
  else if (z < 16)  { in = Wv;  out = WvT;  K = 256; off = (long)(z - 8) * 65536; }
  else if (z < 24)  { in = Wq;  out = WqT;  K = 256; off = (long)(z - 16) * 65536; }
  else if (z == 24) { in = Wo;  out = WoT;  K = 2048; perm = 1; }
  else if (z == 25) { in = W1;  out = W1T;  K = 256; }
  else if (z == 26) { in = W2;  out = W2T;  K = 256; }
  else if (z == 27) { in = W3;  out = W3T;  K = 256; }
  else              { in = Wmu; out = WmuT; K = 256; }
  if (K == 256 && kt >= 8) return;
  const int k0 = kt * 32, n0 = nt * 32;
  const int row = t >> 3, cb = (t & 7) * 4;
  {
    int kk = k0 + row;
    int krow = perm ? (((kk & 255) << 3) | (kk >> 8)) : kk;
#pragma unroll
    for (int j = 0; j < 4; j++)
      tile[row][cb + j] = ldx(in, off + (long)krow * 256 + n0 + cb + j, fl);
  }
  __syncthreads();
  us4 o;
#pragma unroll
  for (int j = 0; j < 4; j++) o[j] = f2bu(tile[cb + j][row]);
  *(us4*)(out + off + (long)(n0 + row) * K + k0 + cb) = o;
}

// ------------------------------------------------------------------
// Unified MFMA GEMM v2, 64x64 tile, K-step 64 (proven round 5).
// Runs at 5 blocks/CU for kproj/vproj -> TLP covers latency; unchanged.
// ------------------------------------------------------------------
__global__ __launch_bounds__(256)
void gemm_mfma(const bf16* __restrict__ A, const bf16* __restrict__ BT,
               const void* __restrict__ bias,
               void* __restrict__ C, int cMode, int epi, int cT,
               const int* __restrict__ dtFlag, float* __restrict__ diagOut,
               float* __restrict__ svOut,
               int M, int N, int K, long sA, int divA, long sB, int modB, long sBias)
{
  __shared__ alignas(16) bf16 As[2][64 * 64];
  __shared__ alignas(16) bf16 Bs[2][64 * 64];
  const int fl = *dtFlag;
  const int cB = (cMode == 2) ? fl : cMode;
  const int t = threadIdx.x;
  const int bz = blockIdx.z;
  const long aOff = (long)(bz / divA) * sA;
  const long bOff = (long)(bz % modB) * sB;
  const long biasOff = (long)(bz % modB) * sBias;
  const long cOff = (long)bz * (long)M * N;
  const int m0 = blockIdx.y * 64, n0 = blockIdx.x * 64;
  const int w = t >> 6, l = t & 63, quad = l >> 4, ln = l & 15;
  const bf16* Ab = A + aOff + (long)m0 * K;
  const bf16* Bb = BT + bOff + (long)n0 * K;
  const int srow = l >> 3;            // 0..7 within the wave's 8-row slab
  const int scc = (l & 7) ^ srow;     // XOR swizzle chunk (row&7 == srow)
  f32x4 acc[4] = {};

  auto stage = [&](int buf, int k0) {
#pragma unroll
    for (int j = 0; j < 2; j++) {
      const int rbase = 32 * j + 8 * w;         // rbase&7 == 0
      const int row = rbase + srow;
      async_copy16(Ab + (long)row * K + k0 + scc * 8, &As[buf][rbase * 64]);
      async_copy16(Bb + (long)row * K + k0 + scc * 8, &Bs[buf][rbase * 64]);
    }
  };

  stage(0, 0);
  __syncthreads();   // full drain: buffer 0 ready

  int cur = 0;
  for (int k0 = 0; k0 < K; k0 += 64) {
    if (k0 + 64 < K) stage(cur ^ 1, k0 + 64);
    const bf16* Ac = &As[cur][0];
    const bf16* Bc = &Bs[cur][0];
    const int arow = 16 * w + ln;
#pragma unroll
    for (int ks = 0; ks < 2; ks++) {
      short8 a = *(const short8*)(Ac + arow * 64 + (((ks * 4 + quad) ^ (arow & 7)) << 3));
#pragma unroll
      for (int i = 0; i < 4; i++) {
        const int brow = 16 * i + ln;
        short8 b = *(const short8*)(Bc + brow * 64 + (((ks * 4 + quad) ^ (brow & 7)) << 3));
        acc[i] = __builtin_amdgcn_mfma_f32_16x16x32_bf16(a, b, acc[i], 0, 0, 0);
      }
    }
    asm volatile("s_waitcnt vmcnt(0)" ::: "memory");
    __builtin_amdgcn_s_barrier();
    __builtin_amdgcn_sched_barrier(0);
    cur ^= 1;
  }

  float s2[4] = {0.f, 0.f, 0.f, 0.f};
  if (cT == 2) {
    const int mm = m0 + 16 * w + quad * 4;
    const int tile = mm >> 5, off = mm & 31;
#pragma unroll
    for (int i = 0; i < 4; i++) {
      int n = n0 + 16 * i + ln;
      us4 cv;
      float colsum = 0.f;
#pragma unroll
      for (int r = 0; r < 4; r++) {
        float c = acc[i][r];
        if (epi >= 1) c += ldx(bias, biasOff + n, fl);
        if (epi == 2) c = fmaxf(c, 0.f);
        colsum += c;
        cv[r] = f2bu(c);
      }
      *(us4*)((bf16*)C + cOff + ((long)tile * N + n) * 32 + off) = cv;
      if (svOut) {
        colsum += __shfl_xor(colsum, 16);
        colsum += __shfl_xor(colsum, 32);
        if (quad == 0) atomicAdd(&svOut[(long)bz * N + n], colsum);
      }
    }
  } else {
#pragma unroll
    for (int i = 0; i < 4; i++) {
#pragma unroll
      for (int r = 0; r < 4; r++) {
        int m = m0 + 16 * w + quad * 4 + r;
        int n = n0 + 16 * i + ln;
        float c = acc[i][r];
        if (epi >= 1) c += ldx(bias, biasOff + n, fl);
        if (epi == 2) c = fmaxf(c, 0.f);
        s2[r] += c * c;
        stx(C, cOff + (long)m * N + n, c, cB);
      }
    }
  }
  if (diagOut) {
#pragma unroll
    for (int r = 0; r < 4; r++) {
      float s = s2[r];
      s += __shfl_xor(s, 1); s += __shfl_xor(s, 2);
      s += __shfl_xor(s, 4); s += __shfl_xor(s, 8);
      if (ln == 0)
        atomicAdd(&diagOut[(long)bz * M + m0 + 16 * w + quad * 4 + r], DIAG_SC * s);
    }
  }
}

// ------------------------------------------------------------------
// BM=32 GEMM v3: triple-buffered, stage distance 2, counted vmcnt(3)
// (3 DMAs per stage: 1 A slab + 2 B slabs per wave), tail vmcnt(0) —
// the proven key_fused schedule applied to the skinny GEMMs. At 2
// blocks/CU these loops had ~500cy of exposed stage latency per iter;
// distance-2 covers it with a full iteration. Optional label fold.
// Generic K (MLP/Wmu K=256; Wo K=2048, 32 iters - the main winner).
// LDS 36KB.
// ------------------------------------------------------------------
__global__ __launch_bounds__(256)
void gemm_mfma32v2(const bf16* __restrict__ A, const bf16* __restrict__ BT,
                   const void* __restrict__ bias,
                   void* __restrict__ C, int cMode, int epi,
                   const int* __restrict__ dtFlag, int M, int N, int K,
                   const void* __restrict__ labp, const void* __restrict__ labW)
{
  __shared__ alignas(16) bf16 As[3][32 * 64];
  __shared__ alignas(16) bf16 Bs[3][64 * 64];
  const int fl = *dtFlag;
  const int cB = (cMode == 2) ? fl : cMode;
  const int t = threadIdx.x;
  const int m0 = blockIdx.y * 32, n0 = blockIdx.x * 64;
  const int w = t >> 6, l = t & 63, quad = l >> 4, ln = l & 15;
  const int mi = w & 1, nh = w >> 1;
  const bf16* Ab = A + (long)m0 * K;
  const bf16* Bb = BT + (long)n0 * K;
  const int srow = l >> 3;
  const int scc = (l & 7) ^ srow;
  const int niter = K >> 6;
  f32x4 acc[2] = {};

  auto stage = [&](int buf, int k0) {
    async_copy16(Ab + (long)(8 * w + srow) * K + k0 + scc * 8, &As[buf][(8 * w) * 64]);
#pragma unroll
    for (int j = 0; j < 2; j++) {
      const int rbase = 32 * j + 8 * w;
      async_copy16(Bb + (long)(rbase + srow) * K + k0 + scc * 8, &Bs[buf][rbase * 64]);
    }
  };

  stage(0, 0);
  if (niter > 1) stage(1, 64);
  __syncthreads();   // full drain: buffers 0,1 ready

  int cur = 0;
  for (int it = 0; it < niter; ++it) {
    if (it + 2 < niter) {
      int nb = cur + 2; if (nb >= 3) nb -= 3;
      stage(nb, (it + 2) * 64);
    }
    __builtin_amdgcn_sched_barrier(0);
    const bf16* Ac = &As[cur][0];
    const bf16* Bc = &Bs[cur][0];
    const int arow = 16 * mi + ln;
#pragma unroll
    for (int ks = 0; ks < 2; ks++) {
      short8 a = *(const short8*)(Ac + arow * 64 + (((ks * 4 + quad) ^ (arow & 7)) << 3));
#pragma unroll
      for (int i = 0; i < 2; i++) {
        const int brow = 16 * (2 * nh + i) + ln;
        short8 b = *(const short8*)(Bc + brow * 64 + (((ks * 4 + quad) ^ (brow & 7)) << 3));
        acc[i] = __builtin_amdgcn_mfma_f32_16x16x32_bf16(a, b, acc[i], 0, 0, 0);
      }
    }
    // counted wait: keep stage(it+2) in flight; tail iterations drain
    if (it + 2 < niter) {
      asm volatile("s_waitcnt vmcnt(3)" ::: "memory");
    } else {
      asm volatile("s_waitcnt vmcnt(0)" ::: "memory");
    }
    __builtin_amdgcn_s_barrier();
    __builtin_amdgcn_sched_barrier(0);
    cur = (cur == 2) ? 0 : cur + 1;
  }

#pragma unroll
  for (int i = 0; i < 2; i++) {
#pragma unroll
    for (int r = 0; r < 4; r++) {
      int m = m0 + 16 * mi + quad * 4 + r;
      int n = n0 + 16 * (2 * nh + i) + ln;
      float c = acc[i][r];
      if (epi >= 1) c += ldx(bias, n, fl);
      if (labp) {
#pragma unroll
        for (int j = 0; j < 3; j++)
          c += ldx(labp, (long)m * 3 + j, fl) * ldx(labW, (long)(256 + j) * 256 + n, fl);
      }
      if (epi == 2) c = fmaxf(c, 0.f);
      stx(C, (long)m * N + n, c, cB);
    }
  }
}

// ------------------------------------------------------------------
// Key-side fused v10 = round-9 proven v9 + tail-race fix: at iters
// 14/15 no new stage is in flight, so the counted vmcnt(4) could
// return with stage(it+1) still pending (won only by timing margin);
// the tail now drains with vmcnt(0).
// ------------------------------------------------------------------
__global__ __launch_bounds__(256)
void key_fused_mfma(const bf16* __restrict__ k, const bf16* __restrict__ vQ,
                    const bf16* __restrict__ projB, const float* __restrict__ diagk,
                    float* __restrict__ ksumE, bf16* __restrict__ ctxQ,
                    float* __restrict__ mpart, float* __restrict__ csRp,
                    float* __restrict__ ktotp)
{
  __shared__ alignas(16) bf16 kS[3][32 * 256];
  __shared__ alignas(16) bf16 pS[2][64 * 40];
  __shared__ float wredM[4];
  __shared__ float wredK[4];

  const int bz = blockIdx.x, ft = blockIdx.y, f0 = ft * 64;
  const int t = threadIdx.x;
  const int w = t >> 6, l = t & 63, quad = l >> 4, ln = l & 15;
  const int fmine = f0 + 16 * w + ln;
  const bool fv = fmine < NBF;

  const bf16* kb = k + (long)bz * NC * 256;
  const bf16* vqb = vQ + (long)bz * 16 * 256 * 32;
  const float* db = diagk + bz * NC;

  auto stage = [&](int buf, int n0) {
#pragma unroll
    for (int j = 0; j < 4; j++) {
      int row = w * 8 + j * 2 + (l >> 5);
      int cc = (l & 31) ^ ((2 * j + (l >> 5)) & 7);   // = (l&31) ^ (row&7)
      async_copy16(kb + (long)(n0 + row) * 256 + cc * 8,
                   &kS[buf][w * 2048 + j * 512]);
    }
  };
  stage(0, 0);
  stage(1, 32);

  short8 pf[8];
  {
    const bf16* prow = projB + (long)fmine * 256;
#pragma unroll
    for (int kc = 0; kc < 8; kc++)
      pf[kc] = *(const short8*)(prow + kc * 32 + quad * 8);
  }

  f32x4 acc[4][4] = {};
  float ksumP = 0.f, mP = -1e30f;

  __syncthreads();   // full drain once: kS[0], kS[1] + pf ready

  int cur = 0;       // buffer holding tile `it`
  for (int it = 0; it < 16; it++) {
    const int n0 = it * 32;
    short8 bfr[4];
#pragma unroll
    for (int ei = 0; ei < 4; ei++) {
      int e = 64 * w + 16 * ei + ln;
      bfr[ei] = *(const short8*)(vqb + ((long)it * 256 + e) * 32 + quad * 8);
    }
    f32x4 dv0 = *(const f32x4*)(db + n0 + quad * 4);
    f32x4 dv1 = *(const f32x4*)(db + n0 + 16 + quad * 4);
    __builtin_amdgcn_sched_barrier(0);
    if (it + 2 < 16) {
      int nb = cur + 2; if (nb >= 3) nb -= 3;
      stage(nb, n0 + 64);
    }
    __builtin_amdgcn_sched_barrier(0);

    const bf16* kcur = &kS[cur][0];
    f32x4 dd[2][2] = {};
    __builtin_amdgcn_s_setprio(1);
#pragma unroll
    for (int kc = 0; kc < 8; kc++) {
      const int hf = kc & 1;
#pragma unroll
      for (int mi = 0; mi < 2; mi++) {
        short8 a = *(const short8*)(kcur + (16 * mi + ln) * 256 +
                                    (((kc * 4 + quad) ^ (ln & 7)) << 3));
        dd[mi][hf] = __builtin_amdgcn_mfma_f32_16x16x32_bf16(a, pf[kc], dd[mi][hf], 0, 0, 0);
      }
    }
    __builtin_amdgcn_s_setprio(0);
    bf16* pcur = &pS[it & 1][0];
#pragma unroll
    for (int mi = 0; mi < 2; mi++) {
      us4 ev;
      f32x4 dvv = mi ? dv1 : dv0;
#pragma unroll
      for (int r = 0; r < 4; r++) {
        float sc = DN * (dd[mi][0][r] + dd[mi][1][r]);
        float E = fv ? __expf(fminf(sc - dvv[r], 80.f)) : 0.f;
        unsigned short u = f2bu(E);
        ksumP += bf2f(u);
        if (fv) mP = fmaxf(mP, sc);
        ev[r] = u;
      }
      *(us4*)(pcur + (16 * w + ln) * 40 + 16 * mi + quad * 4) = ev;
    }
    // single barrier: pS visible; kS[it+1] complete (counted mid-loop,
    // drained at the tail where no newer stage exists)
    if (it + 2 < 16) {
      asm volatile("s_waitcnt vmcnt(4) lgkmcnt(0)" ::: "memory");
    } else {
      asm volatile("s_waitcnt vmcnt(0) lgkmcnt(0)" ::: "memory");
    }
    __builtin_amdgcn_s_barrier();
    __builtin_amdgcn_sched_barrier(0);

    __builtin_amdgcn_s_setprio(1);
#pragma unroll
    for (int fh = 0; fh < 4; fh++) {
      short8 a = *(const short8*)(pcur + (16 * fh + ln) * 40 + quad * 8);
#pragma unroll
      for (int ei = 0; ei < 4; ei++)
        acc[fh][ei] = __builtin_amdgcn_mfma_f32_16x16x32_bf16(a, bfr[ei], acc[fh][ei], 0, 0, 0);
    }
    __builtin_amdgcn_s_setprio(0);
    cur = (cur == 2) ? 0 : cur + 1;
  }
  __syncthreads();

#pragma unroll
  for (int fh = 0; fh < 4; fh++) {
    const int ft32 = 2 * ft + (fh >> 1);
    const int f32b = 16 * (fh & 1) + quad * 4;
#pragma unroll
    for (int ei = 0; ei < 4; ei++) {
      int e = 64 * w + 16 * ei + ln;
      us4 cv;
#pragma unroll
      for (int r = 0; r < 4; r++) cv[r] = f2bu(acc[fh][ei][r]);
      *(us4*)(&ctxQ[((long)(bz * FT32 + ft32) * 256 + e) * 32 + f32b]) = cv;
    }
  }

  // csRp partial: column sum over this block's 64 f-rows per e (plain store)
#pragma unroll
  for (int ei = 0; ei < 4; ei++) {
    float col = 0.f;
#pragma unroll
    for (int fh = 0; fh < 4; fh++)
#pragma unroll
      for (int r = 0; r < 4; r++) col += acc[fh][ei][r];
    col += __shfl_xor(col, 16);
    col += __shfl_xor(col, 32);
    if (quad == 0)
      csRp[((long)bz * 23 + ft) * 256 + 64 * w + 16 * ei + ln] = col;
  }

  float s = ksumP;
  s += __shfl_xor(s, 16); s += __shfl_xor(s, 32);
  if (quad == 0 && fv) ksumE[(long)bz * NBF + fmine] = s;
  float s2 = s;
  s2 += __shfl_xor(s2, 1); s2 += __shfl_xor(s2, 2);
  s2 += __shfl_xor(s2, 4); s2 += __shfl_xor(s2, 8);
  if (l == 0) wredK[w] = s2;

  float m = mP;
#pragma unroll
  for (int off = 1; off < 64; off <<= 1) m = fmaxf(m, __shfl_xor(m, off));
  if (l == 0) wredM[w] = m;
  __syncthreads();
  if (t == 0) {
    mpart[bz * 23 + ft] = fmaxf(fmaxf(wredM[0], wredM[1]), fmaxf(wredM[2], wredM[3]));
    ktotp[bz * 23 + ft] = wredK[0] + wredK[1] + wredK[2] + wredK[3];
  }
}

// ------------------------------------------------------------------
// Query-side fused v10: round-10 v9 (q-proj prologue + folded finalize
// algebra) + finalize_red FOLDED IN (reads csRp/ktotp/mpart partials
// directly: per-thread 23-element reductions, L1-broadcast-hot, hidden
// under the prologue DMAs; deletes the finalize_red dispatch) + tail-
// race fix on the main-loop counted wait.
// ------------------------------------------------------------------
__global__ __launch_bounds__(256)
void q_fused_mfma(const bf16* __restrict__ xtB, const bf16* __restrict__ WqT,
                  const void* __restrict__ bq, const bf16* __restrict__ projB,
                  const bf16* __restrict__ ctxQ,
                  const float* __restrict__ ksum, const float* __restrict__ Sv,
                  const float* __restrict__ csRp, const float* __restrict__ ktotp,
                  const float* __restrict__ mpart, const int* __restrict__ dtFlag,
                  bf16* __restrict__ merged)
{
  __shared__ alignas(16) bf16 projS[3][32 * 256];
  __shared__ alignas(16) bf16 eS[2][64 * 40];
  __shared__ float dS[64];
  __shared__ float svS[256];
  __shared__ float crS[256];
  __shared__ float sS[64];
  __shared__ float mS[64];
  __shared__ float seS[64];

  const int fl = *dtFlag;
  const int bz = blockIdx.x, nt = blockIdx.y, t = threadIdx.x;
  const int w = t >> 6, l = t & 63, quad = l >> 4, ln = l & 15;
  const int tq = bz / H_, hh = bz % H_;
  const bf16* cqb = ctxQ + (long)bz * FT32 * 256 * 32;
  const int srow = l >> 3, scc = (l & 7) ^ srow;

  // folded finalize_red: csR/ktot/mk from partials (wave-uniform mpart/
  // ktotp addresses -> scalar-cached; csRp reads are coalesced)
  float mkv = -1e30f, ktv = 0.f;
  {
    float s = 0.f;
    for (int f2 = 0; f2 < 23; f2++) {
      s += csRp[((long)bz * 23 + f2) * 256 + t];
      mkv = fmaxf(mkv, mpart[bz * 23 + f2]);
      ktv += ktotp[bz * 23 + f2];
    }
    crS[t] = s;
  }
  const float emk = __expf(-mkv);
  const float ktotv = ktv;

  // ---- fused q-projection prologue (uses projS as scratch) ----
  bf16* scr = &projS[0][0];
  bf16* Asq = scr;             // [64][64] swizzled
  bf16* Bsq = scr + 4096;      // [256][64] swizzled
  const bf16* xq = xtB + ((long)tq * NT + nt * 64) * 256;
  const bf16* wq = WqT + (long)hh * 65536;
  f32x4 qacc[16] = {};

  for (int k0 = 0; k0 < 256; k0 += 64) {
    // A: 2 slabs/wave (rows 16w+8j), B: 8 slabs/wave (rows 64w+8j)
#pragma unroll
    for (int j = 0; j < 2; j++) {
      const int rbase = 16 * w + 8 * j;
      async_copy16(xq + (long)(rbase + srow) * 256 + k0 + scc * 8, Asq + rbase * 64);
    }
#pragma unroll
    for (int j = 0; j < 8; j++) {
      const int rbase = 64 * w + 8 * j;
      async_copy16(wq + (long)(rbase + srow) * 256 + k0 + scc * 8, Bsq + rbase * 64);
    }
    asm volatile("s_waitcnt vmcnt(0)" ::: "memory");
    __builtin_amdgcn_s_barrier();
    __builtin_amdgcn_sched_barrier(0);
    const int arow = 16 * w + ln;
#pragma unroll
    for (int ks = 0; ks < 2; ks++) {
      short8 a = *(const short8*)(Asq + arow * 64 + (((ks * 4 + quad) ^ (arow & 7)) << 3));
#pragma unroll
      for (int g = 0; g < 16; g++) {
        const int brow = 16 * g + ln;
        short8 b = *(const short8*)(Bsq + brow * 64 + (((ks * 4 + quad) ^ (brow & 7)) << 3));
        qacc[g] = __builtin_amdgcn_mfma_f32_16x16x32_bf16(a, b, qacc[g], 0, 0, 0);
      }
    }
    __syncthreads();   // protect single-buffered restage / final scratch reuse
  }
  // bias + diag + bf16 q-tile into scr (stride 264)
  {
    float sum2[4] = {0.f, 0.f, 0.f, 0.f};
#pragma unroll
    for (int g = 0; g < 16; g++) {
      float bias = ldx(bq, (long)hh * 256 + 16 * g + ln, fl);
#pragma unroll
      for (int r = 0; r < 4; r++) {
        float v = qacc[g][r] + bias;
        sum2[r] += v * v;
        scr[(16 * w + quad * 4 + r) * 264 + 16 * g + ln] = __float2bfloat16(v);
      }
    }
#pragma unroll
    for (int r = 0; r < 4; r++) {
      float s = sum2[r];
      s += __shfl_xor(s, 1); s += __shfl_xor(s, 2);
      s += __shfl_xor(s, 4); s += __shfl_xor(s, 8);
      if (ln == 0) dS[16 * w + quad * 4 + r] = DIAG_SC * s;
    }
  }
  asm volatile("s_waitcnt lgkmcnt(0)" ::: "memory");
  __builtin_amdgcn_sched_barrier(0);
  // qf fragments (rows 16w+ln: written by THIS wave -> no barrier needed)
  short8 qf[8];
#pragma unroll
  for (int kc = 0; kc < 8; kc++)
    qf[kc] = *(const short8*)(scr + (16 * w + ln) * 264 + kc * 32 + quad * 8);
  __syncthreads();   // all reads done before stage_proj DMA overwrites scr

  auto stage_proj = [&](int buf, int f0n) {
#pragma unroll
    for (int j = 0; j < 4; j++) {
      int row = 8 * w + 2 * j + (l >> 5);
      int cc = (l & 31) ^ (row & 7);
      async_copy16(projB + (long)(f0n + row) * 256 + cc * 8,
                   &projS[buf][(8 * w + 2 * j) * 256]);
    }
  };
  stage_proj(0, 0);
  stage_proj(1, 32);
  svS[t] = Sv[bz * 256 + t];

  f32x4 acc[4][4] = {};           // [mh][ei]: rows 16mh+quad*4+r, e=16(4w+ei)+ln
  float sPart[4] = {0.f, 0.f, 0.f, 0.f};   // stR partial (rows 16w+quad*4+r)
  float sEp[4] = {0.f, 0.f, 0.f, 0.f};     // sE partial
  float mPart[4] = {0.f, 0.f, 0.f, 0.f};
  __syncthreads();   // full drain: projS[0..1] + LDS scalars ready

  int cur = 0;       // buffer holding tile `ft`
  for (int ft = 0; ft < FT32; ft++) {
    const int f0 = ft * 32;
    const bf16* pcur = &projS[cur][0];
    short8 cfr[4];
#pragma unroll
    for (int i = 0; i < 4; i++) {
      int e = 16 * (4 * w + i) + ln;
      cfr[i] = *(const short8*)(cqb + ((long)ft * 256 + e) * 32 + quad * 8);
    }
    const float kv0 = (f0 + ln < NBF) ? ksum[(long)bz * NBF + f0 + ln] : 0.f;
    const float kv1 = (f0 + 16 + ln < NBF) ? ksum[(long)bz * NBF + f0 + 16 + ln] : 0.f;
    __builtin_amdgcn_sched_barrier(0);
    if (ft + 2 < FT32) {
      int nb = cur + 2; if (nb >= 3) nb -= 3;
      stage_proj(nb, f0 + 64);
    }
    __builtin_amdgcn_sched_barrier(0);

    // Phase A: wave w owns rows 16w..16w+15, both f-halves
    f32x4 dd0 = {}, dd1 = {};
    __builtin_amdgcn_s_setprio(1);
#pragma unroll
    for (int kc = 0; kc < 8; kc++) {
      const int co = ((kc * 4 + quad) ^ (ln & 7)) << 3;
      short8 b0 = *(const short8*)(pcur + ln * 256 + co);
      dd0 = __builtin_amdgcn_mfma_f32_16x16x32_bf16(qf[kc], b0, dd0, 0, 0, 0);
      short8 b1 = *(const short8*)(pcur + (16 + ln) * 256 + co);
      dd1 = __builtin_amdgcn_mfma_f32_16x16x32_bf16(qf[kc], b1, dd1, 0, 0, 0);
    }
    __builtin_amdgcn_s_setprio(0);
    const bool fv0 = (f0 + ln) < NBF;
    const bool fv1 = (f0 + 16 + ln) < NBF;
    bf16* ecur = &eS[ft & 1][0];
#pragma unroll
    for (int r = 0; r < 4; r++) {
      float E0 = fv0 ? __expf(fminf(DN * dd0[r], 80.f)) : 0.f;
      float E1 = fv1 ? __expf(fminf(DN * dd1[r], 80.f)) : 0.f;
      bf16 h0 = __float2bfloat16(E0), h1v = __float2bfloat16(E1);
      float e0 = tofloat(h0), e1 = tofloat(h1v);
      ecur[(16 * w + quad * 4 + r) * 40 + ln] = h0;
      ecur[(16 * w + quad * 4 + r) * 40 + 16 + ln] = h1v;
      sPart[r] += e0 * kv0 + e1 * kv1;
      sEp[r] += e0 + e1;
      mPart[r] = fmaxf(mPart[r], fmaxf(e0, e1));
    }
    // single barrier: eS visible, projS for ft+1 complete (counted wait
    // mid-loop; drained at the tail where no newer stage exists)
    if (ft + 2 < FT32) {
      asm volatile("s_waitcnt vmcnt(4) lgkmcnt(0)" ::: "memory");
    } else {
      asm volatile("s_waitcnt vmcnt(0) lgkmcnt(0)" ::: "memory");
    }
    __builtin_amdgcn_s_barrier();
    __builtin_amdgcn_sched_barrier(0);

    // Phase B: all 4 m-halves, 4 e-tiles each (cfr reused)
    __builtin_amdgcn_s_setprio(1);
#pragma unroll
    for (int mh = 0; mh < 4; mh++) {
      short8 a = *(const short8*)(ecur + (16 * mh + ln) * 40 + quad * 8);
#pragma unroll
      for (int i = 0; i < 4; i++)
        acc[mh][i] = __builtin_amdgcn_mfma_f32_16x16x32_bf16(a, cfr[i], acc[mh][i], 0, 0, 0);
    }
    __builtin_amdgcn_s_setprio(0);
    cur = (cur == 2) ? 0 : cur + 1;
  }
  __syncthreads();

  // wave-private row stats: reduce over 16 lanes
#pragma unroll
  for (int r = 0; r < 4; r++) {
    float s = sPart[r], m = mPart[r], se = sEp[r];
#pragma unroll
    for (int off = 1; off < 16; off <<= 1) {
      s += __shfl_xor(s, off);
      m = fmaxf(m, __shfl_xor(m, off));
      se += __shfl_xor(se, off);
    }
    if (ln == 0) {
      sS[16 * w + quad * 4 + r] = s;
      mS[16 * w + quad * 4 + r] = m;
      seS[16 * w + quad * 4 + r] = se;
    }
  }
  __syncthreads();

#pragma unroll
  for (int mh = 0; mh < 4; mh++) {
#pragma unroll
    for (int r = 0; r < 4; r++) {
      int row = 16 * mh + quad * 4 + r;
      float st = sS[row];
      float se = seS[row];
      float mt = fmaxf(mS[row], 1e-30f);
      float c = __expf(-dS[row]) / mt;
      float A = c * se + (float)NBF * EPS_;
      float den = emk * (c * st + EPS_ * ktotv) + (float)NC * EPS_ * A;
      float inv = 1.f / den;
#pragma unroll
      for (int i = 0; i < 4; i++) {
        int e = 16 * (4 * w + i) + ln;
        float val = (emk * (c * acc[mh][i][r] + EPS_ * crS[e]) + EPS_ * svS[e] * A) * inv;
        merged[((long)tq * NT + nt * 64 + row) * 2048 + hh * 256 + e] =
            __float2bfloat16(val);
      }
    }
  }
}

// ------------------------------------------------------------------
extern "C" void kernel_launch(void* const* d_in, const int* in_sizes, int n_in,
                              void* d_out, int out_size, void* d_ws, size_t ws_size,
                              hipStream_t stream)
{
  const void* x_ctx = d_in[0];
  const void* label = d_in[1];
  const void* x_tgt = d_in[2];
  const void* W1 = d_in[3];
  const void* b1 = d_in[4];
  const void* W2 = d_in[5];
  const void* b2 = d_in[6];
  const void* W3 = d_in[7];
  const void* b3 = d_in[8];
  const void* Wk = d_in[9];
  const void* bk = d_in[10];
  const void* Wv = d_in[11];
  const void* bv = d_in[12];
  const void* Wq = d_in[13];
  const void* bq = d_in[14];
  const void* Wo = d_in[15];
  const void* bo = d_in[16];
  const void* Wmu = d_in[17];
  const void* bmu = d_in[18];
  const void* proj = d_in[19];

  // Arena (floats), peak ~93 MB. Overlays:
  //  xcB @ F2+1572864 (dead before ctxQ written by key_fused)
  //  rep @ F0+1048576 (written by Wo GEMM after q_fused; kB dead then)
  //  xtB: dedicated slot (no overlay; written in prep, read in q_fused)
  float* W = (float*)d_ws;
  const long F0 = 0, F1 = 4194304, F2 = 8388608;
  const long CTXQ_F = (long)64 * FT32 * 256 * 32 / 2;
  const long F3 = F2 + CTXQ_F;
  bf16* kB = (bf16*)(W + F0);
  bf16* rep = (bf16*)(W + F0 + 1048576);
  bf16* vQ = (bf16*)(W + F1);
  bf16* merged = (bf16*)(W + F1);
  bf16* h1 = (bf16*)(W + F2);
  bf16* h2 = (bf16*)(W + F2 + 524288);
  bf16* cf = (bf16*)(W + F2 + 1048576);
  bf16* xcB = (bf16*)(W + F2 + 1572864);
  bf16* ctxQ = (bf16*)(W + F2);
  long o = F3;
  auto alloc = [&](long n) { float* p = W + o; o += n; return p; };
  float* zbase = W + o;
  float* dgk = alloc(32768);
  float* dgq = alloc(32768);            // kept for zero-region layout
  float* Sv = alloc(64 * 256);          // end of zeroed region (320 blocks)
  float* csR = alloc(64 * 256);         // unused (finalize folded)
  float* ktotR = alloc(64);             // unused
  alloc(192);
  float* ksumE = alloc((long)64 * NBF);
  float* mpart = alloc(64 * 23);
  float* mk = alloc(64);                // unused
  int* dtFlag = (int*)alloc(64);
  float* csRp = alloc((long)64 * 23 * 256);
  float* ktotp = alloc(64 * 23);
  bf16* projB = (bf16*)alloc((long)FT32 * 32 * 256 / 2);
  bf16* xtB = (bf16*)alloc(524288);   // 1M bf16 (8x512x256)
  bf16* WkT = (bf16*)alloc(262144);   // 8 x 256 x 256 bf16
  bf16* WvT = (bf16*)alloc(262144);
  bf16* WqT = (bf16*)alloc(262144);
  bf16* WoT = (bf16*)alloc(262144);   // 256 x 2048 bf16 (perm folded)
  bf16* W1T = (bf16*)alloc(32768);    // 256 x 256 bf16
  bf16* W2T = (bf16*)alloc(32768);
  bf16* W3T = (bf16*)alloc(32768);
  bf16* WmuT = (bf16*)alloc(32768);
  (void)ws_size; (void)in_sizes; (void)n_in; (void)out_size;
  (void)dgq; (void)csR; (void)ktotR; (void)mk;

  const dim3 B(256);
  detect_dtype<<<1, B, 0, stream>>>(x_ctx, dtFlag);
  // merged prep: weight transposes + conv_proj + xcB/xtB converts + zeroing
  prep_all<<<dim3(64, 8, 32), B, 0, stream>>>(
      Wk, Wv, Wq, Wo, W1, W2, W3, Wmu, proj, x_ctx, x_tgt,
      WkT, WvT, WqT, WoT, W1T, W2T, W3T, WmuT, projB, xcB, xtB, zbase, dtFlag);
  // 1. task-encoder MLP (BM=32 counted-wait gemm; layer 1 folds label+relu)
  gemm_mfma32v2<<<dim3(4, 128), B, 0, stream>>>(
      xcB, W1T, b1, h1, 1, 2, dtFlag, 4096, 256, 256, label, W1);
  gemm_mfma32v2<<<dim3(4, 128), B, 0, stream>>>(
      h1, W2T, b2, h2, 1, 2, dtFlag, 4096, 256, 256, nullptr, nullptr);
  gemm_mfma32v2<<<dim3(4, 128), B, 0, stream>>>(
      h2, W3T, b3, cf, 1, 2, dtFlag, 4096, 256, 256, nullptr, nullptr);
  // 2. k projection (fused diag), v projection (tiled -> vQ, fused Sv)
  gemm_mfma<<<dim3(4, 8, 64), B, 0, stream>>>(
      xcB, WkT, bk, kB, 1, 1, 0, dtFlag, dgk, nullptr,
      512, 256, 256, 131072L, 8, 65536L, 8, 256L);
  gemm_mfma<<<dim3(4, 8, 64), B, 0, stream>>>(
      cf, WvT, bv, vQ, 1, 1, 2, dtFlag, nullptr, Sv,
      512, 256, 256, 131072L, 8, 65536L, 8, 256L);
  // 3. key side (emits csRp / ktotp partials; finalize folded into q_fused)
  key_fused_mfma<<<dim3(64, 23), B, 0, stream>>>(kB, vQ, projB, dgk, ksumE, ctxQ,
                                                 mpart, csRp, ktotp);
  // 4. query side v10 (q-proj + finalize + normalize folded) -> merged
  q_fused_mfma<<<dim3(64, 8), B, 0, stream>>>(xtB, WqT, bq, projB, ctxQ, ksumE,
                                              Sv, csRp, ktotp, mpart, dtFlag, merged);
  // 5. Wo GEMM (single pass, K=2048, counted-wait) then Wmu
  gemm_mfma32v2<<<dim3(4, 128), B, 0, stream>>>(
      merged, WoT, bo, rep, 1, 1, dtFlag, 4096, 256, 2048, nullptr, nullptr);
  gemm_mfma32v2<<<dim3(4, 128), B, 0, stream>>>(
      rep, WmuT, bmu, d_out, 2, 1, dtFlag, 4096, 256, 256, nullptr, nullptr);
}